// Round 11
// baseline (307.265 us; speedup 1.0000x reference)
//
#include <hip/hip_runtime.h>
#include <hip/hip_bf16.h>
#include <cstddef>

#define T_SEQ 1024
#define D_MODEL 512

typedef __attribute__((ext_vector_type(8))) __bf16 bf16x8;
typedef __attribute__((ext_vector_type(4))) float f32x4;
typedef __attribute__((ext_vector_type(16))) float f32x16;
typedef __attribute__((ext_vector_type(8))) unsigned short u16x8;
typedef __attribute__((ext_vector_type(4))) unsigned int u32x4;

typedef const unsigned int __attribute__((address_space(1)))* gas1_t;
typedef unsigned int __attribute__((address_space(3)))* las3_t;

__device__ __forceinline__ void gload_lds16(const void* g, void* l) {
  __builtin_amdgcn_global_load_lds((gas1_t)g, (las3_t)l, 16, 0, 0);
}

__device__ __forceinline__ float bf2f(unsigned short u) {
  return __uint_as_float(((unsigned)u) << 16);
}
__device__ __forceinline__ unsigned short f2bf(float f) {
  __hip_bfloat16 h = __float2bfloat16(f);
  return *(unsigned short*)&h;
}

#define CVTPK(dst, a, b) \
  asm("v_cvt_pk_bf16_f32 %0, %1, %2" : "=v"(dst) : "v"(a), "v"(b))

__device__ __forceinline__ void swap32(unsigned& a, unsigned& b, int lane) {
  const unsigned ax = __shfl_xor(a, 32);
  const unsigned bx = __shfl_xor(b, 32);
  const bool lo = lane < 32;
  const unsigned na = lo ? a : bx;
  const unsigned nb = lo ? ax : b;
  a = na; b = nb;
}

// =====================================================================
// Prep (unchanged, proven): 22 z-slices of weight transpose/cast + x cast
// + bias casts.
// =====================================================================
__global__ __launch_bounds__(256)
void prep_weights_kernel(const float* __restrict__ loc_wq, const float* __restrict__ loc_wk,
                         const float* __restrict__ loc_wv, const float* __restrict__ g_wq,
                         const float* __restrict__ g_wk, const float* __restrict__ g_wv,
                         const float* __restrict__ out_w, const float* __restrict__ loc_wo,
                         const float* __restrict__ g_wo, const float* __restrict__ x,
                         const float* __restrict__ loc_bq, const float* __restrict__ loc_bk,
                         const float* __restrict__ loc_bv,
                         __hip_bfloat16* __restrict__ WT, __hip_bfloat16* __restrict__ xb,
                         __hip_bfloat16* __restrict__ bqkvb) {
  __shared__ float tile[32][33];
  const size_t MS = (size_t)512 * 512;
  const int z = blockIdx.y;
  const int t = threadIdx.x;

  if (z == 20) {
    const int base = blockIdx.x * 16384 + t * 8;
#pragma unroll
    for (int it = 0; it < 8; ++it) {
      const int i = base + it * 2048;
      const float4 a = *(const float4*)(x + i);
      const float4 b = *(const float4*)(x + i + 4);
      u16x8 o;
      o[0] = f2bf(a.x); o[1] = f2bf(a.y); o[2] = f2bf(a.z); o[3] = f2bf(a.w);
      o[4] = f2bf(b.x); o[5] = f2bf(b.y); o[6] = f2bf(b.z); o[7] = f2bf(b.w);
      *(u16x8*)(xb + i) = o;
    }
    return;
  }
  if (z == 21) {
    const int i = blockIdx.x * 256 + t;
    if (blockIdx.x < 18) {
      const int which = i >> 9, lv = which / 3, role = which % 3, e = i & 511;
      const float* src = role == 0 ? loc_bq : role == 1 ? loc_bk : loc_bv;
      bqkvb[i] = __float2bfloat16(src[lv * 512 + e]);
    }
    return;
  }

  const float* src;
  bool tr = true;
  if (z < 3)       src = loc_wq + (size_t)z * MS;
  else if (z < 6)  src = loc_wk + (size_t)(z - 3) * MS;
  else if (z < 9)  src = loc_wv + (size_t)(z - 6) * MS;
  else if (z == 9)  src = g_wq;
  else if (z == 10) src = g_wk;
  else if (z == 11) src = g_wv;
  else if (z < 16) src = out_w + (size_t)(z - 12) * MS;
  else if (z < 19) { src = loc_wo + (size_t)(z - 16) * MS; tr = false; }
  else             { src = g_wo; tr = false; }
  __hip_bfloat16* dst = WT + (size_t)z * MS;

  const int tk = (blockIdx.x & 15) * 32;
  const int tn = (blockIdx.x >> 4) * 32;
  const int r = t >> 3, c4 = (t & 7) * 4;
  const float4 v = *(const float4*)(src + (size_t)(tk + r) * 512 + tn + c4);
  if (tr) {
    tile[r][c4 + 0] = v.x; tile[r][c4 + 1] = v.y;
    tile[r][c4 + 2] = v.z; tile[r][c4 + 3] = v.w;
    __syncthreads();
    ushort4 o;
    o.x = f2bf(tile[c4 + 0][r]); o.y = f2bf(tile[c4 + 1][r]);
    o.z = f2bf(tile[c4 + 2][r]); o.w = f2bf(tile[c4 + 3][r]);
    *(ushort4*)(dst + (size_t)(tn + r) * 512 + tk + c4) = o;
  } else {
    ushort4 o;
    o.x = f2bf(v.x); o.y = f2bf(v.y); o.z = f2bf(v.z); o.w = f2bf(v.w);
    *(ushort4*)(dst + (size_t)(tk + r) * 512 + tn + c4) = o;
  }
}

// =====================================================================
// GEMM cores (proven).
// =====================================================================
__device__ __forceinline__ void gemm_core_b128(
    const __hip_bfloat16* __restrict__ A, const __hip_bfloat16* __restrict__ BT,
    __hip_bfloat16* As, __hip_bfloat16* Bs, int row0, int col0, f32x4 acc[4][4]) {
  const int tid = threadIdx.x;
  const int wv = tid >> 6, lane = tid & 63;
  const int g = lane >> 4, r16 = lane & 15;
  const int wm = wv >> 1, wn = wv & 1;
  const char* Ab = (const char*)A;
  const char* Bb = (const char*)BT;
  for (int k0 = 0; k0 < 512; k0 += 32) {
    {
      const int row = tid >> 2, off = (tid & 3) << 4;
      gload_lds16(Ab + (size_t)(row0 + row) * 1024 + k0 * 2 + off,
                  (char*)As + (wv << 10));
      const int i2 = tid + 256;
      const int row2 = i2 >> 2, off2 = (i2 & 3) << 4;
      gload_lds16(Ab + (size_t)(row0 + row2) * 1024 + k0 * 2 + off2,
                  (char*)As + 4096 + (wv << 10));
    }
    {
      const int row = tid >> 2, off = (tid & 3) << 4;
      gload_lds16(Bb + (size_t)(col0 + row) * 1024 + k0 * 2 + off,
                  (char*)Bs + (wv << 10));
      const int i2 = tid + 256;
      const int row2 = i2 >> 2, off2 = (i2 & 3) << 4;
      gload_lds16(Bb + (size_t)(col0 + row2) * 1024 + k0 * 2 + off2,
                  (char*)Bs + 4096 + (wv << 10));
    }
    __syncthreads();
    bf16x8 a[4], b[4];
#pragma unroll
    for (int m = 0; m < 4; ++m)
      a[m] = *(const bf16x8*)(As + (wm * 64 + m * 16 + r16) * 32 + g * 8);
#pragma unroll
    for (int n = 0; n < 4; ++n)
      b[n] = *(const bf16x8*)(Bs + (wn * 64 + n * 16 + r16) * 32 + g * 8);
#pragma unroll
    for (int m = 0; m < 4; ++m)
#pragma unroll
      for (int n = 0; n < 4; ++n)
        acc[m][n] = __builtin_amdgcn_mfma_f32_16x16x32_bf16(a[m], b[n], acc[m][n], 0, 0, 0);
    __syncthreads();
  }
}

__device__ __forceinline__ void gemm_core_b64(
    const __hip_bfloat16* __restrict__ A, const __hip_bfloat16* __restrict__ BT,
    __hip_bfloat16* As, __hip_bfloat16* Bs, int row0, int col0, f32x4 acc[2][4]) {
  const int tid = threadIdx.x;
  const int wv = tid >> 6, lane = tid & 63;
  const int g = lane >> 4, r16 = lane & 15;
  const int wm = wv >> 1, wn = wv & 1;
  const char* Ab = (const char*)A;
  const char* Bb = (const char*)BT;
  for (int k0 = 0; k0 < 512; k0 += 32) {
    {
      const int row = tid >> 2, off = (tid & 3) << 4;
      gload_lds16(Ab + (size_t)(row0 + row) * 1024 + k0 * 2 + off,
                  (char*)As + (wv << 10));
    }
    {
      const int row = tid >> 2, off = (tid & 3) << 4;
      gload_lds16(Bb + (size_t)(col0 + row) * 1024 + k0 * 2 + off,
                  (char*)Bs + (wv << 10));
      const int i2 = tid + 256;
      const int row2 = i2 >> 2, off2 = (i2 & 3) << 4;
      gload_lds16(Bb + (size_t)(col0 + row2) * 1024 + k0 * 2 + off2,
                  (char*)Bs + 4096 + (wv << 10));
    }
    __syncthreads();
    bf16x8 a[2], b[4];
#pragma unroll
    for (int m = 0; m < 2; ++m)
      a[m] = *(const bf16x8*)(As + (wm * 32 + m * 16 + r16) * 32 + g * 8);
#pragma unroll
    for (int n = 0; n < 4; ++n)
      b[n] = *(const bf16x8*)(Bs + (wn * 64 + n * 16 + r16) * 32 + g * 8);
#pragma unroll
    for (int m = 0; m < 2; ++m)
#pragma unroll
      for (int n = 0; n < 4; ++n)
        acc[m][n] = __builtin_amdgcn_mfma_f32_16x16x32_bf16(a[m], b[n], acc[m][n], 0, 0, 0);
    __syncthreads();
  }
}

// bf16 C = A@W^T + bias (one 128x128 tile)
__device__ __forceinline__ void gemm_bias_body(
    const __hip_bfloat16* __restrict__ A, const __hip_bfloat16* __restrict__ WT,
    const float* __restrict__ bias, __hip_bfloat16* __restrict__ C,
    int row0, int col0, __hip_bfloat16* As, __hip_bfloat16* Bs) {
  f32x4 acc[4][4];
#pragma unroll
  for (int m = 0; m < 4; ++m)
#pragma unroll
    for (int n = 0; n < 4; ++n) acc[m][n] = (f32x4)(0.0f);
  gemm_core_b128(A, WT, As, Bs, row0, col0, acc);
  const int lane = threadIdx.x & 63, wv = threadIdx.x >> 6;
  const int g = lane >> 4, r16 = lane & 15, wm = wv >> 1, wn = wv & 1;
#pragma unroll
  for (int n = 0; n < 4; ++n) {
    const int col = col0 + wn * 64 + n * 16 + r16;
    const float bn = bias ? bias[col] : 0.f;
#pragma unroll
    for (int m = 0; m < 4; ++m) {
      const int rowb = row0 + wm * 64 + m * 16 + g * 4;
#pragma unroll
      for (int r = 0; r < 4; ++r)
        C[(size_t)(rowb + r) * 512 + col] = __float2bfloat16(acc[m][n][r] + bn);
    }
  }
}

__device__ __forceinline__ void bias_fuse_body(
    const float* __restrict__ bo, const float* __restrict__ W,
    const float* __restrict__ add, float* __restrict__ bfz, int n) {
  float acc = add ? add[n] : 0.f;
  for (int m = 0; m < 512; ++m)
    acc = fmaf(bo[m], W[(size_t)m * 512 + n], acc);
  bfz[n] = acc;
}

// =====================================================================
// MEGA GEMM dispatch: blocks [0,3072) qkv (y-outer XCD swizzle),
// [3072,3136) fusew (WfT[z] = (wo_z @ outw_z)^T), [3136,3144) bias fuse.
// =====================================================================
__global__ __launch_bounds__(256)
void mega_gemm_kernel(const __hip_bfloat16* __restrict__ xb,
                      const __hip_bfloat16* __restrict__ WT,
                      const float* __restrict__ loc_bq, const float* __restrict__ loc_bk,
                      const float* __restrict__ loc_bv, const float* __restrict__ g_bq,
                      const float* __restrict__ g_bk, const float* __restrict__ g_bv,
                      const float* __restrict__ loc_bo, const float* __restrict__ g_bo,
                      const float* __restrict__ out_w, const float* __restrict__ out_b,
                      __hip_bfloat16* __restrict__ proj, float* __restrict__ bfused) {
  __shared__ __attribute__((aligned(16))) __hip_bfloat16 As[4096];
  __shared__ __attribute__((aligned(16))) __hip_bfloat16 Bs[4096];
  const size_t MS = (size_t)512 * 512;
  const size_t SZ = (size_t)8192 * 512;
  const int bid = blockIdx.x;

  if (bid < 3072) {
    // y-outer XCD swizzle: XCD k owns y-chunk [8k, 8k+8)
    const int oid = (bid & 7) * 384 + (bid >> 3);
    const int y = oid / 48;
    const int rem = oid - y * 48;
    const int z = rem >> 2, xcol = rem & 3;
    const float* bias;
    if (z < 3)       bias = loc_bq + z * 512;
    else if (z < 6)  bias = loc_bk + (z - 3) * 512;
    else if (z < 9)  bias = loc_bv + (z - 6) * 512;
    else             bias = (z == 9) ? g_bq : (z == 10) ? g_bk : g_bv;
    gemm_bias_body(xb, WT + (size_t)z * MS, bias, proj + (size_t)z * SZ,
                   y * 128, xcol * 128, As, Bs);
  } else if (bid < 3136) {
    const int i = bid - 3072;
    const int z = i >> 4, y = (i >> 2) & 3, xcol = i & 3;
    // WfT[z] = (wo_z @ outw_z)^T via A = outw^T (slots 12..15), BT = wo (16..19)
    f32x4 acc[4][4];
#pragma unroll
    for (int m = 0; m < 4; ++m)
#pragma unroll
      for (int n = 0; n < 4; ++n) acc[m][n] = (f32x4)(0.0f);
    gemm_core_b128(WT + (size_t)(12 + z) * MS, WT + (size_t)(16 + z) * MS,
                   As, Bs, y * 128, xcol * 128, acc);
    __hip_bfloat16* C = (__hip_bfloat16*)(WT + (size_t)(20 + z) * MS);
    const int lane = threadIdx.x & 63, wv = threadIdx.x >> 6;
    const int g = lane >> 4, r16 = lane & 15, wm = wv >> 1, wn = wv & 1;
#pragma unroll
    for (int n = 0; n < 4; ++n) {
      const int col = xcol * 128 + wn * 64 + n * 16 + r16;
#pragma unroll
      for (int m = 0; m < 4; ++m) {
        const int rowb = y * 128 + wm * 64 + m * 16 + g * 4;
#pragma unroll
        for (int r = 0; r < 4; ++r)
          C[(size_t)(rowb + r) * 512 + col] = __float2bfloat16(acc[m][n][r]);
      }
    }
  } else {
    const int i = bid - 3136;
    const int z = i >> 1;
    const int n = (i & 1) * 256 + threadIdx.x;
    const float* bo = (z < 3) ? loc_bo + z * 512 : g_bo;
    bias_fuse_body(bo, out_w + (size_t)z * MS, z == 0 ? out_b : nullptr,
                   bfused + z * 512, n);
  }
}

// =====================================================================
// Local attention body (R9-proven; no setprio). pool = 8192 unsigned.
// =====================================================================
template <int W>
__device__ __forceinline__ const __hip_bfloat16* slot_row(
    const __hip_bfloat16* __restrict__ X, const __hip_bfloat16* __restrict__ biasb,
    int b, int tloc, int pg, int sl, int* ch_out) {
  constexpr int PAD = (W - 1) / 2;
  const int hloc = sl >> 3, p = sl & 7;
  const int m = (pg * 4 + hloc) * W + p;
  const int j = m >> 3;
  *ch_out = m & 7;
  int sr = tloc + j - PAD;
  if (p < W) {
    if (sr >= 0 && sr < T_SEQ) return X + ((size_t)(b * T_SEQ + sr) << 9);
    return biasb;
  }
  sr = sr < 0 ? 0 : (sr > T_SEQ - 1 ? T_SEQ - 1 : sr);
  return X + ((size_t)(b * T_SEQ + sr) << 9);
}

template <int W>
__device__ __forceinline__ void local_attn_body(
    int bx, const __hip_bfloat16* __restrict__ Xq, const __hip_bfloat16* __restrict__ Xk,
    const __hip_bfloat16* __restrict__ Xv, const __hip_bfloat16* __restrict__ bqb,
    const __hip_bfloat16* __restrict__ bkb, const __hip_bfloat16* __restrict__ bvb,
    __hip_bfloat16* __restrict__ abar, unsigned* pool) {
  const int tid = threadIdx.x;
  const int wv = tid >> 6, lane = tid & 63;
  const int bt = bx * 4 + wv;
  const int b = bt >> 10, tloc = bt & 1023;
  unsigned* L = pool + wv * 2048;
  const int dl = lane & 31, hi = lane >> 5;

  {
    const int k2 = dl, dhalf = hi;
    int ch0, ch1;
    const __hip_bfloat16* r0 =
        slot_row<W>(Xv, bvb, b, tloc, (2 * k2) >> 5, (2 * k2) & 31, &ch0);
    const __hip_bfloat16* r1 =
        slot_row<W>(Xv, bvb, b, tloc, (2 * k2 + 1) >> 5, (2 * k2 + 1) & 31, &ch1);
    u16x8 A0[4], A1[4];
#pragma unroll
    for (int q = 0; q < 4; ++q) {
      A0[q] = *(const u16x8*)(r0 + ch0 * 64 + dhalf * 32 + q * 8);
      A1[q] = *(const u16x8*)(r1 + ch1 * 64 + dhalf * 32 + q * 8);
    }
#pragma unroll
    for (int q = 0; q < 4; ++q)
#pragma unroll
      for (int e = 0; e < 8; ++e) {
        const int d_ = dhalf * 32 + q * 8 + e;
        const unsigned dw = (unsigned)A0[q][e] | ((unsigned)A1[q][e] << 16);
        const int byte = (d_ * 128 + k2 * 4) ^ ((d_ & 7) << 4);
        L[byte >> 2] = dw;
      }
  }

  f32x16 accP[2][2];
#pragma unroll
  for (int pg = 0; pg < 2; ++pg)
#pragma unroll
    for (int dh = 0; dh < 2; ++dh) accP[pg][dh] = (f32x16)(0.0f);

  const int myb = dl >> 3;

#pragma unroll
  for (int pg = 0; pg < 2; ++pg) {
    int chK, chQ;
    const __hip_bfloat16* rK = slot_row<W>(Xk, bkb, b, tloc, pg, dl, &chK);
    const __hip_bfloat16* rQ = slot_row<W>(Xq, bqb, b, tloc, pg, dl, &chQ);
    f32x16 sa = (f32x16)(0.0f);
#pragma unroll
    for (int i = 0; i < 4; ++i) {
      const bf16x8 kf = *(const bf16x8*)(rK + chK * 64 + i * 16 + hi * 8);
      const bf16x8 qf = *(const bf16x8*)(rQ + chQ * 64 + i * 16 + hi * 8);
      sa = __builtin_amdgcn_mfma_f32_32x32x16_bf16(kf, qf, sa, 0, 0, 0);
    }

    float sel[4];
#pragma unroll
    for (int r4 = 0; r4 < 4; ++r4)
      sel[r4] = (myb == 0) ? sa[r4]
              : (myb == 1) ? sa[4 + r4]
              : (myb == 2) ? sa[8 + r4] : sa[12 + r4];

    float mx = -3e38f;
#pragma unroll
    for (int r4 = 0; r4 < 4; ++r4)
      if (r4 + 4 * hi < W) mx = fmaxf(mx, sel[r4]);
    mx = fmaxf(mx, __shfl_xor(mx, 32));
    float e[4], ls = 0.f;
#pragma unroll
    for (int r4 = 0; r4 < 4; ++r4) {
      e[r4] = (r4 + 4 * hi < W) ? __expf(0.125f * (sel[r4] - mx)) : 0.f;
      ls += e[r4];
    }
    ls += __shfl_xor(ls, 32);
    const float inv = 1.f / ls;

    unsigned dw0, dw1;
    CVTPK(dw0, e[0] * inv, e[1] * inv);
    CVTPK(dw1, e[2] * inv, e[3] * inv);
    const unsigned q0 = __shfl_xor(dw0, 32);
    const unsigned q1 = __shfl_xor(dw1, 32);

#pragma unroll
    for (int kh = 0; kh < 2; ++kh) {
      const bool on = (2 * kh + hi) == myb;
      u32x4 bw;
      if (hi == 0) { bw[0] = dw0; bw[1] = dw1; bw[2] = q0; bw[3] = q1; }
      else         { bw[0] = q0;  bw[1] = q1;  bw[2] = dw0; bw[3] = dw1; }
      if (!on) { bw[0] = 0u; bw[1] = 0u; bw[2] = 0u; bw[3] = 0u; }
      const bf16x8 pf = __builtin_bit_cast(bf16x8, bw);
#pragma unroll
      for (int dh = 0; dh < 2; ++dh) {
        const int d_ = dh * 32 + dl;
        const int off = (d_ * 128 + pg * 64 + kh * 32 + hi * 16) ^ ((d_ & 7) << 4);
        const bf16x8 va =
            __builtin_bit_cast(bf16x8, *(const u32x4*)((const char*)L + off));
        accP[pg][dh] = __builtin_amdgcn_mfma_f32_32x32x16_bf16(va, pf, accP[pg][dh], 0, 0, 0);
      }
    }
  }

#pragma unroll
  for (int pg = 0; pg < 2; ++pg) {
    if ((dl & 7) < W) {
      const int m_o = (pg * 4 + (dl >> 3)) * W + (dl & 7);
#pragma unroll
      for (int dh = 0; dh < 2; ++dh) {
#pragma unroll
        for (int rq = 0; rq < 4; ++rq) {
          unsigned wa, wb;
          CVTPK(wa, accP[pg][dh][4 * rq + 0], accP[pg][dh][4 * rq + 1]);
          CVTPK(wb, accP[pg][dh][4 * rq + 2], accP[pg][dh][4 * rq + 3]);
          const int dwi = m_o * 34 + dh * 16 + rq * 4 + hi * 2;
          uint2 w; w.x = wa; w.y = wb;
          *(uint2*)(L + dwi) = w;
        }
      }
    }
  }
  asm volatile("s_waitcnt lgkmcnt(0)" ::: "memory");

  const int cho = lane >> 3, fb = lane & 7;
  float o[8] = {0.f, 0.f, 0.f, 0.f, 0.f, 0.f, 0.f, 0.f};
#pragma unroll
  for (int jj = 0; jj < W; ++jj) {
    const int mo = 8 * jj + cho;
    const uint2 w0 = *(const uint2*)(L + mo * 34 + fb * 4);
    const uint2 w1 = *(const uint2*)(L + mo * 34 + fb * 4 + 2);
    o[0] += bf2f((unsigned short)(w0.x & 0xffff));
    o[1] += bf2f((unsigned short)(w0.x >> 16));
    o[2] += bf2f((unsigned short)(w0.y & 0xffff));
    o[3] += bf2f((unsigned short)(w0.y >> 16));
    o[4] += bf2f((unsigned short)(w1.x & 0xffff));
    o[5] += bf2f((unsigned short)(w1.x >> 16));
    o[6] += bf2f((unsigned short)(w1.y & 0xffff));
    o[7] += bf2f((unsigned short)(w1.y >> 16));
  }
  const float invw = 1.f / (float)W;
  u16x8 ov;
#pragma unroll
  for (int e2 = 0; e2 < 8; ++e2) ov[e2] = f2bf(o[e2] * invw);
  *(u16x8*)(abar + ((size_t)bt << 9) + cho * 64 + fb * 8) = ov;
}

// =====================================================================
// Global attention body (R9-proven, 54us): KVBLK=64, dbuf V^T,
// direct K/Q global loads. pool used as vt[2][2048] (16 KB).
// =====================================================================
#define REDIST(pb, kb_)                                                  \
    {                                                                    \
      unsigned t0_, t1_, t2_, t3_, t4_, t5_, t6_, t7_;                   \
      CVTPK(t0_, pb[0], pb[1]);   CVTPK(t1_, pb[2], pb[3]);              \
      CVTPK(t2_, pb[4], pb[5]);   CVTPK(t3_, pb[6], pb[7]);              \
      CVTPK(t4_, pb[8], pb[9]);   CVTPK(t5_, pb[10], pb[11]);            \
      CVTPK(t6_, pb[12], pb[13]); CVTPK(t7_, pb[14], pb[15]);            \
      swap32(t0_, t2_, lane); swap32(t1_, t3_, lane);                    \
      swap32(t4_, t6_, lane); swap32(t5_, t7_, lane);                    \
      bw[kb_][0][0] = t0_; bw[kb_][0][1] = t1_; bw[kb_][0][2] = t2_;     \
      bw[kb_][0][3] = t3_;                                               \
      bw[kb_][1][0] = t4_; bw[kb_][1][1] = t5_; bw[kb_][1][2] = t6_;     \
      bw[kb_][1][3] = t7_;                                               \
    }

__device__ __forceinline__ void global_attn_body(
    int qblk, int bh, const __hip_bfloat16* __restrict__ Xq,
    const __hip_bfloat16* __restrict__ Xk, const __hip_bfloat16* __restrict__ Xv,
    __hip_bfloat16* __restrict__ att, unsigned* pool) {
  const int tid = threadIdx.x;
  const int lane = tid & 63;
  const int wv = tid >> 6;
  const size_t base = (size_t)bh << 16;
  const int c = lane & 31;
  const int g = lane >> 5;
  const int q0 = qblk * 128 + wv * 32;

  const __hip_bfloat16* Qp = Xq + base;
  const __hip_bfloat16* Kp = Xk + base;
  const __hip_bfloat16* Vp = Xv + base;

  bf16x8 qf[4];
#pragma unroll
  for (int s = 0; s < 4; ++s)
    qf[s] = *(const bf16x8*)(Qp + (size_t)(q0 + c) * 64 + s * 16 + g * 8);

  const int k2 = tid & 31, dblk = tid >> 5;

  bf16x8 kf[2][4];
  u16x8 v0, v1, v0n, v1n;

  v0 = *(const u16x8*)(Vp + (size_t)(2 * k2) * 64 + dblk * 8);
  v1 = *(const u16x8*)(Vp + (size_t)(2 * k2 + 1) * 64 + dblk * 8);
#pragma unroll
  for (int kb = 0; kb < 2; ++kb)
#pragma unroll
    for (int s = 0; s < 4; ++s)
      kf[kb][s] = *(const bf16x8*)(Kp + (size_t)(kb * 32 + c) * 64 + s * 16 + g * 8);

  f32x16 Oa = (f32x16)(0.0f), Ob = (f32x16)(0.0f);
  float m_run = -3e38f, l_run = 0.f;

  for (int kt = 0; kt < 16; ++kt) {
    unsigned* vb = pool + (kt & 1) * 2048;
#pragma unroll
    for (int jj = 0; jj < 8; ++jj) {
      const int d = dblk * 8 + jj;
      const unsigned dw = (unsigned)v0[jj] | ((unsigned)v1[jj] << 16);
      const int byte = (d * 128 + k2 * 4) ^ ((d & 7) << 4);
      vb[byte >> 2] = dw;
    }
    if (kt < 15) {
      const __hip_bfloat16* vsrc = Vp + (size_t)((kt + 1) * 64 + 2 * k2) * 64 + dblk * 8;
      v0n = *(const u16x8*)vsrc;
      v1n = *(const u16x8*)(vsrc + 64);
    }
    __syncthreads();

    f32x16 sa = (f32x16)(0.0f), sb = (f32x16)(0.0f);
#pragma unroll
    for (int s = 0; s < 4; ++s)
      sa = __builtin_amdgcn_mfma_f32_32x32x16_bf16(kf[0][s], qf[s], sa, 0, 0, 0);
#pragma unroll
    for (int s = 0; s < 4; ++s)
      sb = __builtin_amdgcn_mfma_f32_32x32x16_bf16(kf[1][s], qf[s], sb, 0, 0, 0);

    if (kt < 15) {
#pragma unroll
      for (int kb = 0; kb < 2; ++kb)
#pragma unroll
        for (int s = 0; s < 4; ++s)
          kf[kb][s] = *(const bf16x8*)(Kp + (size_t)((kt + 1) * 64 + kb * 32 + c) * 64 +
                                       s * 16 + g * 8);
    }

    float mx = sa[0];
#pragma unroll
    for (int r = 1; r < 16; ++r) mx = fmaxf(mx, sa[r]);
#pragma unroll
    for (int r = 0; r < 16; ++r) mx = fmaxf(mx, sb[r]);
    mx = fmaxf(mx, __shfl_xor(mx, 32));
    const float m_new = fmaxf(m_run, mx * 0.125f);
    const float alpha = __expf(m_run - m_new);

    float p0[16], p1[16];
    float lsum = 0.f;
#pragma unroll
    for (int r = 0; r < 16; ++r) { p0[r] = __expf(fmaf(sa[r], 0.125f, -m_new)); lsum += p0[r]; }
#pragma unroll
    for (int r = 0; r < 16; ++r) { p1[r] = __expf(fmaf(sb[r], 0.125f, -m_new)); lsum += p1[r]; }
    lsum += __shfl_xor(lsum, 32);
    l_run = fmaf(l_run, alpha, lsum);
    m_run = m_new;
#pragma unroll
    for (int r = 0; r < 16; ++r) { Oa[r] *= alpha; Ob[r] *= alpha; }

    unsigned bw[2][2][4];
    REDIST(p0, 0)
    REDIST(p1, 1)

    const unsigned* vbr = pool + (kt & 1) * 2048;
#pragma unroll
    for (int kb = 0; kb < 2; ++kb)
#pragma unroll
      for (int st = 0; st < 2; ++st) {
        const u32x4 pw = { bw[kb][st][0], bw[kb][st][1], bw[kb][st][2], bw[kb][st][3] };
        const bf16x8 pf = __builtin_bit_cast(bf16x8, pw);
        {
          const int row = c;
          const int off = (row * 128 + (kb * 64 + st * 32 + g * 16)) ^ ((row & 7) << 4);
          const bf16x8 va = __builtin_bit_cast(bf16x8, *(const u32x4*)((const char*)vbr + off));
          Oa = __builtin_amdgcn_mfma_f32_32x32x16_bf16(va, pf, Oa, 0, 0, 0);
        }
        {
          const int row = 32 + c;
          const int off = (row * 128 + (kb * 64 + st * 32 + g * 16)) ^ ((row & 7) << 4);
          const bf16x8 va = __builtin_bit_cast(bf16x8, *(const u32x4*)((const char*)vbr + off));
          Ob = __builtin_amdgcn_mfma_f32_32x32x16_bf16(va, pf, Ob, 0, 0, 0);
        }
      }

    v0 = v0n; v1 = v1n;
  }

  const float inv = 1.f / l_run;
  __hip_bfloat16* drow = att + base + (size_t)(q0 + c) * 64;
#pragma unroll
  for (int qd = 0; qd < 4; ++qd) {
    unsigned lo, hi2;
    {
      const float a0 = Oa[4 * qd + 0] * inv, a1 = Oa[4 * qd + 1] * inv;
      const float a2 = Oa[4 * qd + 2] * inv, a3 = Oa[4 * qd + 3] * inv;
      CVTPK(lo, a0, a1); CVTPK(hi2, a2, a3);
      uint2 w; w.x = lo; w.y = hi2;
      *(uint2*)(drow + 8 * qd + 4 * g) = w;
    }
    {
      const float a0 = Ob[4 * qd + 0] * inv, a1 = Ob[4 * qd + 1] * inv;
      const float a2 = Ob[4 * qd + 2] * inv, a3 = Ob[4 * qd + 3] * inv;
      CVTPK(lo, a0, a1); CVTPK(hi2, a2, a3);
      uint2 w; w.x = lo; w.y = hi2;
      *(uint2*)(drow + 32 + 8 * qd + 4 * g) = w;
    }
  }
}

// =====================================================================
// ATTN_ALL: blocks [0,512) = global (longest pole first), then
// [512, 512+3*2048) = locals W=3/5/7. One dispatch — independent work
// overlaps instead of serializing on the stream.
// =====================================================================
__global__ __launch_bounds__(256)
void attn_all_kernel(const __hip_bfloat16* __restrict__ proj,
                     const __hip_bfloat16* __restrict__ bqkvb,
                     __hip_bfloat16* __restrict__ abar0, __hip_bfloat16* __restrict__ abar1,
                     __hip_bfloat16* __restrict__ abar2, __hip_bfloat16* __restrict__ abar3) {
  __shared__ __attribute__((aligned(16))) unsigned pool[8192];
  const size_t SZ = (size_t)8192 * 512;
  const int bid = blockIdx.x;
  if (bid < 512) {
    global_attn_body(bid & 7, bid >> 3, proj + 9 * SZ, proj + 10 * SZ, proj + 11 * SZ,
                     abar3, pool);
  } else {
    const int lb = bid - 512;
    const int lv = lb >> 11;
    const int bx = lb & 2047;
    if (lv == 0)
      local_attn_body<3>(bx, proj + 0 * SZ, proj + 3 * SZ, proj + 6 * SZ,
                         bqkvb + 0 * 512, bqkvb + 1 * 512, bqkvb + 2 * 512, abar0, pool);
    else if (lv == 1)
      local_attn_body<5>(bx, proj + 1 * SZ, proj + 4 * SZ, proj + 7 * SZ,
                         bqkvb + 3 * 512, bqkvb + 4 * 512, bqkvb + 5 * 512, abar1, pool);
    else
      local_attn_body<7>(bx, proj + 2 * SZ, proj + 5 * SZ, proj + 8 * SZ,
                         bqkvb + 6 * 512, bqkvb + 7 * 512, bqkvb + 8 * 512, abar2, pool);
  }
}

// =====================================================================
// Final fused output GEMM (BM=64, grid (4,128)) — proven.
// =====================================================================
__global__ __launch_bounds__(256)
void gemm_out_fused_kernel(const __hip_bfloat16* __restrict__ A0,
                           const __hip_bfloat16* __restrict__ A1,
                           const __hip_bfloat16* __restrict__ A2,
                           const __hip_bfloat16* __restrict__ A3,
                           const __hip_bfloat16* __restrict__ WT_base,
                           const float* __restrict__ bfused,
                           float* __restrict__ out) {
  __shared__ __attribute__((aligned(16))) __hip_bfloat16 As[2048];
  __shared__ __attribute__((aligned(16))) __hip_bfloat16 Bs[4096];
  const size_t MS = (size_t)512 * 512;
  const int row0 = blockIdx.y * 64, col0 = blockIdx.x * 128;
  f32x4 acc[2][4];
#pragma unroll
  for (int m = 0; m < 2; ++m)
#pragma unroll
    for (int n = 0; n < 4; ++n) acc[m][n] = (f32x4)(0.0f);
  const __hip_bfloat16* Az[4] = {A0, A1, A2, A3};
  for (int z = 0; z < 4; ++z)
    gemm_core_b64(Az[z], WT_base + (size_t)z * MS, As, Bs, row0, col0, acc);
  const int lane = threadIdx.x & 63, wv = threadIdx.x >> 6;
  const int g = lane >> 4, r16 = lane & 15, wm = wv >> 1, wn = wv & 1;
#pragma unroll
  for (int n = 0; n < 4; ++n) {
    const int col = col0 + wn * 64 + n * 16 + r16;
    const float bn = bfused[col] + bfused[512 + col] + bfused[1024 + col] +
                     bfused[1536 + col];
#pragma unroll
    for (int m = 0; m < 2; ++m) {
      const int rowb = row0 + wm * 32 + m * 16 + g * 4;
#pragma unroll
      for (int r = 0; r < 4; ++r)
        out[(size_t)(rowb + r) * 512 + col] = acc[m][n][r] + bn;
    }
  }
}

// =====================================================================
// Fallback kernels (small-ws path) — thin wrappers over the same bodies.
// =====================================================================
__global__ __launch_bounds__(256)
void gemm_qkv_kernel(const __hip_bfloat16* __restrict__ A,
                     const __hip_bfloat16* __restrict__ WT_base, size_t wt_stride,
                     const float* __restrict__ b0, const float* __restrict__ b1,
                     const float* __restrict__ b2,
                     __hip_bfloat16* __restrict__ out_base) {
  __shared__ __attribute__((aligned(16))) __hip_bfloat16 As[4096];
  __shared__ __attribute__((aligned(16))) __hip_bfloat16 Bs[4096];
  const int z = blockIdx.z;
  const float* bias = (z == 0) ? b0 : (z == 1) ? b1 : b2;
  gemm_bias_body(A, WT_base + (size_t)z * wt_stride, bias,
                 out_base + (size_t)z * (size_t)(8192 * 512),
                 blockIdx.y * 128, blockIdx.x * 128, As, Bs);
}

__global__ __launch_bounds__(256)
void gemm_fusew_kernel(const __hip_bfloat16* __restrict__ A_base,
                       const __hip_bfloat16* __restrict__ BT_base,
                       __hip_bfloat16* __restrict__ C_base) {
  __shared__ __attribute__((aligned(16))) __hip_bfloat16 As[4096];
  __shared__ __attribute__((aligned(16))) __hip_bfloat16 Bs[4096];
  const size_t MS = (size_t)512 * 512;
  const int z = blockIdx.z;
  f32x4 acc[4][4];
#pragma unroll
  for (int m = 0; m < 4; ++m)
#pragma unroll
    for (int n = 0; n < 4; ++n) acc[m][n] = (f32x4)(0.0f);
  gemm_core_b128(A_base + z * MS, BT_base + z * MS, As, Bs,
                 blockIdx.y * 128, blockIdx.x * 128, acc);
  __hip_bfloat16* C = C_base + z * MS;
  const int lane = threadIdx.x & 63, wv = threadIdx.x >> 6;
  const int g = lane >> 4, r16 = lane & 15, wm = wv >> 1, wn = wv & 1;
#pragma unroll
  for (int n = 0; n < 4; ++n) {
    const int col = blockIdx.x * 128 + wn * 64 + n * 16 + r16;
#pragma unroll
    for (int m = 0; m < 4; ++m) {
      const int rowb = blockIdx.y * 128 + wm * 64 + m * 16 + g * 4;
#pragma unroll
      for (int r = 0; r < 4; ++r)
        C[(size_t)(rowb + r) * 512 + col] = __float2bfloat16(acc[m][n][r]);
    }
  }
}

__global__ __launch_bounds__(256)
void bias_fuse_kernel(const float* __restrict__ loc_bo, const float* __restrict__ g_bo,
                      const float* __restrict__ out_w, const float* __restrict__ out_b,
                      float* __restrict__ bfused) {
  const int z = blockIdx.y;
  const int n = blockIdx.x * 256 + threadIdx.x;
  const float* bo = (z < 3) ? loc_bo + z * 512 : g_bo;
  bias_fuse_body(bo, out_w + (size_t)z * 512 * 512, z == 0 ? out_b : nullptr,
                 bfused + z * 512, n);
}

template <int W>
__global__ __launch_bounds__(256)
void local_attn_mfma_kernel(const __hip_bfloat16* __restrict__ Xq,
                            const __hip_bfloat16* __restrict__ Xk,
                            const __hip_bfloat16* __restrict__ Xv,
                            const __hip_bfloat16* __restrict__ bqb,
                            const __hip_bfloat16* __restrict__ bkb,
                            const __hip_bfloat16* __restrict__ bvb,
                            __hip_bfloat16* __restrict__ abar) {
  __shared__ __attribute__((aligned(16))) unsigned pool[8192];
  local_attn_body<W>(blockIdx.x, Xq, Xk, Xv, bqb, bkb, bvb, abar, pool);
}

__global__ __launch_bounds__(256)
void global_attn_mfma_kernel(const __hip_bfloat16* __restrict__ Xq,
                             const __hip_bfloat16* __restrict__ Xk,
                             const __hip_bfloat16* __restrict__ Xv,
                             __hip_bfloat16* __restrict__ att) {
  __shared__ __attribute__((aligned(16))) unsigned pool[4096];
  global_attn_body(blockIdx.x, blockIdx.y, Xq, Xk, Xv, att, pool);
}

// =====================================================================
// Launch
// =====================================================================
extern "C" void kernel_launch(void* const* d_in, const int* in_sizes, int n_in,
                              void* d_out, int out_size, void* d_ws, size_t ws_size,
                              hipStream_t stream) {
  const float* x      = (const float*)d_in[0];
  const float* loc_wq = (const float*)d_in[1];
  const float* loc_bq = (const float*)d_in[2];
  const float* loc_wk = (const float*)d_in[3];
  const float* loc_bk = (const float*)d_in[4];
  const float* loc_wv = (const float*)d_in[5];
  const float* loc_bv = (const float*)d_in[6];
  const float* loc_wo = (const float*)d_in[7];
  const float* loc_bo = (const float*)d_in[8];
  const float* g_wq  = (const float*)d_in[9];
  const float* g_bq  = (const float*)d_in[10];
  const float* g_wk  = (const float*)d_in[11];
  const float* g_bk  = (const float*)d_in[12];
  const float* g_wv  = (const float*)d_in[13];
  const float* g_bv  = (const float*)d_in[14];
  const float* g_wo  = (const float*)d_in[15];
  const float* g_bo  = (const float*)d_in[16];
  const float* out_w = (const float*)d_in[17];
  const float* out_b = (const float*)d_in[18];
  float* out = (float*)d_out;

  __hip_bfloat16* wsb = (__hip_bfloat16*)d_ws;
  const size_t SZ = (size_t)8192 * 512;
  const size_t MS = (size_t)512 * 512;

  __hip_bfloat16* xb    = wsb;
  __hip_bfloat16* WT    = wsb + SZ;
  float* bfused = (float*)(wsb + SZ + 24 * MS);             // 4096 bf16 elems
  __hip_bfloat16* bqkvb = wsb + SZ + 24 * MS + 4096;
  __hip_bfloat16* proj  = wsb + SZ + 24 * MS + 16384;

  const size_t need_big = 2 * (17 * SZ + 24 * MS + 16384);
  const bool big = ws_size >= need_big;

  const dim3 thr(256);

  prep_weights_kernel<<<dim3(256, 22), thr, 0, stream>>>(
      loc_wq, loc_wk, loc_wv, g_wq, g_wk, g_wv, out_w, loc_wo, g_wo,
      x, loc_bq, loc_bk, loc_bv, WT, xb, bqkvb);

  __hip_bfloat16 *abar0, *abar1, *abar2, *abar3;

  if (big) {
    abar0 = proj + 12 * SZ;
    abar1 = proj + 13 * SZ;
    abar2 = proj + 14 * SZ;
    abar3 = proj + 15 * SZ;
    // qkv x12 + fusew + bias-fuse in ONE dispatch
    mega_gemm_kernel<<<3144, thr, 0, stream>>>(
        xb, WT, loc_bq, loc_bk, loc_bv, g_bq, g_bk, g_bv,
        loc_bo, g_bo, out_w, out_b, proj, bfused);
    // all 4 attention branches in ONE dispatch (global first)
    attn_all_kernel<<<6656, thr, 0, stream>>>(proj, bqkvb, abar0, abar1, abar2, abar3);
  } else {
    gemm_fusew_kernel<<<dim3(4, 4, 4), thr, 0, stream>>>(WT + 12 * MS, WT + 16 * MS,
                                                         WT + 20 * MS);
    bias_fuse_kernel<<<dim3(2, 4), thr, 0, stream>>>(loc_bo, g_bo, out_w, out_b, bfused);
    __hip_bfloat16* Xq = proj;
    __hip_bfloat16* Xk = proj + SZ;
    __hip_bfloat16* Xv = proj + 2 * SZ;
    abar0 = proj + 3 * SZ;
    abar1 = proj + 4 * SZ;
    abar2 = proj + 5 * SZ;
    abar3 = proj + 6 * SZ;
    __hip_bfloat16* abars[3] = {abar0, abar1, abar2};
    const dim3 gqkv(4, 64, 3);
    for (int lv = 0; lv < 3; ++lv) {
      gemm_qkv_kernel<<<gqkv, thr, 0, stream>>>(
          xb, WT + lv * MS, 3 * MS,
          loc_bq + lv * 512, loc_bk + lv * 512, loc_bv + lv * 512, Xq);
      const __hip_bfloat16* bqb = bqkvb + (lv * 3 + 0) * 512;
      const __hip_bfloat16* bkb = bqkvb + (lv * 3 + 1) * 512;
      const __hip_bfloat16* bvb = bqkvb + (lv * 3 + 2) * 512;
      if (lv == 0)
        local_attn_mfma_kernel<3><<<2048, thr, 0, stream>>>(Xq, Xk, Xv, bqb, bkb, bvb, abars[lv]);
      else if (lv == 1)
        local_attn_mfma_kernel<5><<<2048, thr, 0, stream>>>(Xq, Xk, Xv, bqb, bkb, bvb, abars[lv]);
      else
        local_attn_mfma_kernel<7><<<2048, thr, 0, stream>>>(Xq, Xk, Xv, bqb, bkb, bvb, abars[lv]);
    }
    gemm_qkv_kernel<<<gqkv, thr, 0, stream>>>(xb, WT + 9 * MS, MS, g_bq, g_bk, g_bv, Xq);
    global_attn_mfma_kernel<<<dim3(8, 64), thr, 0, stream>>>(Xq, Xk, Xv, abar3);
  }

  gemm_out_fused_kernel<<<dim3(4, 128), thr, 0, stream>>>(abar0, abar1, abar2, abar3,
                                                          WT + 20 * MS, bfused, out);
}

// Round 12
// 288.233 us; speedup vs baseline: 1.0660x; 1.0660x over previous
//
#include <hip/hip_runtime.h>
#include <hip/hip_bf16.h>
#include <cstddef>

#define T_SEQ 1024
#define D_MODEL 512

typedef __attribute__((ext_vector_type(8))) __bf16 bf16x8;
typedef __attribute__((ext_vector_type(4))) float f32x4;
typedef __attribute__((ext_vector_type(16))) float f32x16;
typedef __attribute__((ext_vector_type(8))) unsigned short u16x8;
typedef __attribute__((ext_vector_type(4))) unsigned int u32x4;

typedef const unsigned int __attribute__((address_space(1)))* gas1_t;
typedef unsigned int __attribute__((address_space(3)))* las3_t;

__device__ __forceinline__ void gload_lds16(const void* g, void* l) {
  __builtin_amdgcn_global_load_lds((gas1_t)g, (las3_t)l, 16, 0, 0);
}

__device__ __forceinline__ float bf2f(unsigned short u) {
  return __uint_as_float(((unsigned)u) << 16);
}
__device__ __forceinline__ unsigned short f2bf(float f) {
  __hip_bfloat16 h = __float2bfloat16(f);
  return *(unsigned short*)&h;
}

#define CVTPK(dst, a, b) \
  asm("v_cvt_pk_bf16_f32 %0, %1, %2" : "=v"(dst) : "v"(a), "v"(b))

__device__ __forceinline__ void swap32(unsigned& a, unsigned& b, int lane) {
  const unsigned ax = __shfl_xor(a, 32);
  const unsigned bx = __shfl_xor(b, 32);
  const bool lo = lane < 32;
  const unsigned na = lo ? a : bx;
  const unsigned nb = lo ? ax : b;
  a = na; b = nb;
}

// =====================================================================
// Prep (proven): 22 z-slices of weight transpose/cast + x cast + bias.
// =====================================================================
__global__ __launch_bounds__(256)
void prep_weights_kernel(const float* __restrict__ loc_wq, const float* __restrict__ loc_wk,
                         const float* __restrict__ loc_wv, const float* __restrict__ g_wq,
                         const float* __restrict__ g_wk, const float* __restrict__ g_wv,
                         const float* __restrict__ out_w, const float* __restrict__ loc_wo,
                         const float* __restrict__ g_wo, const float* __restrict__ x,
                         const float* __restrict__ loc_bq, const float* __restrict__ loc_bk,
                         const float* __restrict__ loc_bv,
                         __hip_bfloat16* __restrict__ WT, __hip_bfloat16* __restrict__ xb,
                         __hip_bfloat16* __restrict__ bqkvb) {
  __shared__ float tile[32][33];
  const size_t MS = (size_t)512 * 512;
  const int z = blockIdx.y;
  const int t = threadIdx.x;

  if (z == 20) {
    const int base = blockIdx.x * 16384 + t * 8;
#pragma unroll
    for (int it = 0; it < 8; ++it) {
      const int i = base + it * 2048;
      const float4 a = *(const float4*)(x + i);
      const float4 b = *(const float4*)(x + i + 4);
      u16x8 o;
      o[0] = f2bf(a.x); o[1] = f2bf(a.y); o[2] = f2bf(a.z); o[3] = f2bf(a.w);
      o[4] = f2bf(b.x); o[5] = f2bf(b.y); o[6] = f2bf(b.z); o[7] = f2bf(b.w);
      *(u16x8*)(xb + i) = o;
    }
    return;
  }
  if (z == 21) {
    const int i = blockIdx.x * 256 + t;
    if (blockIdx.x < 18) {
      const int which = i >> 9, lv = which / 3, role = which % 3, e = i & 511;
      const float* src = role == 0 ? loc_bq : role == 1 ? loc_bk : loc_bv;
      bqkvb[i] = __float2bfloat16(src[lv * 512 + e]);
    }
    return;
  }

  const float* src;
  bool tr = true;
  if (z < 3)       src = loc_wq + (size_t)z * MS;
  else if (z < 6)  src = loc_wk + (size_t)(z - 3) * MS;
  else if (z < 9)  src = loc_wv + (size_t)(z - 6) * MS;
  else if (z == 9)  src = g_wq;
  else if (z == 10) src = g_wk;
  else if (z == 11) src = g_wv;
  else if (z < 16) src = out_w + (size_t)(z - 12) * MS;
  else if (z < 19) { src = loc_wo + (size_t)(z - 16) * MS; tr = false; }
  else             { src = g_wo; tr = false; }
  __hip_bfloat16* dst = WT + (size_t)z * MS;

  const int tk = (blockIdx.x & 15) * 32;
  const int tn = (blockIdx.x >> 4) * 32;
  const int r = t >> 3, c4 = (t & 7) * 4;
  const float4 v = *(const float4*)(src + (size_t)(tk + r) * 512 + tn + c4);
  if (tr) {
    tile[r][c4 + 0] = v.x; tile[r][c4 + 1] = v.y;
    tile[r][c4 + 2] = v.z; tile[r][c4 + 3] = v.w;
    __syncthreads();
    ushort4 o;
    o.x = f2bf(tile[c4 + 0][r]); o.y = f2bf(tile[c4 + 1][r]);
    o.z = f2bf(tile[c4 + 2][r]); o.w = f2bf(tile[c4 + 3][r]);
    *(ushort4*)(dst + (size_t)(tn + r) * 512 + tk + c4) = o;
  } else {
    ushort4 o;
    o.x = f2bf(v.x); o.y = f2bf(v.y); o.z = f2bf(v.z); o.w = f2bf(v.w);
    *(ushort4*)(dst + (size_t)(tk + r) * 512 + tn + c4) = o;
  }
}

// =====================================================================
// GEMM cores (proven).
// =====================================================================
__device__ __forceinline__ void gemm_core_b128(
    const __hip_bfloat16* __restrict__ A, const __hip_bfloat16* __restrict__ BT,
    __hip_bfloat16* As, __hip_bfloat16* Bs, int row0, int col0, f32x4 acc[4][4]) {
  const int tid = threadIdx.x;
  const int wv = tid >> 6, lane = tid & 63;
  const int g = lane >> 4, r16 = lane & 15;
  const int wm = wv >> 1, wn = wv & 1;
  const char* Ab = (const char*)A;
  const char* Bb = (const char*)BT;
  for (int k0 = 0; k0 < 512; k0 += 32) {
    {
      const int row = tid >> 2, off = (tid & 3) << 4;
      gload_lds16(Ab + (size_t)(row0 + row) * 1024 + k0 * 2 + off,
                  (char*)As + (wv << 10));
      const int i2 = tid + 256;
      const int row2 = i2 >> 2, off2 = (i2 & 3) << 4;
      gload_lds16(Ab + (size_t)(row0 + row2) * 1024 + k0 * 2 + off2,
                  (char*)As + 4096 + (wv << 10));
    }
    {
      const int row = tid >> 2, off = (tid & 3) << 4;
      gload_lds16(Bb + (size_t)(col0 + row) * 1024 + k0 * 2 + off,
                  (char*)Bs + (wv << 10));
      const int i2 = tid + 256;
      const int row2 = i2 >> 2, off2 = (i2 & 3) << 4;
      gload_lds16(Bb + (size_t)(col0 + row2) * 1024 + k0 * 2 + off2,
                  (char*)Bs + 4096 + (wv << 10));
    }
    __syncthreads();
    bf16x8 a[4], b[4];
#pragma unroll
    for (int m = 0; m < 4; ++m)
      a[m] = *(const bf16x8*)(As + (wm * 64 + m * 16 + r16) * 32 + g * 8);
#pragma unroll
    for (int n = 0; n < 4; ++n)
      b[n] = *(const bf16x8*)(Bs + (wn * 64 + n * 16 + r16) * 32 + g * 8);
#pragma unroll
    for (int m = 0; m < 4; ++m)
#pragma unroll
      for (int n = 0; n < 4; ++n)
        acc[m][n] = __builtin_amdgcn_mfma_f32_16x16x32_bf16(a[m], b[n], acc[m][n], 0, 0, 0);
    __syncthreads();
  }
}

__device__ __forceinline__ void gemm_core_b64(
    const __hip_bfloat16* __restrict__ A, const __hip_bfloat16* __restrict__ BT,
    __hip_bfloat16* As, __hip_bfloat16* Bs, int row0, int col0, f32x4 acc[2][4]) {
  const int tid = threadIdx.x;
  const int wv = tid >> 6, lane = tid & 63;
  const int g = lane >> 4, r16 = lane & 15;
  const int wm = wv >> 1, wn = wv & 1;
  const char* Ab = (const char*)A;
  const char* Bb = (const char*)BT;
  for (int k0 = 0; k0 < 512; k0 += 32) {
    {
      const int row = tid >> 2, off = (tid & 3) << 4;
      gload_lds16(Ab + (size_t)(row0 + row) * 1024 + k0 * 2 + off,
                  (char*)As + (wv << 10));
    }
    {
      const int row = tid >> 2, off = (tid & 3) << 4;
      gload_lds16(Bb + (size_t)(col0 + row) * 1024 + k0 * 2 + off,
                  (char*)Bs + (wv << 10));
      const int i2 = tid + 256;
      const int row2 = i2 >> 2, off2 = (i2 & 3) << 4;
      gload_lds16(Bb + (size_t)(col0 + row2) * 1024 + k0 * 2 + off2,
                  (char*)Bs + 4096 + (wv << 10));
    }
    __syncthreads();
    bf16x8 a[2], b[4];
#pragma unroll
    for (int m = 0; m < 2; ++m)
      a[m] = *(const bf16x8*)(As + (wm * 32 + m * 16 + r16) * 32 + g * 8);
#pragma unroll
    for (int n = 0; n < 4; ++n)
      b[n] = *(const bf16x8*)(Bs + (wn * 64 + n * 16 + r16) * 32 + g * 8);
#pragma unroll
    for (int m = 0; m < 2; ++m)
#pragma unroll
      for (int n = 0; n < 4; ++n)
        acc[m][n] = __builtin_amdgcn_mfma_f32_16x16x32_bf16(a[m], b[n], acc[m][n], 0, 0, 0);
    __syncthreads();
  }
}

// bf16 C = A@W^T + bias (one 128x128 tile)
__device__ __forceinline__ void gemm_bias_body(
    const __hip_bfloat16* __restrict__ A, const __hip_bfloat16* __restrict__ WT,
    const float* __restrict__ bias, __hip_bfloat16* __restrict__ C,
    int row0, int col0, __hip_bfloat16* As, __hip_bfloat16* Bs) {
  f32x4 acc[4][4];
#pragma unroll
  for (int m = 0; m < 4; ++m)
#pragma unroll
    for (int n = 0; n < 4; ++n) acc[m][n] = (f32x4)(0.0f);
  gemm_core_b128(A, WT, As, Bs, row0, col0, acc);
  const int lane = threadIdx.x & 63, wv = threadIdx.x >> 6;
  const int g = lane >> 4, r16 = lane & 15, wm = wv >> 1, wn = wv & 1;
#pragma unroll
  for (int n = 0; n < 4; ++n) {
    const int col = col0 + wn * 64 + n * 16 + r16;
    const float bn = bias ? bias[col] : 0.f;
#pragma unroll
    for (int m = 0; m < 4; ++m) {
      const int rowb = row0 + wm * 64 + m * 16 + g * 4;
#pragma unroll
      for (int r = 0; r < 4; ++r)
        C[(size_t)(rowb + r) * 512 + col] = __float2bfloat16(acc[m][n][r] + bn);
    }
  }
}

// Mega Q/K/V: ALL 12 projections in one dispatch (proven in R10, ~90us).
__global__ __launch_bounds__(256)
void gemm_qkv_all_kernel(const __hip_bfloat16* __restrict__ A,
                         const __hip_bfloat16* __restrict__ WT_base,
                         const float* __restrict__ loc_bq, const float* __restrict__ loc_bk,
                         const float* __restrict__ loc_bv, const float* __restrict__ g_bq,
                         const float* __restrict__ g_bk, const float* __restrict__ g_bv,
                         __hip_bfloat16* __restrict__ proj_base) {
  __shared__ __attribute__((aligned(16))) __hip_bfloat16 As[4096];
  __shared__ __attribute__((aligned(16))) __hip_bfloat16 Bs[4096];
  const size_t MS = (size_t)512 * 512;
  const int z = blockIdx.z;
  const float* bias;
  if (z < 3)       bias = loc_bq + z * 512;
  else if (z < 6)  bias = loc_bk + (z - 3) * 512;
  else if (z < 9)  bias = loc_bv + (z - 6) * 512;
  else             bias = (z == 9) ? g_bq : (z == 10) ? g_bk : g_bv;
  gemm_bias_body(A, WT_base + (size_t)z * MS, bias,
                 proj_base + (size_t)z * (size_t)(8192 * 512),
                 blockIdx.y * 128, blockIdx.x * 128, As, Bs);
}

// Fallback per-level Q/K/V projection.
__global__ __launch_bounds__(256)
void gemm_qkv_kernel(const __hip_bfloat16* __restrict__ A,
                     const __hip_bfloat16* __restrict__ WT_base, size_t wt_stride,
                     const float* __restrict__ b0, const float* __restrict__ b1,
                     const float* __restrict__ b2,
                     __hip_bfloat16* __restrict__ out_base) {
  __shared__ __attribute__((aligned(16))) __hip_bfloat16 As[4096];
  __shared__ __attribute__((aligned(16))) __hip_bfloat16 Bs[4096];
  const int z = blockIdx.z;
  const float* bias = (z == 0) ? b0 : (z == 1) ? b1 : b2;
  gemm_bias_body(A, WT_base + (size_t)z * wt_stride, bias,
                 out_base + (size_t)z * (size_t)(8192 * 512),
                 blockIdx.y * 128, blockIdx.x * 128, As, Bs);
}

// Fused-weight GEMM: WfT[z] = (wo_z @ outw_z)^T (BM=128, batched z).
__global__ __launch_bounds__(256)
void gemm_fusew_kernel(const __hip_bfloat16* __restrict__ A_base,
                       const __hip_bfloat16* __restrict__ BT_base,
                       __hip_bfloat16* __restrict__ C_base) {
  __shared__ __attribute__((aligned(16))) __hip_bfloat16 As[4096];
  __shared__ __attribute__((aligned(16))) __hip_bfloat16 Bs[4096];
  const size_t MS = (size_t)512 * 512;
  const int z = blockIdx.z;
  f32x4 acc[4][4];
#pragma unroll
  for (int m = 0; m < 4; ++m)
#pragma unroll
    for (int n = 0; n < 4; ++n) acc[m][n] = (f32x4)(0.0f);
  gemm_core_b128(A_base + z * MS, BT_base + z * MS, As, Bs,
                 blockIdx.y * 128, blockIdx.x * 128, acc);
  __hip_bfloat16* C = C_base + z * MS;
  const int lane = threadIdx.x & 63, wv = threadIdx.x >> 6;
  const int g = lane >> 4, r16 = lane & 15, wm = wv >> 1, wn = wv & 1;
#pragma unroll
  for (int n = 0; n < 4; ++n) {
    const int col = blockIdx.x * 128 + wn * 64 + n * 16 + r16;
#pragma unroll
    for (int m = 0; m < 4; ++m) {
      const int rowb = blockIdx.y * 128 + wm * 64 + m * 16 + g * 4;
#pragma unroll
      for (int r = 0; r < 4; ++r)
        C[(size_t)(rowb + r) * 512 + col] = __float2bfloat16(acc[m][n][r]);
    }
  }
}

__global__ __launch_bounds__(256)
void bias_fuse_kernel(const float* __restrict__ loc_bo, const float* __restrict__ g_bo,
                      const float* __restrict__ out_w, const float* __restrict__ out_b,
                      float* __restrict__ bfused) {
  const int z = blockIdx.y;
  const int n = blockIdx.x * 256 + threadIdx.x;
  const float* bo = (z < 3) ? loc_bo + z * 512 : g_bo;
  const float* W = out_w + (size_t)z * 512 * 512;
  float acc = (z == 0) ? out_b[n] : 0.f;
  for (int m = 0; m < 512; ++m)
    acc = fmaf(bo[m], W[(size_t)m * 512 + n], acc);
  bfused[z * 512 + n] = acc;
}

// =====================================================================
// Local attention body (R9-proven).
// =====================================================================
template <int W>
__device__ __forceinline__ const __hip_bfloat16* slot_row(
    const __hip_bfloat16* __restrict__ X, const __hip_bfloat16* __restrict__ biasb,
    int b, int tloc, int pg, int sl, int* ch_out) {
  constexpr int PAD = (W - 1) / 2;
  const int hloc = sl >> 3, p = sl & 7;
  const int m = (pg * 4 + hloc) * W + p;
  const int j = m >> 3;
  *ch_out = m & 7;
  int sr = tloc + j - PAD;
  if (p < W) {
    if (sr >= 0 && sr < T_SEQ) return X + ((size_t)(b * T_SEQ + sr) << 9);
    return biasb;
  }
  sr = sr < 0 ? 0 : (sr > T_SEQ - 1 ? T_SEQ - 1 : sr);
  return X + ((size_t)(b * T_SEQ + sr) << 9);
}

template <int W>
__device__ __forceinline__ void local_attn_body(
    int bx, const __hip_bfloat16* __restrict__ Xq, const __hip_bfloat16* __restrict__ Xk,
    const __hip_bfloat16* __restrict__ Xv, const __hip_bfloat16* __restrict__ bqb,
    const __hip_bfloat16* __restrict__ bkb, const __hip_bfloat16* __restrict__ bvb,
    __hip_bfloat16* __restrict__ abar, unsigned* pool) {
  const int tid = threadIdx.x;
  const int wv = tid >> 6, lane = tid & 63;
  const int bt = bx * 4 + wv;
  const int b = bt >> 10, tloc = bt & 1023;
  unsigned* L = pool + wv * 2048;
  const int dl = lane & 31, hi = lane >> 5;

  {
    const int k2 = dl, dhalf = hi;
    int ch0, ch1;
    const __hip_bfloat16* r0 =
        slot_row<W>(Xv, bvb, b, tloc, (2 * k2) >> 5, (2 * k2) & 31, &ch0);
    const __hip_bfloat16* r1 =
        slot_row<W>(Xv, bvb, b, tloc, (2 * k2 + 1) >> 5, (2 * k2 + 1) & 31, &ch1);
    u16x8 A0[4], A1[4];
#pragma unroll
    for (int q = 0; q < 4; ++q) {
      A0[q] = *(const u16x8*)(r0 + ch0 * 64 + dhalf * 32 + q * 8);
      A1[q] = *(const u16x8*)(r1 + ch1 * 64 + dhalf * 32 + q * 8);
    }
#pragma unroll
    for (int q = 0; q < 4; ++q)
#pragma unroll
      for (int e = 0; e < 8; ++e) {
        const int d_ = dhalf * 32 + q * 8 + e;
        const unsigned dw = (unsigned)A0[q][e] | ((unsigned)A1[q][e] << 16);
        const int byte = (d_ * 128 + k2 * 4) ^ ((d_ & 7) << 4);
        L[byte >> 2] = dw;
      }
  }

  f32x16 accP[2][2];
#pragma unroll
  for (int pg = 0; pg < 2; ++pg)
#pragma unroll
    for (int dh = 0; dh < 2; ++dh) accP[pg][dh] = (f32x16)(0.0f);

  const int myb = dl >> 3;

#pragma unroll
  for (int pg = 0; pg < 2; ++pg) {
    int chK, chQ;
    const __hip_bfloat16* rK = slot_row<W>(Xk, bkb, b, tloc, pg, dl, &chK);
    const __hip_bfloat16* rQ = slot_row<W>(Xq, bqb, b, tloc, pg, dl, &chQ);
    f32x16 sa = (f32x16)(0.0f);
#pragma unroll
    for (int i = 0; i < 4; ++i) {
      const bf16x8 kf = *(const bf16x8*)(rK + chK * 64 + i * 16 + hi * 8);
      const bf16x8 qf = *(const bf16x8*)(rQ + chQ * 64 + i * 16 + hi * 8);
      sa = __builtin_amdgcn_mfma_f32_32x32x16_bf16(kf, qf, sa, 0, 0, 0);
    }

    float sel[4];
#pragma unroll
    for (int r4 = 0; r4 < 4; ++r4)
      sel[r4] = (myb == 0) ? sa[r4]
              : (myb == 1) ? sa[4 + r4]
              : (myb == 2) ? sa[8 + r4] : sa[12 + r4];

    float mx = -3e38f;
#pragma unroll
    for (int r4 = 0; r4 < 4; ++r4)
      if (r4 + 4 * hi < W) mx = fmaxf(mx, sel[r4]);
    mx = fmaxf(mx, __shfl_xor(mx, 32));
    float e[4], ls = 0.f;
#pragma unroll
    for (int r4 = 0; r4 < 4; ++r4) {
      e[r4] = (r4 + 4 * hi < W) ? __expf(0.125f * (sel[r4] - mx)) : 0.f;
      ls += e[r4];
    }
    ls += __shfl_xor(ls, 32);
    const float inv = 1.f / ls;

    unsigned dw0, dw1;
    CVTPK(dw0, e[0] * inv, e[1] * inv);
    CVTPK(dw1, e[2] * inv, e[3] * inv);
    const unsigned q0 = __shfl_xor(dw0, 32);
    const unsigned q1 = __shfl_xor(dw1, 32);

#pragma unroll
    for (int kh = 0; kh < 2; ++kh) {
      const bool on = (2 * kh + hi) == myb;
      u32x4 bw;
      if (hi == 0) { bw[0] = dw0; bw[1] = dw1; bw[2] = q0; bw[3] = q1; }
      else         { bw[0] = q0;  bw[1] = q1;  bw[2] = dw0; bw[3] = dw1; }
      if (!on) { bw[0] = 0u; bw[1] = 0u; bw[2] = 0u; bw[3] = 0u; }
      const bf16x8 pf = __builtin_bit_cast(bf16x8, bw);
#pragma unroll
      for (int dh = 0; dh < 2; ++dh) {
        const int d_ = dh * 32 + dl;
        const int off = (d_ * 128 + pg * 64 + kh * 32 + hi * 16) ^ ((d_ & 7) << 4);
        const bf16x8 va =
            __builtin_bit_cast(bf16x8, *(const u32x4*)((const char*)L + off));
        accP[pg][dh] = __builtin_amdgcn_mfma_f32_32x32x16_bf16(va, pf, accP[pg][dh], 0, 0, 0);
      }
    }
  }

#pragma unroll
  for (int pg = 0; pg < 2; ++pg) {
    if ((dl & 7) < W) {
      const int m_o = (pg * 4 + (dl >> 3)) * W + (dl & 7);
#pragma unroll
      for (int dh = 0; dh < 2; ++dh) {
#pragma unroll
        for (int rq = 0; rq < 4; ++rq) {
          unsigned wa, wb;
          CVTPK(wa, accP[pg][dh][4 * rq + 0], accP[pg][dh][4 * rq + 1]);
          CVTPK(wb, accP[pg][dh][4 * rq + 2], accP[pg][dh][4 * rq + 3]);
          const int dwi = m_o * 34 + dh * 16 + rq * 4 + hi * 2;
          uint2 w; w.x = wa; w.y = wb;
          *(uint2*)(L + dwi) = w;
        }
      }
    }
  }
  asm volatile("s_waitcnt lgkmcnt(0)" ::: "memory");

  const int cho = lane >> 3, fb = lane & 7;
  float o[8] = {0.f, 0.f, 0.f, 0.f, 0.f, 0.f, 0.f, 0.f};
#pragma unroll
  for (int jj = 0; jj < W; ++jj) {
    const int mo = 8 * jj + cho;
    const uint2 w0 = *(const uint2*)(L + mo * 34 + fb * 4);
    const uint2 w1 = *(const uint2*)(L + mo * 34 + fb * 4 + 2);
    o[0] += bf2f((unsigned short)(w0.x & 0xffff));
    o[1] += bf2f((unsigned short)(w0.x >> 16));
    o[2] += bf2f((unsigned short)(w0.y & 0xffff));
    o[3] += bf2f((unsigned short)(w0.y >> 16));
    o[4] += bf2f((unsigned short)(w1.x & 0xffff));
    o[5] += bf2f((unsigned short)(w1.x >> 16));
    o[6] += bf2f((unsigned short)(w1.y & 0xffff));
    o[7] += bf2f((unsigned short)(w1.y >> 16));
  }
  const float invw = 1.f / (float)W;
  u16x8 ov;
#pragma unroll
  for (int e2 = 0; e2 < 8; ++e2) ov[e2] = f2bf(o[e2] * invw);
  *(u16x8*)(abar + ((size_t)bt << 9) + cho * 64 + fb * 8) = ov;
}

// XCD-chunked swizzle wrapper: 2048 blocks, 8 XCDs -> each XCD gets a
// contiguous 256-block chunk = one full batch b (its Q/K/V fit 4MB L2).
template <int W>
__global__ __launch_bounds__(256)
void local_attn_mfma_kernel(const __hip_bfloat16* __restrict__ Xq,
                            const __hip_bfloat16* __restrict__ Xk,
                            const __hip_bfloat16* __restrict__ Xv,
                            const __hip_bfloat16* __restrict__ bqb,
                            const __hip_bfloat16* __restrict__ bkb,
                            const __hip_bfloat16* __restrict__ bvb,
                            __hip_bfloat16* __restrict__ abar) {
  __shared__ __attribute__((aligned(16))) unsigned pool[8192];
  const int bx = (blockIdx.x & 7) * 256 + (blockIdx.x >> 3);
  local_attn_body<W>(bx, Xq, Xk, Xv, bqb, bkb, bvb, abar, pool);
}

// =====================================================================
// Global attention body (R9-proven, 54us).
// =====================================================================
#define REDIST(pb, kb_)                                                  \
    {                                                                    \
      unsigned t0_, t1_, t2_, t3_, t4_, t5_, t6_, t7_;                   \
      CVTPK(t0_, pb[0], pb[1]);   CVTPK(t1_, pb[2], pb[3]);              \
      CVTPK(t2_, pb[4], pb[5]);   CVTPK(t3_, pb[6], pb[7]);              \
      CVTPK(t4_, pb[8], pb[9]);   CVTPK(t5_, pb[10], pb[11]);            \
      CVTPK(t6_, pb[12], pb[13]); CVTPK(t7_, pb[14], pb[15]);            \
      swap32(t0_, t2_, lane); swap32(t1_, t3_, lane);                    \
      swap32(t4_, t6_, lane); swap32(t5_, t7_, lane);                    \
      bw[kb_][0][0] = t0_; bw[kb_][0][1] = t1_; bw[kb_][0][2] = t2_;     \
      bw[kb_][0][3] = t3_;                                               \
      bw[kb_][1][0] = t4_; bw[kb_][1][1] = t5_; bw[kb_][1][2] = t6_;     \
      bw[kb_][1][3] = t7_;                                               \
    }

__device__ __forceinline__ void global_attn_body(
    int qblk, int bh, const __hip_bfloat16* __restrict__ Xq,
    const __hip_bfloat16* __restrict__ Xk, const __hip_bfloat16* __restrict__ Xv,
    __hip_bfloat16* __restrict__ att, unsigned* pool) {
  const int tid = threadIdx.x;
  const int lane = tid & 63;
  const int wv = tid >> 6;
  const size_t base = (size_t)bh << 16;
  const int c = lane & 31;
  const int g = lane >> 5;
  const int q0 = qblk * 128 + wv * 32;

  const __hip_bfloat16* Qp = Xq + base;
  const __hip_bfloat16* Kp = Xk + base;
  const __hip_bfloat16* Vp = Xv + base;

  bf16x8 qf[4];
#pragma unroll
  for (int s = 0; s < 4; ++s)
    qf[s] = *(const bf16x8*)(Qp + (size_t)(q0 + c) * 64 + s * 16 + g * 8);

  const int k2 = tid & 31, dblk = tid >> 5;

  bf16x8 kf[2][4];
  u16x8 v0, v1, v0n, v1n;

  v0 = *(const u16x8*)(Vp + (size_t)(2 * k2) * 64 + dblk * 8);
  v1 = *(const u16x8*)(Vp + (size_t)(2 * k2 + 1) * 64 + dblk * 8);
#pragma unroll
  for (int kb = 0; kb < 2; ++kb)
#pragma unroll
    for (int s = 0; s < 4; ++s)
      kf[kb][s] = *(const bf16x8*)(Kp + (size_t)(kb * 32 + c) * 64 + s * 16 + g * 8);

  f32x16 Oa = (f32x16)(0.0f), Ob = (f32x16)(0.0f);
  float m_run = -3e38f, l_run = 0.f;

  for (int kt = 0; kt < 16; ++kt) {
    unsigned* vb = pool + (kt & 1) * 2048;
#pragma unroll
    for (int jj = 0; jj < 8; ++jj) {
      const int d = dblk * 8 + jj;
      const unsigned dw = (unsigned)v0[jj] | ((unsigned)v1[jj] << 16);
      const int byte = (d * 128 + k2 * 4) ^ ((d & 7) << 4);
      vb[byte >> 2] = dw;
    }
    if (kt < 15) {
      const __hip_bfloat16* vsrc = Vp + (size_t)((kt + 1) * 64 + 2 * k2) * 64 + dblk * 8;
      v0n = *(const u16x8*)vsrc;
      v1n = *(const u16x8*)(vsrc + 64);
    }
    __syncthreads();

    f32x16 sa = (f32x16)(0.0f), sb = (f32x16)(0.0f);
#pragma unroll
    for (int s = 0; s < 4; ++s)
      sa = __builtin_amdgcn_mfma_f32_32x32x16_bf16(kf[0][s], qf[s], sa, 0, 0, 0);
#pragma unroll
    for (int s = 0; s < 4; ++s)
      sb = __builtin_amdgcn_mfma_f32_32x32x16_bf16(kf[1][s], qf[s], sb, 0, 0, 0);

    if (kt < 15) {
#pragma unroll
      for (int kb = 0; kb < 2; ++kb)
#pragma unroll
        for (int s = 0; s < 4; ++s)
          kf[kb][s] = *(const bf16x8*)(Kp + (size_t)((kt + 1) * 64 + kb * 32 + c) * 64 +
                                       s * 16 + g * 8);
    }

    float mx = sa[0];
#pragma unroll
    for (int r = 1; r < 16; ++r) mx = fmaxf(mx, sa[r]);
#pragma unroll
    for (int r = 0; r < 16; ++r) mx = fmaxf(mx, sb[r]);
    mx = fmaxf(mx, __shfl_xor(mx, 32));
    const float m_new = fmaxf(m_run, mx * 0.125f);
    const float alpha = __expf(m_run - m_new);

    float p0[16], p1[16];
    float lsum = 0.f;
#pragma unroll
    for (int r = 0; r < 16; ++r) { p0[r] = __expf(fmaf(sa[r], 0.125f, -m_new)); lsum += p0[r]; }
#pragma unroll
    for (int r = 0; r < 16; ++r) { p1[r] = __expf(fmaf(sb[r], 0.125f, -m_new)); lsum += p1[r]; }
    lsum += __shfl_xor(lsum, 32);
    l_run = fmaf(l_run, alpha, lsum);
    m_run = m_new;
#pragma unroll
    for (int r = 0; r < 16; ++r) { Oa[r] *= alpha; Ob[r] *= alpha; }

    unsigned bw[2][2][4];
    REDIST(p0, 0)
    REDIST(p1, 1)

    const unsigned* vbr = pool + (kt & 1) * 2048;
#pragma unroll
    for (int kb = 0; kb < 2; ++kb)
#pragma unroll
      for (int st = 0; st < 2; ++st) {
        const u32x4 pw = { bw[kb][st][0], bw[kb][st][1], bw[kb][st][2], bw[kb][st][3] };
        const bf16x8 pf = __builtin_bit_cast(bf16x8, pw);
        {
          const int row = c;
          const int off = (row * 128 + (kb * 64 + st * 32 + g * 16)) ^ ((row & 7) << 4);
          const bf16x8 va = __builtin_bit_cast(bf16x8, *(const u32x4*)((const char*)vbr + off));
          Oa = __builtin_amdgcn_mfma_f32_32x32x16_bf16(va, pf, Oa, 0, 0, 0);
        }
        {
          const int row = 32 + c;
          const int off = (row * 128 + (kb * 64 + st * 32 + g * 16)) ^ ((row & 7) << 4);
          const bf16x8 va = __builtin_bit_cast(bf16x8, *(const u32x4*)((const char*)vbr + off));
          Ob = __builtin_amdgcn_mfma_f32_32x32x16_bf16(va, pf, Ob, 0, 0, 0);
        }
      }

    v0 = v0n; v1 = v1n;
  }

  const float inv = 1.f / l_run;
  __hip_bfloat16* drow = att + base + (size_t)(q0 + c) * 64;
#pragma unroll
  for (int qd = 0; qd < 4; ++qd) {
    unsigned lo, hi2;
    {
      const float a0 = Oa[4 * qd + 0] * inv, a1 = Oa[4 * qd + 1] * inv;
      const float a2 = Oa[4 * qd + 2] * inv, a3 = Oa[4 * qd + 3] * inv;
      CVTPK(lo, a0, a1); CVTPK(hi2, a2, a3);
      uint2 w; w.x = lo; w.y = hi2;
      *(uint2*)(drow + 8 * qd + 4 * g) = w;
    }
    {
      const float a0 = Ob[4 * qd + 0] * inv, a1 = Ob[4 * qd + 1] * inv;
      const float a2 = Ob[4 * qd + 2] * inv, a3 = Ob[4 * qd + 3] * inv;
      CVTPK(lo, a0, a1); CVTPK(hi2, a2, a3);
      uint2 w; w.x = lo; w.y = hi2;
      *(uint2*)(drow + 32 + 8 * qd + 4 * g) = w;
    }
  }
}

// Grid (64,8): linear id = bh + qblk*64 -> XCD = bh & 7, so all 8
// q-blocks of one head land on ONE XCD -> its K/V fetched into that L2
// once instead of 8 HBM re-fetches.
__global__ __launch_bounds__(256)
void global_attn_mfma_kernel(const __hip_bfloat16* __restrict__ Xq,
                             const __hip_bfloat16* __restrict__ Xk,
                             const __hip_bfloat16* __restrict__ Xv,
                             __hip_bfloat16* __restrict__ att) {
  __shared__ __attribute__((aligned(16))) unsigned pool[4096];
  global_attn_body(blockIdx.y, blockIdx.x, Xq, Xk, Xv, att, pool);
}

// =====================================================================
// Final fused output GEMM (BM=64, grid (4,128)) — proven.
// =====================================================================
__global__ __launch_bounds__(256)
void gemm_out_fused_kernel(const __hip_bfloat16* __restrict__ A0,
                           const __hip_bfloat16* __restrict__ A1,
                           const __hip_bfloat16* __restrict__ A2,
                           const __hip_bfloat16* __restrict__ A3,
                           const __hip_bfloat16* __restrict__ WT_base,
                           const float* __restrict__ bfused,
                           float* __restrict__ out) {
  __shared__ __attribute__((aligned(16))) __hip_bfloat16 As[2048];
  __shared__ __attribute__((aligned(16))) __hip_bfloat16 Bs[4096];
  const size_t MS = (size_t)512 * 512;
  const int row0 = blockIdx.y * 64, col0 = blockIdx.x * 128;
  f32x4 acc[2][4];
#pragma unroll
  for (int m = 0; m < 2; ++m)
#pragma unroll
    for (int n = 0; n < 4; ++n) acc[m][n] = (f32x4)(0.0f);
  const __hip_bfloat16* Az[4] = {A0, A1, A2, A3};
  for (int z = 0; z < 4; ++z)
    gemm_core_b64(Az[z], WT_base + (size_t)z * MS, As, Bs, row0, col0, acc);
  const int lane = threadIdx.x & 63, wv = threadIdx.x >> 6;
  const int g = lane >> 4, r16 = lane & 15, wm = wv >> 1, wn = wv & 1;
#pragma unroll
  for (int n = 0; n < 4; ++n) {
    const int col = col0 + wn * 64 + n * 16 + r16;
    const float bn = bfused[col] + bfused[512 + col] + bfused[1024 + col] +
                     bfused[1536 + col];
#pragma unroll
    for (int m = 0; m < 2; ++m) {
      const int rowb = row0 + wm * 32 + m * 16 + g * 4;
#pragma unroll
      for (int r = 0; r < 4; ++r)
        out[(size_t)(rowb + r) * 512 + col] = acc[m][n][r] + bn;
    }
  }
}

// =====================================================================
// Launch (R10 structure — measured best — with swizzled attn grids)
// =====================================================================
extern "C" void kernel_launch(void* const* d_in, const int* in_sizes, int n_in,
                              void* d_out, int out_size, void* d_ws, size_t ws_size,
                              hipStream_t stream) {
  const float* x      = (const float*)d_in[0];
  const float* loc_wq = (const float*)d_in[1];
  const float* loc_bq = (const float*)d_in[2];
  const float* loc_wk = (const float*)d_in[3];
  const float* loc_bk = (const float*)d_in[4];
  const float* loc_wv = (const float*)d_in[5];
  const float* loc_bv = (const float*)d_in[6];
  const float* loc_wo = (const float*)d_in[7];
  const float* loc_bo = (const float*)d_in[8];
  const float* g_wq  = (const float*)d_in[9];
  const float* g_bq  = (const float*)d_in[10];
  const float* g_wk  = (const float*)d_in[11];
  const float* g_bk  = (const float*)d_in[12];
  const float* g_wv  = (const float*)d_in[13];
  const float* g_bv  = (const float*)d_in[14];
  const float* g_wo  = (const float*)d_in[15];
  const float* g_bo  = (const float*)d_in[16];
  const float* out_w = (const float*)d_in[17];
  const float* out_b = (const float*)d_in[18];
  float* out = (float*)d_out;

  __hip_bfloat16* wsb = (__hip_bfloat16*)d_ws;
  const size_t SZ = (size_t)8192 * 512;
  const size_t MS = (size_t)512 * 512;

  __hip_bfloat16* xb    = wsb;
  __hip_bfloat16* WT    = wsb + SZ;
  float* bfused = (float*)(wsb + SZ + 24 * MS);
  __hip_bfloat16* bqkvb = wsb + SZ + 24 * MS + 4096;
  __hip_bfloat16* proj  = wsb + SZ + 24 * MS + 16384;

  const size_t need_big = 2 * (17 * SZ + 24 * MS + 16384);
  const bool big = ws_size >= need_big;

  const dim3 thr(256);

  prep_weights_kernel<<<dim3(256, 22), thr, 0, stream>>>(
      loc_wq, loc_wk, loc_wv, g_wq, g_wk, g_wv, out_w, loc_wo, g_wo,
      x, loc_bq, loc_bk, loc_bv, WT, xb, bqkvb);
  gemm_fusew_kernel<<<dim3(4, 4, 4), thr, 0, stream>>>(WT + 12 * MS, WT + 16 * MS,
                                                       WT + 20 * MS);
  bias_fuse_kernel<<<dim3(2, 4), thr, 0, stream>>>(loc_bo, g_bo, out_w, out_b, bfused);

  __hip_bfloat16 *abar0, *abar1, *abar2, *abar3;

  if (big) {
    abar0 = proj + 12 * SZ;
    abar1 = proj + 13 * SZ;
    abar2 = proj + 14 * SZ;
    abar3 = proj + 15 * SZ;
    gemm_qkv_all_kernel<<<dim3(4, 64, 12), thr, 0, stream>>>(
        xb, WT, loc_bq, loc_bk, loc_bv, g_bq, g_bk, g_bv, proj);
    local_attn_mfma_kernel<3><<<2048, thr, 0, stream>>>(
        proj + 0 * SZ, proj + 3 * SZ, proj + 6 * SZ,
        bqkvb + 0 * 512, bqkvb + 1 * 512, bqkvb + 2 * 512, abar0);
    local_attn_mfma_kernel<5><<<2048, thr, 0, stream>>>(
        proj + 1 * SZ, proj + 4 * SZ, proj + 7 * SZ,
        bqkvb + 3 * 512, bqkvb + 4 * 512, bqkvb + 5 * 512, abar1);
    local_attn_mfma_kernel<7><<<2048, thr, 0, stream>>>(
        proj + 2 * SZ, proj + 5 * SZ, proj + 8 * SZ,
        bqkvb + 6 * 512, bqkvb + 7 * 512, bqkvb + 8 * 512, abar2);
    global_attn_mfma_kernel<<<dim3(64, 8), thr, 0, stream>>>(
        proj + 9 * SZ, proj + 10 * SZ, proj + 11 * SZ, abar3);
  } else {
    __hip_bfloat16* Xq = proj;
    __hip_bfloat16* Xk = proj + SZ;
    __hip_bfloat16* Xv = proj + 2 * SZ;
    abar0 = proj + 3 * SZ;
    abar1 = proj + 4 * SZ;
    abar2 = proj + 5 * SZ;
    abar3 = proj + 6 * SZ;
    __hip_bfloat16* abars[3] = {abar0, abar1, abar2};
    const dim3 gqkv(4, 64, 3);
    for (int lv = 0; lv < 3; ++lv) {
      gemm_qkv_kernel<<<gqkv, thr, 0, stream>>>(
          xb, WT + lv * MS, 3 * MS,
          loc_bq + lv * 512, loc_bk + lv * 512, loc_bv + lv * 512, Xq);
      const __hip_bfloat16* bqb = bqkvb + (lv * 3 + 0) * 512;
      const __hip_bfloat16* bkb = bqkvb + (lv * 3 + 1) * 512;
      const __hip_bfloat16* bvb = bqkvb + (lv * 3 + 2) * 512;
      if (lv == 0)
        local_attn_mfma_kernel<3><<<2048, thr, 0, stream>>>(Xq, Xk, Xv, bqb, bkb, bvb, abars[lv]);
      else if (lv == 1)
        local_attn_mfma_kernel<5><<<2048, thr, 0, stream>>>(Xq, Xk, Xv, bqb, bkb, bvb, abars[lv]);
      else
        local_attn_mfma_kernel<7><<<2048, thr, 0, stream>>>(Xq, Xk, Xv, bqb, bkb, bvb, abars[lv]);
    }
    gemm_qkv_kernel<<<gqkv, thr, 0, stream>>>(xb, WT + 9 * MS, MS, g_bq, g_bk, g_bv, Xq);
    global_attn_mfma_kernel<<<dim3(64, 8), thr, 0, stream>>>(Xq, Xk, Xv, abar3);
  }

  gemm_out_fused_kernel<<<dim3(4, 128), thr, 0, stream>>>(abar0, abar1, abar2, abar3,
                                                          WT + 20 * MS, bfused, out);
}

// Round 13
// 257.416 us; speedup vs baseline: 1.1937x; 1.1197x over previous
//
#include <hip/hip_runtime.h>
#include <hip/hip_bf16.h>
#include <cstddef>

#define T_SEQ 1024
#define D_MODEL 512

typedef __attribute__((ext_vector_type(8))) __bf16 bf16x8;
typedef __attribute__((ext_vector_type(4))) float f32x4;
typedef __attribute__((ext_vector_type(16))) float f32x16;
typedef __attribute__((ext_vector_type(8))) unsigned short u16x8;
typedef __attribute__((ext_vector_type(4))) unsigned int u32x4;

typedef const unsigned int __attribute__((address_space(1)))* gas1_t;
typedef unsigned int __attribute__((address_space(3)))* las3_t;

__device__ __forceinline__ void gload_lds16(const void* g, void* l) {
  __builtin_amdgcn_global_load_lds((gas1_t)g, (las3_t)l, 16, 0, 0);
}

__device__ __forceinline__ float bf2f(unsigned short u) {
  return __uint_as_float(((unsigned)u) << 16);
}
__device__ __forceinline__ unsigned short f2bf(float f) {
  __hip_bfloat16 h = __float2bfloat16(f);
  return *(unsigned short*)&h;
}

#define CVTPK(dst, a, b) \
  asm("v_cvt_pk_bf16_f32 %0, %1, %2" : "=v"(dst) : "v"(a), "v"(b))

__device__ __forceinline__ void swap32(unsigned& a, unsigned& b, int lane) {
  const unsigned ax = __shfl_xor(a, 32);
  const unsigned bx = __shfl_xor(b, 32);
  const bool lo = lane < 32;
  const unsigned na = lo ? a : bx;
  const unsigned nb = lo ? ax : b;
  a = na; b = nb;
}

// =====================================================================
// Prep (proven): 22 z-slices of weight transpose/cast + x cast + bias.
// =====================================================================
__global__ __launch_bounds__(256)
void prep_weights_kernel(const float* __restrict__ loc_wq, const float* __restrict__ loc_wk,
                         const float* __restrict__ loc_wv, const float* __restrict__ g_wq,
                         const float* __restrict__ g_wk, const float* __restrict__ g_wv,
                         const float* __restrict__ out_w, const float* __restrict__ loc_wo,
                         const float* __restrict__ g_wo, const float* __restrict__ x,
                         const float* __restrict__ loc_bq, const float* __restrict__ loc_bk,
                         const float* __restrict__ loc_bv,
                         __hip_bfloat16* __restrict__ WT, __hip_bfloat16* __restrict__ xb,
                         __hip_bfloat16* __restrict__ bqkvb) {
  __shared__ float tile[32][33];
  const size_t MS = (size_t)512 * 512;
  const int z = blockIdx.y;
  const int t = threadIdx.x;

  if (z == 20) {
    const int base = blockIdx.x * 16384 + t * 8;
#pragma unroll
    for (int it = 0; it < 8; ++it) {
      const int i = base + it * 2048;
      const float4 a = *(const float4*)(x + i);
      const float4 b = *(const float4*)(x + i + 4);
      u16x8 o;
      o[0] = f2bf(a.x); o[1] = f2bf(a.y); o[2] = f2bf(a.z); o[3] = f2bf(a.w);
      o[4] = f2bf(b.x); o[5] = f2bf(b.y); o[6] = f2bf(b.z); o[7] = f2bf(b.w);
      *(u16x8*)(xb + i) = o;
    }
    return;
  }
  if (z == 21) {
    const int i = blockIdx.x * 256 + t;
    if (blockIdx.x < 18) {
      const int which = i >> 9, lv = which / 3, role = which % 3, e = i & 511;
      const float* src = role == 0 ? loc_bq : role == 1 ? loc_bk : loc_bv;
      bqkvb[i] = __float2bfloat16(src[lv * 512 + e]);
    }
    return;
  }

  const float* src;
  bool tr = true;
  if (z < 3)       src = loc_wq + (size_t)z * MS;
  else if (z < 6)  src = loc_wk + (size_t)(z - 3) * MS;
  else if (z < 9)  src = loc_wv + (size_t)(z - 6) * MS;
  else if (z == 9)  src = g_wq;
  else if (z == 10) src = g_wk;
  else if (z == 11) src = g_wv;
  else if (z < 16) src = out_w + (size_t)(z - 12) * MS;
  else if (z < 19) { src = loc_wo + (size_t)(z - 16) * MS; tr = false; }
  else             { src = g_wo; tr = false; }
  __hip_bfloat16* dst = WT + (size_t)z * MS;

  const int tk = (blockIdx.x & 15) * 32;
  const int tn = (blockIdx.x >> 4) * 32;
  const int r = t >> 3, c4 = (t & 7) * 4;
  const float4 v = *(const float4*)(src + (size_t)(tk + r) * 512 + tn + c4);
  if (tr) {
    tile[r][c4 + 0] = v.x; tile[r][c4 + 1] = v.y;
    tile[r][c4 + 2] = v.z; tile[r][c4 + 3] = v.w;
    __syncthreads();
    ushort4 o;
    o.x = f2bf(tile[c4 + 0][r]); o.y = f2bf(tile[c4 + 1][r]);
    o.z = f2bf(tile[c4 + 2][r]); o.w = f2bf(tile[c4 + 3][r]);
    *(ushort4*)(dst + (size_t)(tn + r) * 512 + tk + c4) = o;
  } else {
    ushort4 o;
    o.x = f2bf(v.x); o.y = f2bf(v.y); o.z = f2bf(v.z); o.w = f2bf(v.w);
    *(ushort4*)(dst + (size_t)(tk + r) * 512 + tn + c4) = o;
  }
}

// =====================================================================
// GEMM cores (proven).
// =====================================================================
__device__ __forceinline__ void gemm_core_b128(
    const __hip_bfloat16* __restrict__ A, const __hip_bfloat16* __restrict__ BT,
    __hip_bfloat16* As, __hip_bfloat16* Bs, int row0, int col0, f32x4 acc[4][4]) {
  const int tid = threadIdx.x;
  const int wv = tid >> 6, lane = tid & 63;
  const int g = lane >> 4, r16 = lane & 15;
  const int wm = wv >> 1, wn = wv & 1;
  const char* Ab = (const char*)A;
  const char* Bb = (const char*)BT;
  for (int k0 = 0; k0 < 512; k0 += 32) {
    {
      const int row = tid >> 2, off = (tid & 3) << 4;
      gload_lds16(Ab + (size_t)(row0 + row) * 1024 + k0 * 2 + off,
                  (char*)As + (wv << 10));
      const int i2 = tid + 256;
      const int row2 = i2 >> 2, off2 = (i2 & 3) << 4;
      gload_lds16(Ab + (size_t)(row0 + row2) * 1024 + k0 * 2 + off2,
                  (char*)As + 4096 + (wv << 10));
    }
    {
      const int row = tid >> 2, off = (tid & 3) << 4;
      gload_lds16(Bb + (size_t)(col0 + row) * 1024 + k0 * 2 + off,
                  (char*)Bs + (wv << 10));
      const int i2 = tid + 256;
      const int row2 = i2 >> 2, off2 = (i2 & 3) << 4;
      gload_lds16(Bb + (size_t)(col0 + row2) * 1024 + k0 * 2 + off2,
                  (char*)Bs + 4096 + (wv << 10));
    }
    __syncthreads();
    bf16x8 a[4], b[4];
#pragma unroll
    for (int m = 0; m < 4; ++m)
      a[m] = *(const bf16x8*)(As + (wm * 64 + m * 16 + r16) * 32 + g * 8);
#pragma unroll
    for (int n = 0; n < 4; ++n)
      b[n] = *(const bf16x8*)(Bs + (wn * 64 + n * 16 + r16) * 32 + g * 8);
#pragma unroll
    for (int m = 0; m < 4; ++m)
#pragma unroll
      for (int n = 0; n < 4; ++n)
        acc[m][n] = __builtin_amdgcn_mfma_f32_16x16x32_bf16(a[m], b[n], acc[m][n], 0, 0, 0);
    __syncthreads();
  }
}

__device__ __forceinline__ void gemm_core_b64(
    const __hip_bfloat16* __restrict__ A, const __hip_bfloat16* __restrict__ BT,
    __hip_bfloat16* As, __hip_bfloat16* Bs, int row0, int col0, f32x4 acc[2][4]) {
  const int tid = threadIdx.x;
  const int wv = tid >> 6, lane = tid & 63;
  const int g = lane >> 4, r16 = lane & 15;
  const int wm = wv >> 1, wn = wv & 1;
  const char* Ab = (const char*)A;
  const char* Bb = (const char*)BT;
  for (int k0 = 0; k0 < 512; k0 += 32) {
    {
      const int row = tid >> 2, off = (tid & 3) << 4;
      gload_lds16(Ab + (size_t)(row0 + row) * 1024 + k0 * 2 + off,
                  (char*)As + (wv << 10));
    }
    {
      const int row = tid >> 2, off = (tid & 3) << 4;
      gload_lds16(Bb + (size_t)(col0 + row) * 1024 + k0 * 2 + off,
                  (char*)Bs + (wv << 10));
      const int i2 = tid + 256;
      const int row2 = i2 >> 2, off2 = (i2 & 3) << 4;
      gload_lds16(Bb + (size_t)(col0 + row2) * 1024 + k0 * 2 + off2,
                  (char*)Bs + 4096 + (wv << 10));
    }
    __syncthreads();
    bf16x8 a[2], b[4];
#pragma unroll
    for (int m = 0; m < 2; ++m)
      a[m] = *(const bf16x8*)(As + (wm * 32 + m * 16 + r16) * 32 + g * 8);
#pragma unroll
    for (int n = 0; n < 4; ++n)
      b[n] = *(const bf16x8*)(Bs + (wn * 64 + n * 16 + r16) * 32 + g * 8);
#pragma unroll
    for (int m = 0; m < 2; ++m)
#pragma unroll
      for (int n = 0; n < 4; ++n)
        acc[m][n] = __builtin_amdgcn_mfma_f32_16x16x32_bf16(a[m], b[n], acc[m][n], 0, 0, 0);
    __syncthreads();
  }
}

// bf16 C = A@W^T + bias (one 128x128 tile)
__device__ __forceinline__ void gemm_bias_body(
    const __hip_bfloat16* __restrict__ A, const __hip_bfloat16* __restrict__ WT,
    const float* __restrict__ bias, __hip_bfloat16* __restrict__ C,
    int row0, int col0, __hip_bfloat16* As, __hip_bfloat16* Bs) {
  f32x4 acc[4][4];
#pragma unroll
  for (int m = 0; m < 4; ++m)
#pragma unroll
    for (int n = 0; n < 4; ++n) acc[m][n] = (f32x4)(0.0f);
  gemm_core_b128(A, WT, As, Bs, row0, col0, acc);
  const int lane = threadIdx.x & 63, wv = threadIdx.x >> 6;
  const int g = lane >> 4, r16 = lane & 15, wm = wv >> 1, wn = wv & 1;
#pragma unroll
  for (int n = 0; n < 4; ++n) {
    const int col = col0 + wn * 64 + n * 16 + r16;
    const float bn = bias ? bias[col] : 0.f;
#pragma unroll
    for (int m = 0; m < 4; ++m) {
      const int rowb = row0 + wm * 64 + m * 16 + g * 4;
#pragma unroll
      for (int r = 0; r < 4; ++r)
        C[(size_t)(rowb + r) * 512 + col] = __float2bfloat16(acc[m][n][r] + bn);
    }
  }
}

__device__ __forceinline__ void bias_fuse_body(
    const float* __restrict__ bo, const float* __restrict__ W,
    const float* __restrict__ add, float* __restrict__ bfz, int n) {
  float acc = add ? add[n] : 0.f;
  for (int m = 0; m < 512; ++m)
    acc = fmaf(bo[m], W[(size_t)m * 512 + n], acc);
  bfz[n] = acc;
}

// =====================================================================
// Mega Q/K/V + folded fusew/bias-fuse. z = 0..11: projections (proven
// R10 body). z == 12: homogeneous extras — (y&12)==0: fusew tile
// (WfT[wz] = (wo_wz @ outw_wz)^T, wz=y>>4, row=y&3, col=x);
// (y&15)==4|5: bias-fuse half. Other blocks exit immediately.
// =====================================================================
__global__ __launch_bounds__(256)
void gemm_qkv_all_kernel(const __hip_bfloat16* __restrict__ A,
                         const __hip_bfloat16* __restrict__ WT_base,
                         const float* __restrict__ loc_bq, const float* __restrict__ loc_bk,
                         const float* __restrict__ loc_bv, const float* __restrict__ g_bq,
                         const float* __restrict__ g_bk, const float* __restrict__ g_bv,
                         const float* __restrict__ loc_bo, const float* __restrict__ g_bo,
                         const float* __restrict__ out_w, const float* __restrict__ out_b,
                         __hip_bfloat16* __restrict__ proj_base,
                         float* __restrict__ bfused) {
  __shared__ __attribute__((aligned(16))) __hip_bfloat16 As[4096];
  __shared__ __attribute__((aligned(16))) __hip_bfloat16 Bs[4096];
  const size_t MS = (size_t)512 * 512;
  const int z = blockIdx.z;

  if (z == 12) {
    const int y = blockIdx.y;
    if ((y & 12) == 0) {
      // fusew: 64 blocks
      const int wz = y >> 4, row = y & 3, col = blockIdx.x;
      f32x4 acc[4][4];
#pragma unroll
      for (int m = 0; m < 4; ++m)
#pragma unroll
        for (int n = 0; n < 4; ++n) acc[m][n] = (f32x4)(0.0f);
      gemm_core_b128(WT_base + (size_t)(12 + wz) * MS, WT_base + (size_t)(16 + wz) * MS,
                     As, Bs, row * 128, col * 128, acc);
      __hip_bfloat16* C = (__hip_bfloat16*)(WT_base + (size_t)(20 + wz) * MS);
      const int lane = threadIdx.x & 63, wv = threadIdx.x >> 6;
      const int g = lane >> 4, r16 = lane & 15, wm = wv >> 1, wn = wv & 1;
#pragma unroll
      for (int n = 0; n < 4; ++n) {
        const int cc = col * 128 + wn * 64 + n * 16 + r16;
#pragma unroll
        for (int m = 0; m < 4; ++m) {
          const int rowb = row * 128 + wm * 64 + m * 16 + g * 4;
#pragma unroll
          for (int r = 0; r < 4; ++r)
            C[(size_t)(rowb + r) * 512 + cc] = __float2bfloat16(acc[m][n][r]);
        }
      }
    } else if (((y & 15) == 4 || (y & 15) == 5) && blockIdx.x == 0) {
      // bias fuse: 8 blocks
      const int wz = y >> 4, half = y & 1;
      const int n = half * 256 + threadIdx.x;
      const float* bo = (wz < 3) ? loc_bo + wz * 512 : g_bo;
      bias_fuse_body(bo, out_w + (size_t)wz * MS, wz == 0 ? out_b : nullptr,
                     bfused + wz * 512, n);
    }
    return;
  }

  const float* bias;
  if (z < 3)       bias = loc_bq + z * 512;
  else if (z < 6)  bias = loc_bk + (z - 3) * 512;
  else if (z < 9)  bias = loc_bv + (z - 6) * 512;
  else             bias = (z == 9) ? g_bq : (z == 10) ? g_bk : g_bv;
  gemm_bias_body(A, WT_base + (size_t)z * MS, bias,
                 proj_base + (size_t)z * (size_t)(8192 * 512),
                 blockIdx.y * 128, blockIdx.x * 128, As, Bs);
}

// Fallback per-level Q/K/V projection.
__global__ __launch_bounds__(256)
void gemm_qkv_kernel(const __hip_bfloat16* __restrict__ A,
                     const __hip_bfloat16* __restrict__ WT_base, size_t wt_stride,
                     const float* __restrict__ b0, const float* __restrict__ b1,
                     const float* __restrict__ b2,
                     __hip_bfloat16* __restrict__ out_base) {
  __shared__ __attribute__((aligned(16))) __hip_bfloat16 As[4096];
  __shared__ __attribute__((aligned(16))) __hip_bfloat16 Bs[4096];
  const int z = blockIdx.z;
  const float* bias = (z == 0) ? b0 : (z == 1) ? b1 : b2;
  gemm_bias_body(A, WT_base + (size_t)z * wt_stride, bias,
                 out_base + (size_t)z * (size_t)(8192 * 512),
                 blockIdx.y * 128, blockIdx.x * 128, As, Bs);
}

// Fused-weight GEMM (fallback path).
__global__ __launch_bounds__(256)
void gemm_fusew_kernel(const __hip_bfloat16* __restrict__ A_base,
                       const __hip_bfloat16* __restrict__ BT_base,
                       __hip_bfloat16* __restrict__ C_base) {
  __shared__ __attribute__((aligned(16))) __hip_bfloat16 As[4096];
  __shared__ __attribute__((aligned(16))) __hip_bfloat16 Bs[4096];
  const size_t MS = (size_t)512 * 512;
  const int z = blockIdx.z;
  f32x4 acc[4][4];
#pragma unroll
  for (int m = 0; m < 4; ++m)
#pragma unroll
    for (int n = 0; n < 4; ++n) acc[m][n] = (f32x4)(0.0f);
  gemm_core_b128(A_base + z * MS, BT_base + z * MS, As, Bs,
                 blockIdx.y * 128, blockIdx.x * 128, acc);
  __hip_bfloat16* C = C_base + z * MS;
  const int lane = threadIdx.x & 63, wv = threadIdx.x >> 6;
  const int g = lane >> 4, r16 = lane & 15, wm = wv >> 1, wn = wv & 1;
#pragma unroll
  for (int n = 0; n < 4; ++n) {
    const int col = blockIdx.x * 128 + wn * 64 + n * 16 + r16;
#pragma unroll
    for (int m = 0; m < 4; ++m) {
      const int rowb = blockIdx.y * 128 + wm * 64 + m * 16 + g * 4;
#pragma unroll
      for (int r = 0; r < 4; ++r)
        C[(size_t)(rowb + r) * 512 + col] = __float2bfloat16(acc[m][n][r]);
    }
  }
}

__global__ __launch_bounds__(256)
void bias_fuse_kernel(const float* __restrict__ loc_bo, const float* __restrict__ g_bo,
                      const float* __restrict__ out_w, const float* __restrict__ out_b,
                      float* __restrict__ bfused) {
  const int z = blockIdx.y;
  const int n = blockIdx.x * 256 + threadIdx.x;
  const float* bo = (z < 3) ? loc_bo + z * 512 : g_bo;
  bias_fuse_body(bo, out_w + (size_t)z * 512 * 512, z == 0 ? out_b : nullptr,
                 bfused + z * 512, n);
}

// =====================================================================
// Local attention body (R9-proven).
// =====================================================================
template <int W>
__device__ __forceinline__ const __hip_bfloat16* slot_row(
    const __hip_bfloat16* __restrict__ X, const __hip_bfloat16* __restrict__ biasb,
    int b, int tloc, int pg, int sl, int* ch_out) {
  constexpr int PAD = (W - 1) / 2;
  const int hloc = sl >> 3, p = sl & 7;
  const int m = (pg * 4 + hloc) * W + p;
  const int j = m >> 3;
  *ch_out = m & 7;
  int sr = tloc + j - PAD;
  if (p < W) {
    if (sr >= 0 && sr < T_SEQ) return X + ((size_t)(b * T_SEQ + sr) << 9);
    return biasb;
  }
  sr = sr < 0 ? 0 : (sr > T_SEQ - 1 ? T_SEQ - 1 : sr);
  return X + ((size_t)(b * T_SEQ + sr) << 9);
}

template <int W>
__device__ __forceinline__ void local_attn_body(
    int bx, const __hip_bfloat16* __restrict__ Xq, const __hip_bfloat16* __restrict__ Xk,
    const __hip_bfloat16* __restrict__ Xv, const __hip_bfloat16* __restrict__ bqb,
    const __hip_bfloat16* __restrict__ bkb, const __hip_bfloat16* __restrict__ bvb,
    __hip_bfloat16* __restrict__ abar, unsigned* pool) {
  const int tid = threadIdx.x;
  const int wv = tid >> 6, lane = tid & 63;
  const int bt = bx * 4 + wv;
  const int b = bt >> 10, tloc = bt & 1023;
  unsigned* L = pool + wv * 2048;
  const int dl = lane & 31, hi = lane >> 5;

  {
    const int k2 = dl, dhalf = hi;
    int ch0, ch1;
    const __hip_bfloat16* r0 =
        slot_row<W>(Xv, bvb, b, tloc, (2 * k2) >> 5, (2 * k2) & 31, &ch0);
    const __hip_bfloat16* r1 =
        slot_row<W>(Xv, bvb, b, tloc, (2 * k2 + 1) >> 5, (2 * k2 + 1) & 31, &ch1);
    u16x8 A0[4], A1[4];
#pragma unroll
    for (int q = 0; q < 4; ++q) {
      A0[q] = *(const u16x8*)(r0 + ch0 * 64 + dhalf * 32 + q * 8);
      A1[q] = *(const u16x8*)(r1 + ch1 * 64 + dhalf * 32 + q * 8);
    }
#pragma unroll
    for (int q = 0; q < 4; ++q)
#pragma unroll
      for (int e = 0; e < 8; ++e) {
        const int d_ = dhalf * 32 + q * 8 + e;
        const unsigned dw = (unsigned)A0[q][e] | ((unsigned)A1[q][e] << 16);
        const int byte = (d_ * 128 + k2 * 4) ^ ((d_ & 7) << 4);
        L[byte >> 2] = dw;
      }
  }

  f32x16 accP[2][2];
#pragma unroll
  for (int pg = 0; pg < 2; ++pg)
#pragma unroll
    for (int dh = 0; dh < 2; ++dh) accP[pg][dh] = (f32x16)(0.0f);

  const int myb = dl >> 3;

#pragma unroll
  for (int pg = 0; pg < 2; ++pg) {
    int chK, chQ;
    const __hip_bfloat16* rK = slot_row<W>(Xk, bkb, b, tloc, pg, dl, &chK);
    const __hip_bfloat16* rQ = slot_row<W>(Xq, bqb, b, tloc, pg, dl, &chQ);
    f32x16 sa = (f32x16)(0.0f);
#pragma unroll
    for (int i = 0; i < 4; ++i) {
      const bf16x8 kf = *(const bf16x8*)(rK + chK * 64 + i * 16 + hi * 8);
      const bf16x8 qf = *(const bf16x8*)(rQ + chQ * 64 + i * 16 + hi * 8);
      sa = __builtin_amdgcn_mfma_f32_32x32x16_bf16(kf, qf, sa, 0, 0, 0);
    }

    float sel[4];
#pragma unroll
    for (int r4 = 0; r4 < 4; ++r4)
      sel[r4] = (myb == 0) ? sa[r4]
              : (myb == 1) ? sa[4 + r4]
              : (myb == 2) ? sa[8 + r4] : sa[12 + r4];

    float mx = -3e38f;
#pragma unroll
    for (int r4 = 0; r4 < 4; ++r4)
      if (r4 + 4 * hi < W) mx = fmaxf(mx, sel[r4]);
    mx = fmaxf(mx, __shfl_xor(mx, 32));
    float e[4], ls = 0.f;
#pragma unroll
    for (int r4 = 0; r4 < 4; ++r4) {
      e[r4] = (r4 + 4 * hi < W) ? __expf(0.125f * (sel[r4] - mx)) : 0.f;
      ls += e[r4];
    }
    ls += __shfl_xor(ls, 32);
    const float inv = 1.f / ls;

    unsigned dw0, dw1;
    CVTPK(dw0, e[0] * inv, e[1] * inv);
    CVTPK(dw1, e[2] * inv, e[3] * inv);
    const unsigned q0 = __shfl_xor(dw0, 32);
    const unsigned q1 = __shfl_xor(dw1, 32);

#pragma unroll
    for (int kh = 0; kh < 2; ++kh) {
      const bool on = (2 * kh + hi) == myb;
      u32x4 bw;
      if (hi == 0) { bw[0] = dw0; bw[1] = dw1; bw[2] = q0; bw[3] = q1; }
      else         { bw[0] = q0;  bw[1] = q1;  bw[2] = dw0; bw[3] = dw1; }
      if (!on) { bw[0] = 0u; bw[1] = 0u; bw[2] = 0u; bw[3] = 0u; }
      const bf16x8 pf = __builtin_bit_cast(bf16x8, bw);
#pragma unroll
      for (int dh = 0; dh < 2; ++dh) {
        const int d_ = dh * 32 + dl;
        const int off = (d_ * 128 + pg * 64 + kh * 32 + hi * 16) ^ ((d_ & 7) << 4);
        const bf16x8 va =
            __builtin_bit_cast(bf16x8, *(const u32x4*)((const char*)L + off));
        accP[pg][dh] = __builtin_amdgcn_mfma_f32_32x32x16_bf16(va, pf, accP[pg][dh], 0, 0, 0);
      }
    }
  }

#pragma unroll
  for (int pg = 0; pg < 2; ++pg) {
    if ((dl & 7) < W) {
      const int m_o = (pg * 4 + (dl >> 3)) * W + (dl & 7);
#pragma unroll
      for (int dh = 0; dh < 2; ++dh) {
#pragma unroll
        for (int rq = 0; rq < 4; ++rq) {
          unsigned wa, wb;
          CVTPK(wa, accP[pg][dh][4 * rq + 0], accP[pg][dh][4 * rq + 1]);
          CVTPK(wb, accP[pg][dh][4 * rq + 2], accP[pg][dh][4 * rq + 3]);
          const int dwi = m_o * 34 + dh * 16 + rq * 4 + hi * 2;
          uint2 w; w.x = wa; w.y = wb;
          *(uint2*)(L + dwi) = w;
        }
      }
    }
  }
  asm volatile("s_waitcnt lgkmcnt(0)" ::: "memory");

  const int cho = lane >> 3, fb = lane & 7;
  float o[8] = {0.f, 0.f, 0.f, 0.f, 0.f, 0.f, 0.f, 0.f};
#pragma unroll
  for (int jj = 0; jj < W; ++jj) {
    const int mo = 8 * jj + cho;
    const uint2 w0 = *(const uint2*)(L + mo * 34 + fb * 4);
    const uint2 w1 = *(const uint2*)(L + mo * 34 + fb * 4 + 2);
    o[0] += bf2f((unsigned short)(w0.x & 0xffff));
    o[1] += bf2f((unsigned short)(w0.x >> 16));
    o[2] += bf2f((unsigned short)(w0.y & 0xffff));
    o[3] += bf2f((unsigned short)(w0.y >> 16));
    o[4] += bf2f((unsigned short)(w1.x & 0xffff));
    o[5] += bf2f((unsigned short)(w1.x >> 16));
    o[6] += bf2f((unsigned short)(w1.y & 0xffff));
    o[7] += bf2f((unsigned short)(w1.y >> 16));
  }
  const float invw = 1.f / (float)W;
  u16x8 ov;
#pragma unroll
  for (int e2 = 0; e2 < 8; ++e2) ov[e2] = f2bf(o[e2] * invw);
  *(u16x8*)(abar + ((size_t)bt << 9) + cho * 64 + fb * 8) = ov;
}

// Wrapper: __launch_bounds__(256, 4) forces VGPR <= 128 (was 132, just
// past the m69 occupancy cliff) -> 4 waves/SIMD for this latency-bound
// kernel. XCD-chunked swizzle kept.
template <int W>
__global__ __launch_bounds__(256, 4)
void local_attn_mfma_kernel(const __hip_bfloat16* __restrict__ Xq,
                            const __hip_bfloat16* __restrict__ Xk,
                            const __hip_bfloat16* __restrict__ Xv,
                            const __hip_bfloat16* __restrict__ bqb,
                            const __hip_bfloat16* __restrict__ bkb,
                            const __hip_bfloat16* __restrict__ bvb,
                            __hip_bfloat16* __restrict__ abar) {
  __shared__ __attribute__((aligned(16))) unsigned pool[8192];
  const int bx = (blockIdx.x & 7) * 256 + (blockIdx.x >> 3);
  local_attn_body<W>(bx, Xq, Xk, Xv, bqb, bkb, bvb, abar, pool);
}

// =====================================================================
// Global attention body (R9-proven, 54us).
// =====================================================================
#define REDIST(pb, kb_)                                                  \
    {                                                                    \
      unsigned t0_, t1_, t2_, t3_, t4_, t5_, t6_, t7_;                   \
      CVTPK(t0_, pb[0], pb[1]);   CVTPK(t1_, pb[2], pb[3]);              \
      CVTPK(t2_, pb[4], pb[5]);   CVTPK(t3_, pb[6], pb[7]);              \
      CVTPK(t4_, pb[8], pb[9]);   CVTPK(t5_, pb[10], pb[11]);            \
      CVTPK(t6_, pb[12], pb[13]); CVTPK(t7_, pb[14], pb[15]);            \
      swap32(t0_, t2_, lane); swap32(t1_, t3_, lane);                    \
      swap32(t4_, t6_, lane); swap32(t5_, t7_, lane);                    \
      bw[kb_][0][0] = t0_; bw[kb_][0][1] = t1_; bw[kb_][0][2] = t2_;     \
      bw[kb_][0][3] = t3_;                                               \
      bw[kb_][1][0] = t4_; bw[kb_][1][1] = t5_; bw[kb_][1][2] = t6_;     \
      bw[kb_][1][3] = t7_;                                               \
    }

__device__ __forceinline__ void global_attn_body(
    int qblk, int bh, const __hip_bfloat16* __restrict__ Xq,
    const __hip_bfloat16* __restrict__ Xk, const __hip_bfloat16* __restrict__ Xv,
    __hip_bfloat16* __restrict__ att, unsigned* pool) {
  const int tid = threadIdx.x;
  const int lane = tid & 63;
  const int wv = tid >> 6;
  const size_t base = (size_t)bh << 16;
  const int c = lane & 31;
  const int g = lane >> 5;
  const int q0 = qblk * 128 + wv * 32;

  const __hip_bfloat16* Qp = Xq + base;
  const __hip_bfloat16* Kp = Xk + base;
  const __hip_bfloat16* Vp = Xv + base;

  bf16x8 qf[4];
#pragma unroll
  for (int s = 0; s < 4; ++s)
    qf[s] = *(const bf16x8*)(Qp + (size_t)(q0 + c) * 64 + s * 16 + g * 8);

  const int k2 = tid & 31, dblk = tid >> 5;

  bf16x8 kf[2][4];
  u16x8 v0, v1, v0n, v1n;

  v0 = *(const u16x8*)(Vp + (size_t)(2 * k2) * 64 + dblk * 8);
  v1 = *(const u16x8*)(Vp + (size_t)(2 * k2 + 1) * 64 + dblk * 8);
#pragma unroll
  for (int kb = 0; kb < 2; ++kb)
#pragma unroll
    for (int s = 0; s < 4; ++s)
      kf[kb][s] = *(const bf16x8*)(Kp + (size_t)(kb * 32 + c) * 64 + s * 16 + g * 8);

  f32x16 Oa = (f32x16)(0.0f), Ob = (f32x16)(0.0f);
  float m_run = -3e38f, l_run = 0.f;

  for (int kt = 0; kt < 16; ++kt) {
    unsigned* vb = pool + (kt & 1) * 2048;
#pragma unroll
    for (int jj = 0; jj < 8; ++jj) {
      const int d = dblk * 8 + jj;
      const unsigned dw = (unsigned)v0[jj] | ((unsigned)v1[jj] << 16);
      const int byte = (d * 128 + k2 * 4) ^ ((d & 7) << 4);
      vb[byte >> 2] = dw;
    }
    if (kt < 15) {
      const __hip_bfloat16* vsrc = Vp + (size_t)((kt + 1) * 64 + 2 * k2) * 64 + dblk * 8;
      v0n = *(const u16x8*)vsrc;
      v1n = *(const u16x8*)(vsrc + 64);
    }
    __syncthreads();

    f32x16 sa = (f32x16)(0.0f), sb = (f32x16)(0.0f);
#pragma unroll
    for (int s = 0; s < 4; ++s)
      sa = __builtin_amdgcn_mfma_f32_32x32x16_bf16(kf[0][s], qf[s], sa, 0, 0, 0);
#pragma unroll
    for (int s = 0; s < 4; ++s)
      sb = __builtin_amdgcn_mfma_f32_32x32x16_bf16(kf[1][s], qf[s], sb, 0, 0, 0);

    if (kt < 15) {
#pragma unroll
      for (int kb = 0; kb < 2; ++kb)
#pragma unroll
        for (int s = 0; s < 4; ++s)
          kf[kb][s] = *(const bf16x8*)(Kp + (size_t)((kt + 1) * 64 + kb * 32 + c) * 64 +
                                       s * 16 + g * 8);
    }

    float mx = sa[0];
#pragma unroll
    for (int r = 1; r < 16; ++r) mx = fmaxf(mx, sa[r]);
#pragma unroll
    for (int r = 0; r < 16; ++r) mx = fmaxf(mx, sb[r]);
    mx = fmaxf(mx, __shfl_xor(mx, 32));
    const float m_new = fmaxf(m_run, mx * 0.125f);
    const float alpha = __expf(m_run - m_new);

    float p0[16], p1[16];
    float lsum = 0.f;
#pragma unroll
    for (int r = 0; r < 16; ++r) { p0[r] = __expf(fmaf(sa[r], 0.125f, -m_new)); lsum += p0[r]; }
#pragma unroll
    for (int r = 0; r < 16; ++r) { p1[r] = __expf(fmaf(sb[r], 0.125f, -m_new)); lsum += p1[r]; }
    lsum += __shfl_xor(lsum, 32);
    l_run = fmaf(l_run, alpha, lsum);
    m_run = m_new;
#pragma unroll
    for (int r = 0; r < 16; ++r) { Oa[r] *= alpha; Ob[r] *= alpha; }

    unsigned bw[2][2][4];
    REDIST(p0, 0)
    REDIST(p1, 1)

    const unsigned* vbr = pool + (kt & 1) * 2048;
#pragma unroll
    for (int kb = 0; kb < 2; ++kb)
#pragma unroll
      for (int st = 0; st < 2; ++st) {
        const u32x4 pw = { bw[kb][st][0], bw[kb][st][1], bw[kb][st][2], bw[kb][st][3] };
        const bf16x8 pf = __builtin_bit_cast(bf16x8, pw);
        {
          const int row = c;
          const int off = (row * 128 + (kb * 64 + st * 32 + g * 16)) ^ ((row & 7) << 4);
          const bf16x8 va = __builtin_bit_cast(bf16x8, *(const u32x4*)((const char*)vbr + off));
          Oa = __builtin_amdgcn_mfma_f32_32x32x16_bf16(va, pf, Oa, 0, 0, 0);
        }
        {
          const int row = 32 + c;
          const int off = (row * 128 + (kb * 64 + st * 32 + g * 16)) ^ ((row & 7) << 4);
          const bf16x8 va = __builtin_bit_cast(bf16x8, *(const u32x4*)((const char*)vbr + off));
          Ob = __builtin_amdgcn_mfma_f32_32x32x16_bf16(va, pf, Ob, 0, 0, 0);
        }
      }

    v0 = v0n; v1 = v1n;
  }

  const float inv = 1.f / l_run;
  __hip_bfloat16* drow = att + base + (size_t)(q0 + c) * 64;
#pragma unroll
  for (int qd = 0; qd < 4; ++qd) {
    unsigned lo, hi2;
    {
      const float a0 = Oa[4 * qd + 0] * inv, a1 = Oa[4 * qd + 1] * inv;
      const float a2 = Oa[4 * qd + 2] * inv, a3 = Oa[4 * qd + 3] * inv;
      CVTPK(lo, a0, a1); CVTPK(hi2, a2, a3);
      uint2 w; w.x = lo; w.y = hi2;
      *(uint2*)(drow + 8 * qd + 4 * g) = w;
    }
    {
      const float a0 = Ob[4 * qd + 0] * inv, a1 = Ob[4 * qd + 1] * inv;
      const float a2 = Ob[4 * qd + 2] * inv, a3 = Ob[4 * qd + 3] * inv;
      CVTPK(lo, a0, a1); CVTPK(hi2, a2, a3);
      uint2 w; w.x = lo; w.y = hi2;
      *(uint2*)(drow + 32 + 8 * qd + 4 * g) = w;
    }
  }
}

// Grid (64,8): XCD = bh & 7 -> all q-blocks of one head on one XCD.
__global__ __launch_bounds__(256)
void global_attn_mfma_kernel(const __hip_bfloat16* __restrict__ Xq,
                             const __hip_bfloat16* __restrict__ Xk,
                             const __hip_bfloat16* __restrict__ Xv,
                             __hip_bfloat16* __restrict__ att) {
  __shared__ __attribute__((aligned(16))) unsigned pool[4096];
  global_attn_body(blockIdx.y, blockIdx.x, Xq, Xk, Xv, att, pool);
}

// =====================================================================
// Final fused output GEMM (BM=64, grid (4,128)) — proven.
// =====================================================================
__global__ __launch_bounds__(256)
void gemm_out_fused_kernel(const __hip_bfloat16* __restrict__ A0,
                           const __hip_bfloat16* __restrict__ A1,
                           const __hip_bfloat16* __restrict__ A2,
                           const __hip_bfloat16* __restrict__ A3,
                           const __hip_bfloat16* __restrict__ WT_base,
                           const float* __restrict__ bfused,
                           float* __restrict__ out) {
  __shared__ __attribute__((aligned(16))) __hip_bfloat16 As[2048];
  __shared__ __attribute__((aligned(16))) __hip_bfloat16 Bs[4096];
  const size_t MS = (size_t)512 * 512;
  const int row0 = blockIdx.y * 64, col0 = blockIdx.x * 128;
  f32x4 acc[2][4];
#pragma unroll
  for (int m = 0; m < 2; ++m)
#pragma unroll
    for (int n = 0; n < 4; ++n) acc[m][n] = (f32x4)(0.0f);
  const __hip_bfloat16* Az[4] = {A0, A1, A2, A3};
  for (int z = 0; z < 4; ++z)
    gemm_core_b64(Az[z], WT_base + (size_t)z * MS, As, Bs, row0, col0, acc);
  const int lane = threadIdx.x & 63, wv = threadIdx.x >> 6;
  const int g = lane >> 4, r16 = lane & 15, wm = wv >> 1, wn = wv & 1;
#pragma unroll
  for (int n = 0; n < 4; ++n) {
    const int col = col0 + wn * 64 + n * 16 + r16;
    const float bn = bfused[col] + bfused[512 + col] + bfused[1024 + col] +
                     bfused[1536 + col];
#pragma unroll
    for (int m = 0; m < 2; ++m) {
      const int rowb = row0 + wm * 32 + m * 16 + g * 4;
#pragma unroll
      for (int r = 0; r < 4; ++r)
        out[(size_t)(rowb + r) * 512 + col] = acc[m][n][r] + bn;
    }
  }
}

// =====================================================================
// Launch
// =====================================================================
extern "C" void kernel_launch(void* const* d_in, const int* in_sizes, int n_in,
                              void* d_out, int out_size, void* d_ws, size_t ws_size,
                              hipStream_t stream) {
  const float* x      = (const float*)d_in[0];
  const float* loc_wq = (const float*)d_in[1];
  const float* loc_bq = (const float*)d_in[2];
  const float* loc_wk = (const float*)d_in[3];
  const float* loc_bk = (const float*)d_in[4];
  const float* loc_wv = (const float*)d_in[5];
  const float* loc_bv = (const float*)d_in[6];
  const float* loc_wo = (const float*)d_in[7];
  const float* loc_bo = (const float*)d_in[8];
  const float* g_wq  = (const float*)d_in[9];
  const float* g_bq  = (const float*)d_in[10];
  const float* g_wk  = (const float*)d_in[11];
  const float* g_bk  = (const float*)d_in[12];
  const float* g_wv  = (const float*)d_in[13];
  const float* g_bv  = (const float*)d_in[14];
  const float* g_wo  = (const float*)d_in[15];
  const float* g_bo  = (const float*)d_in[16];
  const float* out_w = (const float*)d_in[17];
  const float* out_b = (const float*)d_in[18];
  float* out = (float*)d_out;

  __hip_bfloat16* wsb = (__hip_bfloat16*)d_ws;
  const size_t SZ = (size_t)8192 * 512;
  const size_t MS = (size_t)512 * 512;

  __hip_bfloat16* xb    = wsb;
  __hip_bfloat16* WT    = wsb + SZ;
  float* bfused = (float*)(wsb + SZ + 24 * MS);
  __hip_bfloat16* bqkvb = wsb + SZ + 24 * MS + 4096;
  __hip_bfloat16* proj  = wsb + SZ + 24 * MS + 16384;

  const size_t need_big = 2 * (17 * SZ + 24 * MS + 16384);
  const bool big = ws_size >= need_big;

  const dim3 thr(256);

  prep_weights_kernel<<<dim3(256, 22), thr, 0, stream>>>(
      loc_wq, loc_wk, loc_wv, g_wq, g_wk, g_wv, out_w, loc_wo, g_wo,
      x, loc_bq, loc_bk, loc_bv, WT, xb, bqkvb);

  __hip_bfloat16 *abar0, *abar1, *abar2, *abar3;

  if (big) {
    abar0 = proj + 12 * SZ;
    abar1 = proj + 13 * SZ;
    abar2 = proj + 14 * SZ;
    abar3 = proj + 15 * SZ;
    // qkv x12 + fusew + bias-fuse in one homogeneous GEMM dispatch
    gemm_qkv_all_kernel<<<dim3(4, 64, 13), thr, 0, stream>>>(
        xb, WT, loc_bq, loc_bk, loc_bv, g_bq, g_bk, g_bv,
        loc_bo, g_bo, out_w, out_b, proj, bfused);
    local_attn_mfma_kernel<3><<<2048, thr, 0, stream>>>(
        proj + 0 * SZ, proj + 3 * SZ, proj + 6 * SZ,
        bqkvb + 0 * 512, bqkvb + 1 * 512, bqkvb + 2 * 512, abar0);
    local_attn_mfma_kernel<5><<<2048, thr, 0, stream>>>(
        proj + 1 * SZ, proj + 4 * SZ, proj + 7 * SZ,
        bqkvb + 3 * 512, bqkvb + 4 * 512, bqkvb + 5 * 512, abar1);
    local_attn_mfma_kernel<7><<<2048, thr, 0, stream>>>(
        proj + 2 * SZ, proj + 5 * SZ, proj + 8 * SZ,
        bqkvb + 6 * 512, bqkvb + 7 * 512, bqkvb + 8 * 512, abar2);
    global_attn_mfma_kernel<<<dim3(64, 8), thr, 0, stream>>>(
        proj + 9 * SZ, proj + 10 * SZ, proj + 11 * SZ, abar3);
  } else {
    gemm_fusew_kernel<<<dim3(4, 4, 4), thr, 0, stream>>>(WT + 12 * MS, WT + 16 * MS,
                                                         WT + 20 * MS);
    bias_fuse_kernel<<<dim3(2, 4), thr, 0, stream>>>(loc_bo, g_bo, out_w, out_b, bfused);
    __hip_bfloat16* Xq = proj;
    __hip_bfloat16* Xk = proj + SZ;
    __hip_bfloat16* Xv = proj + 2 * SZ;
    abar0 = proj + 3 * SZ;
    abar1 = proj + 4 * SZ;
    abar2 = proj + 5 * SZ;
    abar3 = proj + 6 * SZ;
    __hip_bfloat16* abars[3] = {abar0, abar1, abar2};
    const dim3 gqkv(4, 64, 3);
    for (int lv = 0; lv < 3; ++lv) {
      gemm_qkv_kernel<<<gqkv, thr, 0, stream>>>(
          xb, WT + lv * MS, 3 * MS,
          loc_bq + lv * 512, loc_bk + lv * 512, loc_bv + lv * 512, Xq);
      const __hip_bfloat16* bqb = bqkvb + (lv * 3 + 0) * 512;
      const __hip_bfloat16* bkb = bqkvb + (lv * 3 + 1) * 512;
      const __hip_bfloat16* bvb = bqkvb + (lv * 3 + 2) * 512;
      if (lv == 0)
        local_attn_mfma_kernel<3><<<2048, thr, 0, stream>>>(Xq, Xk, Xv, bqb, bkb, bvb, abars[lv]);
      else if (lv == 1)
        local_attn_mfma_kernel<5><<<2048, thr, 0, stream>>>(Xq, Xk, Xv, bqb, bkb, bvb, abars[lv]);
      else
        local_attn_mfma_kernel<7><<<2048, thr, 0, stream>>>(Xq, Xk, Xv, bqb, bkb, bvb, abars[lv]);
    }
    gemm_qkv_kernel<<<gqkv, thr, 0, stream>>>(xb, WT + 9 * MS, MS, g_bq, g_bk, g_bv, Xq);
    global_attn_mfma_kernel<<<dim3(64, 8), thr, 0, stream>>>(Xq, Xk, Xv, abar3);
  }

  gemm_out_fused_kernel<<<dim3(4, 128), thr, 0, stream>>>(abar0, abar1, abar2, abar3,
                                                          WT + 20 * MS, bfused, out);
}

// Round 14
// 256.646 us; speedup vs baseline: 1.1972x; 1.0030x over previous
//
#include <hip/hip_runtime.h>
#include <hip/hip_bf16.h>
#include <cstddef>

#define T_SEQ 1024
#define D_MODEL 512

typedef __attribute__((ext_vector_type(8))) __bf16 bf16x8;
typedef __attribute__((ext_vector_type(4))) float f32x4;
typedef __attribute__((ext_vector_type(16))) float f32x16;
typedef __attribute__((ext_vector_type(8))) unsigned short u16x8;
typedef __attribute__((ext_vector_type(4))) unsigned int u32x4;

typedef const unsigned int __attribute__((address_space(1)))* gas1_t;
typedef unsigned int __attribute__((address_space(3)))* las3_t;

__device__ __forceinline__ void gload_lds16(const void* g, void* l) {
  __builtin_amdgcn_global_load_lds((gas1_t)g, (las3_t)l, 16, 0, 0);
}

__device__ __forceinline__ float bf2f(unsigned short u) {
  return __uint_as_float(((unsigned)u) << 16);
}
__device__ __forceinline__ unsigned short f2bf(float f) {
  __hip_bfloat16 h = __float2bfloat16(f);
  return *(unsigned short*)&h;
}

#define CVTPK(dst, a, b) \
  asm("v_cvt_pk_bf16_f32 %0, %1, %2" : "=v"(dst) : "v"(a), "v"(b))

__device__ __forceinline__ void swap32(unsigned& a, unsigned& b, int lane) {
  const unsigned ax = __shfl_xor(a, 32);
  const unsigned bx = __shfl_xor(b, 32);
  const bool lo = lane < 32;
  const unsigned na = lo ? a : bx;
  const unsigned nb = lo ? ax : b;
  a = na; b = nb;
}

// =====================================================================
// Prep (proven): 22 z-slices of weight transpose/cast + x cast + bias.
// =====================================================================
__global__ __launch_bounds__(256)
void prep_weights_kernel(const float* __restrict__ loc_wq, const float* __restrict__ loc_wk,
                         const float* __restrict__ loc_wv, const float* __restrict__ g_wq,
                         const float* __restrict__ g_wk, const float* __restrict__ g_wv,
                         const float* __restrict__ out_w, const float* __restrict__ loc_wo,
                         const float* __restrict__ g_wo, const float* __restrict__ x,
                         const float* __restrict__ loc_bq, const float* __restrict__ loc_bk,
                         const float* __restrict__ loc_bv,
                         __hip_bfloat16* __restrict__ WT, __hip_bfloat16* __restrict__ xb,
                         __hip_bfloat16* __restrict__ bqkvb) {
  __shared__ float tile[32][33];
  const size_t MS = (size_t)512 * 512;
  const int z = blockIdx.y;
  const int t = threadIdx.x;

  if (z == 20) {
    const int base = blockIdx.x * 16384 + t * 8;
#pragma unroll
    for (int it = 0; it < 8; ++it) {
      const int i = base + it * 2048;
      const float4 a = *(const float4*)(x + i);
      const float4 b = *(const float4*)(x + i + 4);
      u16x8 o;
      o[0] = f2bf(a.x); o[1] = f2bf(a.y); o[2] = f2bf(a.z); o[3] = f2bf(a.w);
      o[4] = f2bf(b.x); o[5] = f2bf(b.y); o[6] = f2bf(b.z); o[7] = f2bf(b.w);
      *(u16x8*)(xb + i) = o;
    }
    return;
  }
  if (z == 21) {
    const int i = blockIdx.x * 256 + t;
    if (blockIdx.x < 18) {
      const int which = i >> 9, lv = which / 3, role = which % 3, e = i & 511;
      const float* src = role == 0 ? loc_bq : role == 1 ? loc_bk : loc_bv;
      bqkvb[i] = __float2bfloat16(src[lv * 512 + e]);
    }
    return;
  }

  const float* src;
  bool tr = true;
  if (z < 3)       src = loc_wq + (size_t)z * MS;
  else if (z < 6)  src = loc_wk + (size_t)(z - 3) * MS;
  else if (z < 9)  src = loc_wv + (size_t)(z - 6) * MS;
  else if (z == 9)  src = g_wq;
  else if (z == 10) src = g_wk;
  else if (z == 11) src = g_wv;
  else if (z < 16) src = out_w + (size_t)(z - 12) * MS;
  else if (z < 19) { src = loc_wo + (size_t)(z - 16) * MS; tr = false; }
  else             { src = g_wo; tr = false; }
  __hip_bfloat16* dst = WT + (size_t)z * MS;

  const int tk = (blockIdx.x & 15) * 32;
  const int tn = (blockIdx.x >> 4) * 32;
  const int r = t >> 3, c4 = (t & 7) * 4;
  const float4 v = *(const float4*)(src + (size_t)(tk + r) * 512 + tn + c4);
  if (tr) {
    tile[r][c4 + 0] = v.x; tile[r][c4 + 1] = v.y;
    tile[r][c4 + 2] = v.z; tile[r][c4 + 3] = v.w;
    __syncthreads();
    ushort4 o;
    o.x = f2bf(tile[c4 + 0][r]); o.y = f2bf(tile[c4 + 1][r]);
    o.z = f2bf(tile[c4 + 2][r]); o.w = f2bf(tile[c4 + 3][r]);
    *(ushort4*)(dst + (size_t)(tn + r) * 512 + tk + c4) = o;
  } else {
    ushort4 o;
    o.x = f2bf(v.x); o.y = f2bf(v.y); o.z = f2bf(v.z); o.w = f2bf(v.w);
    *(ushort4*)(dst + (size_t)(tk + r) * 512 + tn + c4) = o;
  }
}

// =====================================================================
// GEMM cores (proven).
// =====================================================================
__device__ __forceinline__ void gemm_core_b128(
    const __hip_bfloat16* __restrict__ A, const __hip_bfloat16* __restrict__ BT,
    __hip_bfloat16* As, __hip_bfloat16* Bs, int row0, int col0, f32x4 acc[4][4]) {
  const int tid = threadIdx.x;
  const int wv = tid >> 6, lane = tid & 63;
  const int g = lane >> 4, r16 = lane & 15;
  const int wm = wv >> 1, wn = wv & 1;
  const char* Ab = (const char*)A;
  const char* Bb = (const char*)BT;
  for (int k0 = 0; k0 < 512; k0 += 32) {
    {
      const int row = tid >> 2, off = (tid & 3) << 4;
      gload_lds16(Ab + (size_t)(row0 + row) * 1024 + k0 * 2 + off,
                  (char*)As + (wv << 10));
      const int i2 = tid + 256;
      const int row2 = i2 >> 2, off2 = (i2 & 3) << 4;
      gload_lds16(Ab + (size_t)(row0 + row2) * 1024 + k0 * 2 + off2,
                  (char*)As + 4096 + (wv << 10));
    }
    {
      const int row = tid >> 2, off = (tid & 3) << 4;
      gload_lds16(Bb + (size_t)(col0 + row) * 1024 + k0 * 2 + off,
                  (char*)Bs + (wv << 10));
      const int i2 = tid + 256;
      const int row2 = i2 >> 2, off2 = (i2 & 3) << 4;
      gload_lds16(Bb + (size_t)(col0 + row2) * 1024 + k0 * 2 + off2,
                  (char*)Bs + 4096 + (wv << 10));
    }
    __syncthreads();
    bf16x8 a[4], b[4];
#pragma unroll
    for (int m = 0; m < 4; ++m)
      a[m] = *(const bf16x8*)(As + (wm * 64 + m * 16 + r16) * 32 + g * 8);
#pragma unroll
    for (int n = 0; n < 4; ++n)
      b[n] = *(const bf16x8*)(Bs + (wn * 64 + n * 16 + r16) * 32 + g * 8);
#pragma unroll
    for (int m = 0; m < 4; ++m)
#pragma unroll
      for (int n = 0; n < 4; ++n)
        acc[m][n] = __builtin_amdgcn_mfma_f32_16x16x32_bf16(a[m], b[n], acc[m][n], 0, 0, 0);
    __syncthreads();
  }
}

__device__ __forceinline__ void gemm_core_b64(
    const __hip_bfloat16* __restrict__ A, const __hip_bfloat16* __restrict__ BT,
    __hip_bfloat16* As, __hip_bfloat16* Bs, int row0, int col0, f32x4 acc[2][4]) {
  const int tid = threadIdx.x;
  const int wv = tid >> 6, lane = tid & 63;
  const int g = lane >> 4, r16 = lane & 15;
  const int wm = wv >> 1, wn = wv & 1;
  const char* Ab = (const char*)A;
  const char* Bb = (const char*)BT;
  for (int k0 = 0; k0 < 512; k0 += 32) {
    {
      const int row = tid >> 2, off = (tid & 3) << 4;
      gload_lds16(Ab + (size_t)(row0 + row) * 1024 + k0 * 2 + off,
                  (char*)As + (wv << 10));
    }
    {
      const int row = tid >> 2, off = (tid & 3) << 4;
      gload_lds16(Bb + (size_t)(col0 + row) * 1024 + k0 * 2 + off,
                  (char*)Bs + (wv << 10));
      const int i2 = tid + 256;
      const int row2 = i2 >> 2, off2 = (i2 & 3) << 4;
      gload_lds16(Bb + (size_t)(col0 + row2) * 1024 + k0 * 2 + off2,
                  (char*)Bs + 4096 + (wv << 10));
    }
    __syncthreads();
    bf16x8 a[2], b[4];
#pragma unroll
    for (int m = 0; m < 2; ++m)
      a[m] = *(const bf16x8*)(As + (wm * 32 + m * 16 + r16) * 32 + g * 8);
#pragma unroll
    for (int n = 0; n < 4; ++n)
      b[n] = *(const bf16x8*)(Bs + (wn * 64 + n * 16 + r16) * 32 + g * 8);
#pragma unroll
    for (int m = 0; m < 2; ++m)
#pragma unroll
      for (int n = 0; n < 4; ++n)
        acc[m][n] = __builtin_amdgcn_mfma_f32_16x16x32_bf16(a[m], b[n], acc[m][n], 0, 0, 0);
    __syncthreads();
  }
}

// bf16 C = A@W^T + bias (one 128x128 tile)
__device__ __forceinline__ void gemm_bias_body(
    const __hip_bfloat16* __restrict__ A, const __hip_bfloat16* __restrict__ WT,
    const float* __restrict__ bias, __hip_bfloat16* __restrict__ C,
    int row0, int col0, __hip_bfloat16* As, __hip_bfloat16* Bs) {
  f32x4 acc[4][4];
#pragma unroll
  for (int m = 0; m < 4; ++m)
#pragma unroll
    for (int n = 0; n < 4; ++n) acc[m][n] = (f32x4)(0.0f);
  gemm_core_b128(A, WT, As, Bs, row0, col0, acc);
  const int lane = threadIdx.x & 63, wv = threadIdx.x >> 6;
  const int g = lane >> 4, r16 = lane & 15, wm = wv >> 1, wn = wv & 1;
#pragma unroll
  for (int n = 0; n < 4; ++n) {
    const int col = col0 + wn * 64 + n * 16 + r16;
    const float bn = bias ? bias[col] : 0.f;
#pragma unroll
    for (int m = 0; m < 4; ++m) {
      const int rowb = row0 + wm * 64 + m * 16 + g * 4;
#pragma unroll
      for (int r = 0; r < 4; ++r)
        C[(size_t)(rowb + r) * 512 + col] = __float2bfloat16(acc[m][n][r] + bn);
    }
  }
}

__device__ __forceinline__ void bias_fuse_body(
    const float* __restrict__ bo, const float* __restrict__ W,
    const float* __restrict__ add, float* __restrict__ bfz, int n) {
  float acc = add ? add[n] : 0.f;
  for (int m = 0; m < 512; ++m)
    acc = fmaf(bo[m], W[(size_t)m * 512 + n], acc);
  bfz[n] = acc;
}

// =====================================================================
// Mega Q/K/V + folded fusew/bias-fuse. z = 0..11: projections (proven
// R10 body). z == 12: homogeneous extras — (y&12)==0: fusew tile
// (WfT[wz] = (wo_wz @ outw_wz)^T, wz=y>>4, row=y&3, col=x);
// (y&15)==4|5: bias-fuse half. Other blocks exit immediately.
// =====================================================================
__global__ __launch_bounds__(256)
void gemm_qkv_all_kernel(const __hip_bfloat16* __restrict__ A,
                         const __hip_bfloat16* __restrict__ WT_base,
                         const float* __restrict__ loc_bq, const float* __restrict__ loc_bk,
                         const float* __restrict__ loc_bv, const float* __restrict__ g_bq,
                         const float* __restrict__ g_bk, const float* __restrict__ g_bv,
                         const float* __restrict__ loc_bo, const float* __restrict__ g_bo,
                         const float* __restrict__ out_w, const float* __restrict__ out_b,
                         __hip_bfloat16* __restrict__ proj_base,
                         float* __restrict__ bfused) {
  __shared__ __attribute__((aligned(16))) __hip_bfloat16 As[4096];
  __shared__ __attribute__((aligned(16))) __hip_bfloat16 Bs[4096];
  const size_t MS = (size_t)512 * 512;
  const int z = blockIdx.z;

  if (z == 12) {
    const int y = blockIdx.y;
    if ((y & 12) == 0) {
      // fusew: 64 blocks
      const int wz = y >> 4, row = y & 3, col = blockIdx.x;
      f32x4 acc[4][4];
#pragma unroll
      for (int m = 0; m < 4; ++m)
#pragma unroll
        for (int n = 0; n < 4; ++n) acc[m][n] = (f32x4)(0.0f);
      gemm_core_b128(WT_base + (size_t)(12 + wz) * MS, WT_base + (size_t)(16 + wz) * MS,
                     As, Bs, row * 128, col * 128, acc);
      __hip_bfloat16* C = (__hip_bfloat16*)(WT_base + (size_t)(20 + wz) * MS);
      const int lane = threadIdx.x & 63, wv = threadIdx.x >> 6;
      const int g = lane >> 4, r16 = lane & 15, wm = wv >> 1, wn = wv & 1;
#pragma unroll
      for (int n = 0; n < 4; ++n) {
        const int cc = col * 128 + wn * 64 + n * 16 + r16;
#pragma unroll
        for (int m = 0; m < 4; ++m) {
          const int rowb = row * 128 + wm * 64 + m * 16 + g * 4;
#pragma unroll
          for (int r = 0; r < 4; ++r)
            C[(size_t)(rowb + r) * 512 + cc] = __float2bfloat16(acc[m][n][r]);
        }
      }
    } else if (((y & 15) == 4 || (y & 15) == 5) && blockIdx.x == 0) {
      // bias fuse: 8 blocks
      const int wz = y >> 4, half = y & 1;
      const int n = half * 256 + threadIdx.x;
      const float* bo = (wz < 3) ? loc_bo + wz * 512 : g_bo;
      bias_fuse_body(bo, out_w + (size_t)wz * MS, wz == 0 ? out_b : nullptr,
                     bfused + wz * 512, n);
    }
    return;
  }

  const float* bias;
  if (z < 3)       bias = loc_bq + z * 512;
  else if (z < 6)  bias = loc_bk + (z - 3) * 512;
  else if (z < 9)  bias = loc_bv + (z - 6) * 512;
  else             bias = (z == 9) ? g_bq : (z == 10) ? g_bk : g_bv;
  gemm_bias_body(A, WT_base + (size_t)z * MS, bias,
                 proj_base + (size_t)z * (size_t)(8192 * 512),
                 blockIdx.y * 128, blockIdx.x * 128, As, Bs);
}

// Fallback per-level Q/K/V projection.
__global__ __launch_bounds__(256)
void gemm_qkv_kernel(const __hip_bfloat16* __restrict__ A,
                     const __hip_bfloat16* __restrict__ WT_base, size_t wt_stride,
                     const float* __restrict__ b0, const float* __restrict__ b1,
                     const float* __restrict__ b2,
                     __hip_bfloat16* __restrict__ out_base) {
  __shared__ __attribute__((aligned(16))) __hip_bfloat16 As[4096];
  __shared__ __attribute__((aligned(16))) __hip_bfloat16 Bs[4096];
  const int z = blockIdx.z;
  const float* bias = (z == 0) ? b0 : (z == 1) ? b1 : b2;
  gemm_bias_body(A, WT_base + (size_t)z * wt_stride, bias,
                 out_base + (size_t)z * (size_t)(8192 * 512),
                 blockIdx.y * 128, blockIdx.x * 128, As, Bs);
}

// Fused-weight GEMM (fallback path).
__global__ __launch_bounds__(256)
void gemm_fusew_kernel(const __hip_bfloat16* __restrict__ A_base,
                       const __hip_bfloat16* __restrict__ BT_base,
                       __hip_bfloat16* __restrict__ C_base) {
  __shared__ __attribute__((aligned(16))) __hip_bfloat16 As[4096];
  __shared__ __attribute__((aligned(16))) __hip_bfloat16 Bs[4096];
  const size_t MS = (size_t)512 * 512;
  const int z = blockIdx.z;
  f32x4 acc[4][4];
#pragma unroll
  for (int m = 0; m < 4; ++m)
#pragma unroll
    for (int n = 0; n < 4; ++n) acc[m][n] = (f32x4)(0.0f);
  gemm_core_b128(A_base + z * MS, BT_base + z * MS, As, Bs,
                 blockIdx.y * 128, blockIdx.x * 128, acc);
  __hip_bfloat16* C = C_base + z * MS;
  const int lane = threadIdx.x & 63, wv = threadIdx.x >> 6;
  const int g = lane >> 4, r16 = lane & 15, wm = wv >> 1, wn = wv & 1;
#pragma unroll
  for (int n = 0; n < 4; ++n) {
    const int col = blockIdx.x * 128 + wn * 64 + n * 16 + r16;
#pragma unroll
    for (int m = 0; m < 4; ++m) {
      const int rowb = blockIdx.y * 128 + wm * 64 + m * 16 + g * 4;
#pragma unroll
      for (int r = 0; r < 4; ++r)
        C[(size_t)(rowb + r) * 512 + col] = __float2bfloat16(acc[m][n][r]);
    }
  }
}

__global__ __launch_bounds__(256)
void bias_fuse_kernel(const float* __restrict__ loc_bo, const float* __restrict__ g_bo,
                      const float* __restrict__ out_w, const float* __restrict__ out_b,
                      float* __restrict__ bfused) {
  const int z = blockIdx.y;
  const int n = blockIdx.x * 256 + threadIdx.x;
  const float* bo = (z < 3) ? loc_bo + z * 512 : g_bo;
  bias_fuse_body(bo, out_w + (size_t)z * 512 * 512, z == 0 ? out_b : nullptr,
                 bfused + z * 512, n);
}

// =====================================================================
// Local attention body (R9-proven).
// =====================================================================
template <int W>
__device__ __forceinline__ const __hip_bfloat16* slot_row(
    const __hip_bfloat16* __restrict__ X, const __hip_bfloat16* __restrict__ biasb,
    int b, int tloc, int pg, int sl, int* ch_out) {
  constexpr int PAD = (W - 1) / 2;
  const int hloc = sl >> 3, p = sl & 7;
  const int m = (pg * 4 + hloc) * W + p;
  const int j = m >> 3;
  *ch_out = m & 7;
  int sr = tloc + j - PAD;
  if (p < W) {
    if (sr >= 0 && sr < T_SEQ) return X + ((size_t)(b * T_SEQ + sr) << 9);
    return biasb;
  }
  sr = sr < 0 ? 0 : (sr > T_SEQ - 1 ? T_SEQ - 1 : sr);
  return X + ((size_t)(b * T_SEQ + sr) << 9);
}

template <int W>
__device__ __forceinline__ void local_attn_body(
    int bx, const __hip_bfloat16* __restrict__ Xq, const __hip_bfloat16* __restrict__ Xk,
    const __hip_bfloat16* __restrict__ Xv, const __hip_bfloat16* __restrict__ bqb,
    const __hip_bfloat16* __restrict__ bkb, const __hip_bfloat16* __restrict__ bvb,
    __hip_bfloat16* __restrict__ abar, unsigned* pool) {
  const int tid = threadIdx.x;
  const int wv = tid >> 6, lane = tid & 63;
  const int bt = bx * 4 + wv;
  const int b = bt >> 10, tloc = bt & 1023;
  unsigned* L = pool + wv * 2048;
  const int dl = lane & 31, hi = lane >> 5;

  {
    const int k2 = dl, dhalf = hi;
    int ch0, ch1;
    const __hip_bfloat16* r0 =
        slot_row<W>(Xv, bvb, b, tloc, (2 * k2) >> 5, (2 * k2) & 31, &ch0);
    const __hip_bfloat16* r1 =
        slot_row<W>(Xv, bvb, b, tloc, (2 * k2 + 1) >> 5, (2 * k2 + 1) & 31, &ch1);
    u16x8 A0[4], A1[4];
#pragma unroll
    for (int q = 0; q < 4; ++q) {
      A0[q] = *(const u16x8*)(r0 + ch0 * 64 + dhalf * 32 + q * 8);
      A1[q] = *(const u16x8*)(r1 + ch1 * 64 + dhalf * 32 + q * 8);
    }
#pragma unroll
    for (int q = 0; q < 4; ++q)
#pragma unroll
      for (int e = 0; e < 8; ++e) {
        const int d_ = dhalf * 32 + q * 8 + e;
        const unsigned dw = (unsigned)A0[q][e] | ((unsigned)A1[q][e] << 16);
        const int byte = (d_ * 128 + k2 * 4) ^ ((d_ & 7) << 4);
        L[byte >> 2] = dw;
      }
  }

  f32x16 accP[2][2];
#pragma unroll
  for (int pg = 0; pg < 2; ++pg)
#pragma unroll
    for (int dh = 0; dh < 2; ++dh) accP[pg][dh] = (f32x16)(0.0f);

  const int myb = dl >> 3;

#pragma unroll
  for (int pg = 0; pg < 2; ++pg) {
    int chK, chQ;
    const __hip_bfloat16* rK = slot_row<W>(Xk, bkb, b, tloc, pg, dl, &chK);
    const __hip_bfloat16* rQ = slot_row<W>(Xq, bqb, b, tloc, pg, dl, &chQ);
    f32x16 sa = (f32x16)(0.0f);
#pragma unroll
    for (int i = 0; i < 4; ++i) {
      const bf16x8 kf = *(const bf16x8*)(rK + chK * 64 + i * 16 + hi * 8);
      const bf16x8 qf = *(const bf16x8*)(rQ + chQ * 64 + i * 16 + hi * 8);
      sa = __builtin_amdgcn_mfma_f32_32x32x16_bf16(kf, qf, sa, 0, 0, 0);
    }

    float sel[4];
#pragma unroll
    for (int r4 = 0; r4 < 4; ++r4)
      sel[r4] = (myb == 0) ? sa[r4]
              : (myb == 1) ? sa[4 + r4]
              : (myb == 2) ? sa[8 + r4] : sa[12 + r4];

    float mx = -3e38f;
#pragma unroll
    for (int r4 = 0; r4 < 4; ++r4)
      if (r4 + 4 * hi < W) mx = fmaxf(mx, sel[r4]);
    mx = fmaxf(mx, __shfl_xor(mx, 32));
    float e[4], ls = 0.f;
#pragma unroll
    for (int r4 = 0; r4 < 4; ++r4) {
      e[r4] = (r4 + 4 * hi < W) ? __expf(0.125f * (sel[r4] - mx)) : 0.f;
      ls += e[r4];
    }
    ls += __shfl_xor(ls, 32);
    const float inv = 1.f / ls;

    unsigned dw0, dw1;
    CVTPK(dw0, e[0] * inv, e[1] * inv);
    CVTPK(dw1, e[2] * inv, e[3] * inv);
    const unsigned q0 = __shfl_xor(dw0, 32);
    const unsigned q1 = __shfl_xor(dw1, 32);

#pragma unroll
    for (int kh = 0; kh < 2; ++kh) {
      const bool on = (2 * kh + hi) == myb;
      u32x4 bw;
      if (hi == 0) { bw[0] = dw0; bw[1] = dw1; bw[2] = q0; bw[3] = q1; }
      else         { bw[0] = q0;  bw[1] = q1;  bw[2] = dw0; bw[3] = dw1; }
      if (!on) { bw[0] = 0u; bw[1] = 0u; bw[2] = 0u; bw[3] = 0u; }
      const bf16x8 pf = __builtin_bit_cast(bf16x8, bw);
#pragma unroll
      for (int dh = 0; dh < 2; ++dh) {
        const int d_ = dh * 32 + dl;
        const int off = (d_ * 128 + pg * 64 + kh * 32 + hi * 16) ^ ((d_ & 7) << 4);
        const bf16x8 va =
            __builtin_bit_cast(bf16x8, *(const u32x4*)((const char*)L + off));
        accP[pg][dh] = __builtin_amdgcn_mfma_f32_32x32x16_bf16(va, pf, accP[pg][dh], 0, 0, 0);
      }
    }
  }

#pragma unroll
  for (int pg = 0; pg < 2; ++pg) {
    if ((dl & 7) < W) {
      const int m_o = (pg * 4 + (dl >> 3)) * W + (dl & 7);
#pragma unroll
      for (int dh = 0; dh < 2; ++dh) {
#pragma unroll
        for (int rq = 0; rq < 4; ++rq) {
          unsigned wa, wb;
          CVTPK(wa, accP[pg][dh][4 * rq + 0], accP[pg][dh][4 * rq + 1]);
          CVTPK(wb, accP[pg][dh][4 * rq + 2], accP[pg][dh][4 * rq + 3]);
          const int dwi = m_o * 34 + dh * 16 + rq * 4 + hi * 2;
          uint2 w; w.x = wa; w.y = wb;
          *(uint2*)(L + dwi) = w;
        }
      }
    }
  }
  asm volatile("s_waitcnt lgkmcnt(0)" ::: "memory");

  const int cho = lane >> 3, fb = lane & 7;
  float o[8] = {0.f, 0.f, 0.f, 0.f, 0.f, 0.f, 0.f, 0.f};
#pragma unroll
  for (int jj = 0; jj < W; ++jj) {
    const int mo = 8 * jj + cho;
    const uint2 w0 = *(const uint2*)(L + mo * 34 + fb * 4);
    const uint2 w1 = *(const uint2*)(L + mo * 34 + fb * 4 + 2);
    o[0] += bf2f((unsigned short)(w0.x & 0xffff));
    o[1] += bf2f((unsigned short)(w0.x >> 16));
    o[2] += bf2f((unsigned short)(w0.y & 0xffff));
    o[3] += bf2f((unsigned short)(w0.y >> 16));
    o[4] += bf2f((unsigned short)(w1.x & 0xffff));
    o[5] += bf2f((unsigned short)(w1.x >> 16));
    o[6] += bf2f((unsigned short)(w1.y & 0xffff));
    o[7] += bf2f((unsigned short)(w1.y >> 16));
  }
  const float invw = 1.f / (float)W;
  u16x8 ov;
#pragma unroll
  for (int e2 = 0; e2 < 8; ++e2) ov[e2] = f2bf(o[e2] * invw);
  *(u16x8*)(abar + ((size_t)bt << 9) + cho * 64 + fb * 8) = ov;
}

// Wrapper: __launch_bounds__(256, 4) forces VGPR <= 128 (was 132, just
// past the m69 occupancy cliff) -> 4 waves/SIMD for this latency-bound
// kernel. XCD-chunked swizzle kept.
template <int W>
__global__ __launch_bounds__(256, 4)
void local_attn_mfma_kernel(const __hip_bfloat16* __restrict__ Xq,
                            const __hip_bfloat16* __restrict__ Xk,
                            const __hip_bfloat16* __restrict__ Xv,
                            const __hip_bfloat16* __restrict__ bqb,
                            const __hip_bfloat16* __restrict__ bkb,
                            const __hip_bfloat16* __restrict__ bvb,
                            __hip_bfloat16* __restrict__ abar) {
  __shared__ __attribute__((aligned(16))) unsigned pool[8192];
  const int bx = (blockIdx.x & 7) * 256 + (blockIdx.x >> 3);
  local_attn_body<W>(bx, Xq, Xk, Xv, bqb, bkb, bvb, abar, pool);
}

// =====================================================================
// Global attention body (R9-proven, 54us).
// =====================================================================
#define REDIST(pb, kb_)                                                  \
    {                                                                    \
      unsigned t0_, t1_, t2_, t3_, t4_, t5_, t6_, t7_;                   \
      CVTPK(t0_, pb[0], pb[1]);   CVTPK(t1_, pb[2], pb[3]);              \
      CVTPK(t2_, pb[4], pb[5]);   CVTPK(t3_, pb[6], pb[7]);              \
      CVTPK(t4_, pb[8], pb[9]);   CVTPK(t5_, pb[10], pb[11]);            \
      CVTPK(t6_, pb[12], pb[13]); CVTPK(t7_, pb[14], pb[15]);            \
      swap32(t0_, t2_, lane); swap32(t1_, t3_, lane);                    \
      swap32(t4_, t6_, lane); swap32(t5_, t7_, lane);                    \
      bw[kb_][0][0] = t0_; bw[kb_][0][1] = t1_; bw[kb_][0][2] = t2_;     \
      bw[kb_][0][3] = t3_;                                               \
      bw[kb_][1][0] = t4_; bw[kb_][1][1] = t5_; bw[kb_][1][2] = t6_;     \
      bw[kb_][1][3] = t7_;                                               \
    }

__device__ __forceinline__ void global_attn_body(
    int qblk, int bh, const __hip_bfloat16* __restrict__ Xq,
    const __hip_bfloat16* __restrict__ Xk, const __hip_bfloat16* __restrict__ Xv,
    __hip_bfloat16* __restrict__ att, unsigned* pool) {
  const int tid = threadIdx.x;
  const int lane = tid & 63;
  const int wv = tid >> 6;
  const size_t base = (size_t)bh << 16;
  const int c = lane & 31;
  const int g = lane >> 5;
  const int q0 = qblk * 128 + wv * 32;

  const __hip_bfloat16* Qp = Xq + base;
  const __hip_bfloat16* Kp = Xk + base;
  const __hip_bfloat16* Vp = Xv + base;

  bf16x8 qf[4];
#pragma unroll
  for (int s = 0; s < 4; ++s)
    qf[s] = *(const bf16x8*)(Qp + (size_t)(q0 + c) * 64 + s * 16 + g * 8);

  const int k2 = tid & 31, dblk = tid >> 5;

  bf16x8 kf[2][4];
  u16x8 v0, v1, v0n, v1n;

  v0 = *(const u16x8*)(Vp + (size_t)(2 * k2) * 64 + dblk * 8);
  v1 = *(const u16x8*)(Vp + (size_t)(2 * k2 + 1) * 64 + dblk * 8);
#pragma unroll
  for (int kb = 0; kb < 2; ++kb)
#pragma unroll
    for (int s = 0; s < 4; ++s)
      kf[kb][s] = *(const bf16x8*)(Kp + (size_t)(kb * 32 + c) * 64 + s * 16 + g * 8);

  f32x16 Oa = (f32x16)(0.0f), Ob = (f32x16)(0.0f);
  float m_run = -3e38f, l_run = 0.f;

  for (int kt = 0; kt < 16; ++kt) {
    unsigned* vb = pool + (kt & 1) * 2048;
#pragma unroll
    for (int jj = 0; jj < 8; ++jj) {
      const int d = dblk * 8 + jj;
      const unsigned dw = (unsigned)v0[jj] | ((unsigned)v1[jj] << 16);
      const int byte = (d * 128 + k2 * 4) ^ ((d & 7) << 4);
      vb[byte >> 2] = dw;
    }
    if (kt < 15) {
      const __hip_bfloat16* vsrc = Vp + (size_t)((kt + 1) * 64 + 2 * k2) * 64 + dblk * 8;
      v0n = *(const u16x8*)vsrc;
      v1n = *(const u16x8*)(vsrc + 64);
    }
    __syncthreads();

    f32x16 sa = (f32x16)(0.0f), sb = (f32x16)(0.0f);
#pragma unroll
    for (int s = 0; s < 4; ++s)
      sa = __builtin_amdgcn_mfma_f32_32x32x16_bf16(kf[0][s], qf[s], sa, 0, 0, 0);
#pragma unroll
    for (int s = 0; s < 4; ++s)
      sb = __builtin_amdgcn_mfma_f32_32x32x16_bf16(kf[1][s], qf[s], sb, 0, 0, 0);

    if (kt < 15) {
#pragma unroll
      for (int kb = 0; kb < 2; ++kb)
#pragma unroll
        for (int s = 0; s < 4; ++s)
          kf[kb][s] = *(const bf16x8*)(Kp + (size_t)((kt + 1) * 64 + kb * 32 + c) * 64 +
                                       s * 16 + g * 8);
    }

    float mx = sa[0];
#pragma unroll
    for (int r = 1; r < 16; ++r) mx = fmaxf(mx, sa[r]);
#pragma unroll
    for (int r = 0; r < 16; ++r) mx = fmaxf(mx, sb[r]);
    mx = fmaxf(mx, __shfl_xor(mx, 32));
    const float m_new = fmaxf(m_run, mx * 0.125f);
    const float alpha = __expf(m_run - m_new);

    float p0[16], p1[16];
    float lsum = 0.f;
#pragma unroll
    for (int r = 0; r < 16; ++r) { p0[r] = __expf(fmaf(sa[r], 0.125f, -m_new)); lsum += p0[r]; }
#pragma unroll
    for (int r = 0; r < 16; ++r) { p1[r] = __expf(fmaf(sb[r], 0.125f, -m_new)); lsum += p1[r]; }
    lsum += __shfl_xor(lsum, 32);
    l_run = fmaf(l_run, alpha, lsum);
    m_run = m_new;
#pragma unroll
    for (int r = 0; r < 16; ++r) { Oa[r] *= alpha; Ob[r] *= alpha; }

    unsigned bw[2][2][4];
    REDIST(p0, 0)
    REDIST(p1, 1)

    const unsigned* vbr = pool + (kt & 1) * 2048;
#pragma unroll
    for (int kb = 0; kb < 2; ++kb)
#pragma unroll
      for (int st = 0; st < 2; ++st) {
        const u32x4 pw = { bw[kb][st][0], bw[kb][st][1], bw[kb][st][2], bw[kb][st][3] };
        const bf16x8 pf = __builtin_bit_cast(bf16x8, pw);
        {
          const int row = c;
          const int off = (row * 128 + (kb * 64 + st * 32 + g * 16)) ^ ((row & 7) << 4);
          const bf16x8 va = __builtin_bit_cast(bf16x8, *(const u32x4*)((const char*)vbr + off));
          Oa = __builtin_amdgcn_mfma_f32_32x32x16_bf16(va, pf, Oa, 0, 0, 0);
        }
        {
          const int row = 32 + c;
          const int off = (row * 128 + (kb * 64 + st * 32 + g * 16)) ^ ((row & 7) << 4);
          const bf16x8 va = __builtin_bit_cast(bf16x8, *(const u32x4*)((const char*)vbr + off));
          Ob = __builtin_amdgcn_mfma_f32_32x32x16_bf16(va, pf, Ob, 0, 0, 0);
        }
      }

    v0 = v0n; v1 = v1n;
  }

  const float inv = 1.f / l_run;
  __hip_bfloat16* drow = att + base + (size_t)(q0 + c) * 64;
#pragma unroll
  for (int qd = 0; qd < 4; ++qd) {
    unsigned lo, hi2;
    {
      const float a0 = Oa[4 * qd + 0] * inv, a1 = Oa[4 * qd + 1] * inv;
      const float a2 = Oa[4 * qd + 2] * inv, a3 = Oa[4 * qd + 3] * inv;
      CVTPK(lo, a0, a1); CVTPK(hi2, a2, a3);
      uint2 w; w.x = lo; w.y = hi2;
      *(uint2*)(drow + 8 * qd + 4 * g) = w;
    }
    {
      const float a0 = Ob[4 * qd + 0] * inv, a1 = Ob[4 * qd + 1] * inv;
      const float a2 = Ob[4 * qd + 2] * inv, a3 = Ob[4 * qd + 3] * inv;
      CVTPK(lo, a0, a1); CVTPK(hi2, a2, a3);
      uint2 w; w.x = lo; w.y = hi2;
      *(uint2*)(drow + 32 + 8 * qd + 4 * g) = w;
    }
  }
}

// Grid (64,8): XCD = bh & 7 -> all q-blocks of one head on one XCD.
__global__ __launch_bounds__(256)
void global_attn_mfma_kernel(const __hip_bfloat16* __restrict__ Xq,
                             const __hip_bfloat16* __restrict__ Xk,
                             const __hip_bfloat16* __restrict__ Xv,
                             __hip_bfloat16* __restrict__ att) {
  __shared__ __attribute__((aligned(16))) unsigned pool[4096];
  global_attn_body(blockIdx.y, blockIdx.x, Xq, Xk, Xv, att, pool);
}

// =====================================================================
// Final fused output GEMM (BM=64, grid (4,128)) — proven.
// =====================================================================
__global__ __launch_bounds__(256)
void gemm_out_fused_kernel(const __hip_bfloat16* __restrict__ A0,
                           const __hip_bfloat16* __restrict__ A1,
                           const __hip_bfloat16* __restrict__ A2,
                           const __hip_bfloat16* __restrict__ A3,
                           const __hip_bfloat16* __restrict__ WT_base,
                           const float* __restrict__ bfused,
                           float* __restrict__ out) {
  __shared__ __attribute__((aligned(16))) __hip_bfloat16 As[2048];
  __shared__ __attribute__((aligned(16))) __hip_bfloat16 Bs[4096];
  const size_t MS = (size_t)512 * 512;
  const int row0 = blockIdx.y * 64, col0 = blockIdx.x * 128;
  f32x4 acc[2][4];
#pragma unroll
  for (int m = 0; m < 2; ++m)
#pragma unroll
    for (int n = 0; n < 4; ++n) acc[m][n] = (f32x4)(0.0f);
  const __hip_bfloat16* Az[4] = {A0, A1, A2, A3};
  for (int z = 0; z < 4; ++z)
    gemm_core_b64(Az[z], WT_base + (size_t)z * MS, As, Bs, row0, col0, acc);
  const int lane = threadIdx.x & 63, wv = threadIdx.x >> 6;
  const int g = lane >> 4, r16 = lane & 15, wm = wv >> 1, wn = wv & 1;
#pragma unroll
  for (int n = 0; n < 4; ++n) {
    const int col = col0 + wn * 64 + n * 16 + r16;
    const float bn = bfused[col] + bfused[512 + col] + bfused[1024 + col] +
                     bfused[1536 + col];
#pragma unroll
    for (int m = 0; m < 2; ++m) {
      const int rowb = row0 + wm * 32 + m * 16 + g * 4;
#pragma unroll
      for (int r = 0; r < 4; ++r)
        out[(size_t)(rowb + r) * 512 + col] = acc[m][n][r] + bn;
    }
  }
}

// =====================================================================
// Launch
// =====================================================================
extern "C" void kernel_launch(void* const* d_in, const int* in_sizes, int n_in,
                              void* d_out, int out_size, void* d_ws, size_t ws_size,
                              hipStream_t stream) {
  const float* x      = (const float*)d_in[0];
  const float* loc_wq = (const float*)d_in[1];
  const float* loc_bq = (const float*)d_in[2];
  const float* loc_wk = (const float*)d_in[3];
  const float* loc_bk = (const float*)d_in[4];
  const float* loc_wv = (const float*)d_in[5];
  const float* loc_bv = (const float*)d_in[6];
  const float* loc_wo = (const float*)d_in[7];
  const float* loc_bo = (const float*)d_in[8];
  const float* g_wq  = (const float*)d_in[9];
  const float* g_bq  = (const float*)d_in[10];
  const float* g_wk  = (const float*)d_in[11];
  const float* g_bk  = (const float*)d_in[12];
  const float* g_wv  = (const float*)d_in[13];
  const float* g_bv  = (const float*)d_in[14];
  const float* g_wo  = (const float*)d_in[15];
  const float* g_bo  = (const float*)d_in[16];
  const float* out_w = (const float*)d_in[17];
  const float* out_b = (const float*)d_in[18];
  float* out = (float*)d_out;

  __hip_bfloat16* wsb = (__hip_bfloat16*)d_ws;
  const size_t SZ = (size_t)8192 * 512;
  const size_t MS = (size_t)512 * 512;

  __hip_bfloat16* xb    = wsb;
  __hip_bfloat16* WT    = wsb + SZ;
  float* bfused = (float*)(wsb + SZ + 24 * MS);
  __hip_bfloat16* bqkvb = wsb + SZ + 24 * MS + 4096;
  __hip_bfloat16* proj  = wsb + SZ + 24 * MS + 16384;

  const size_t need_big = 2 * (17 * SZ + 24 * MS + 16384);
  const bool big = ws_size >= need_big;

  const dim3 thr(256);

  prep_weights_kernel<<<dim3(256, 22), thr, 0, stream>>>(
      loc_wq, loc_wk, loc_wv, g_wq, g_wk, g_wv, out_w, loc_wo, g_wo,
      x, loc_bq, loc_bk, loc_bv, WT, xb, bqkvb);

  __hip_bfloat16 *abar0, *abar1, *abar2, *abar3;

  if (big) {
    abar0 = proj + 12 * SZ;
    abar1 = proj + 13 * SZ;
    abar2 = proj + 14 * SZ;
    abar3 = proj + 15 * SZ;
    // qkv x12 + fusew + bias-fuse in one homogeneous GEMM dispatch
    gemm_qkv_all_kernel<<<dim3(4, 64, 13), thr, 0, stream>>>(
        xb, WT, loc_bq, loc_bk, loc_bv, g_bq, g_bk, g_bv,
        loc_bo, g_bo, out_w, out_b, proj, bfused);
    local_attn_mfma_kernel<3><<<2048, thr, 0, stream>>>(
        proj + 0 * SZ, proj + 3 * SZ, proj + 6 * SZ,
        bqkvb + 0 * 512, bqkvb + 1 * 512, bqkvb + 2 * 512, abar0);
    local_attn_mfma_kernel<5><<<2048, thr, 0, stream>>>(
        proj + 1 * SZ, proj + 4 * SZ, proj + 7 * SZ,
        bqkvb + 3 * 512, bqkvb + 4 * 512, bqkvb + 5 * 512, abar1);
    local_attn_mfma_kernel<7><<<2048, thr, 0, stream>>>(
        proj + 2 * SZ, proj + 5 * SZ, proj + 8 * SZ,
        bqkvb + 6 * 512, bqkvb + 7 * 512, bqkvb + 8 * 512, abar2);
    global_attn_mfma_kernel<<<dim3(64, 8), thr, 0, stream>>>(
        proj + 9 * SZ, proj + 10 * SZ, proj + 11 * SZ, abar3);
  } else {
    gemm_fusew_kernel<<<dim3(4, 4, 4), thr, 0, stream>>>(WT + 12 * MS, WT + 16 * MS,
                                                         WT + 20 * MS);
    bias_fuse_kernel<<<dim3(2, 4), thr, 0, stream>>>(loc_bo, g_bo, out_w, out_b, bfused);
    __hip_bfloat16* Xq = proj;
    __hip_bfloat16* Xk = proj + SZ;
    __hip_bfloat16* Xv = proj + 2 * SZ;
    abar0 = proj + 3 * SZ;
    abar1 = proj + 4 * SZ;
    abar2 = proj + 5 * SZ;
    abar3 = proj + 6 * SZ;
    __hip_bfloat16* abars[3] = {abar0, abar1, abar2};
    const dim3 gqkv(4, 64, 3);
    for (int lv = 0; lv < 3; ++lv) {
      gemm_qkv_kernel<<<gqkv, thr, 0, stream>>>(
          xb, WT + lv * MS, 3 * MS,
          loc_bq + lv * 512, loc_bk + lv * 512, loc_bv + lv * 512, Xq);
      const __hip_bfloat16* bqb = bqkvb + (lv * 3 + 0) * 512;
      const __hip_bfloat16* bkb = bqkvb + (lv * 3 + 1) * 512;
      const __hip_bfloat16* bvb = bqkvb + (lv * 3 + 2) * 512;
      if (lv == 0)
        local_attn_mfma_kernel<3><<<2048, thr, 0, stream>>>(Xq, Xk, Xv, bqb, bkb, bvb, abars[lv]);
      else if (lv == 1)
        local_attn_mfma_kernel<5><<<2048, thr, 0, stream>>>(Xq, Xk, Xv, bqb, bkb, bvb, abars[lv]);
      else
        local_attn_mfma_kernel<7><<<2048, thr, 0, stream>>>(Xq, Xk, Xv, bqb, bkb, bvb, abars[lv]);
    }
    gemm_qkv_kernel<<<gqkv, thr, 0, stream>>>(xb, WT + 9 * MS, MS, g_bq, g_bk, g_bv, Xq);
    global_attn_mfma_kernel<<<dim3(64, 8), thr, 0, stream>>>(Xq, Xk, Xv, abar3);
  }

  gemm_out_fused_kernel<<<dim3(4, 128), thr, 0, stream>>>(abar0, abar1, abar2, abar3,
                                                          WT + 20 * MS, bfused, out);
}

// Round 15
// 243.295 us; speedup vs baseline: 1.2629x; 1.0549x over previous
//
#include <hip/hip_runtime.h>
#include <hip/hip_bf16.h>
#include <cstddef>

#define T_SEQ 1024
#define D_MODEL 512

typedef __attribute__((ext_vector_type(8))) __bf16 bf16x8;
typedef __attribute__((ext_vector_type(4))) float f32x4;
typedef __attribute__((ext_vector_type(16))) float f32x16;
typedef __attribute__((ext_vector_type(8))) unsigned short u16x8;
typedef __attribute__((ext_vector_type(4))) unsigned int u32x4;

typedef const unsigned int __attribute__((address_space(1)))* gas1_t;
typedef unsigned int __attribute__((address_space(3)))* las3_t;

__device__ __forceinline__ void gload_lds16(const void* g, void* l) {
  __builtin_amdgcn_global_load_lds((gas1_t)g, (las3_t)l, 16, 0, 0);
}

__device__ __forceinline__ float bf2f(unsigned short u) {
  return __uint_as_float(((unsigned)u) << 16);
}
__device__ __forceinline__ unsigned short f2bf(float f) {
  __hip_bfloat16 h = __float2bfloat16(f);
  return *(unsigned short*)&h;
}

#define CVTPK(dst, a, b) \
  asm("v_cvt_pk_bf16_f32 %0, %1, %2" : "=v"(dst) : "v"(a), "v"(b))

__device__ __forceinline__ void swap32(unsigned& a, unsigned& b, int lane) {
  const unsigned ax = __shfl_xor(a, 32);
  const unsigned bx = __shfl_xor(b, 32);
  const bool lo = lane < 32;
  const unsigned na = lo ? a : bx;
  const unsigned nb = lo ? ax : b;
  a = na; b = nb;
}

// =====================================================================
// Prep (proven): 22 z-slices of weight transpose/cast + x cast + bias.
// =====================================================================
__global__ __launch_bounds__(256)
void prep_weights_kernel(const float* __restrict__ loc_wq, const float* __restrict__ loc_wk,
                         const float* __restrict__ loc_wv, const float* __restrict__ g_wq,
                         const float* __restrict__ g_wk, const float* __restrict__ g_wv,
                         const float* __restrict__ out_w, const float* __restrict__ loc_wo,
                         const float* __restrict__ g_wo, const float* __restrict__ x,
                         const float* __restrict__ loc_bq, const float* __restrict__ loc_bk,
                         const float* __restrict__ loc_bv,
                         __hip_bfloat16* __restrict__ WT, __hip_bfloat16* __restrict__ xb,
                         __hip_bfloat16* __restrict__ bqkvb) {
  __shared__ float tile[32][33];
  const size_t MS = (size_t)512 * 512;
  const int z = blockIdx.y;
  const int t = threadIdx.x;

  if (z == 20) {
    const int base = blockIdx.x * 16384 + t * 8;
#pragma unroll
    for (int it = 0; it < 8; ++it) {
      const int i = base + it * 2048;
      const float4 a = *(const float4*)(x + i);
      const float4 b = *(const float4*)(x + i + 4);
      u16x8 o;
      o[0] = f2bf(a.x); o[1] = f2bf(a.y); o[2] = f2bf(a.z); o[3] = f2bf(a.w);
      o[4] = f2bf(b.x); o[5] = f2bf(b.y); o[6] = f2bf(b.z); o[7] = f2bf(b.w);
      *(u16x8*)(xb + i) = o;
    }
    return;
  }
  if (z == 21) {
    const int i = blockIdx.x * 256 + t;
    if (blockIdx.x < 18) {
      const int which = i >> 9, lv = which / 3, role = which % 3, e = i & 511;
      const float* src = role == 0 ? loc_bq : role == 1 ? loc_bk : loc_bv;
      bqkvb[i] = __float2bfloat16(src[lv * 512 + e]);
    }
    return;
  }

  const float* src;
  bool tr = true;
  if (z < 3)       src = loc_wq + (size_t)z * MS;
  else if (z < 6)  src = loc_wk + (size_t)(z - 3) * MS;
  else if (z < 9)  src = loc_wv + (size_t)(z - 6) * MS;
  else if (z == 9)  src = g_wq;
  else if (z == 10) src = g_wk;
  else if (z == 11) src = g_wv;
  else if (z < 16) src = out_w + (size_t)(z - 12) * MS;
  else if (z < 19) { src = loc_wo + (size_t)(z - 16) * MS; tr = false; }
  else             { src = g_wo; tr = false; }
  __hip_bfloat16* dst = WT + (size_t)z * MS;

  const int tk = (blockIdx.x & 15) * 32;
  const int tn = (blockIdx.x >> 4) * 32;
  const int r = t >> 3, c4 = (t & 7) * 4;
  const float4 v = *(const float4*)(src + (size_t)(tk + r) * 512 + tn + c4);
  if (tr) {
    tile[r][c4 + 0] = v.x; tile[r][c4 + 1] = v.y;
    tile[r][c4 + 2] = v.z; tile[r][c4 + 3] = v.w;
    __syncthreads();
    ushort4 o;
    o.x = f2bf(tile[c4 + 0][r]); o.y = f2bf(tile[c4 + 1][r]);
    o.z = f2bf(tile[c4 + 2][r]); o.w = f2bf(tile[c4 + 3][r]);
    *(ushort4*)(dst + (size_t)(tn + r) * 512 + tk + c4) = o;
  } else {
    ushort4 o;
    o.x = f2bf(v.x); o.y = f2bf(v.y); o.z = f2bf(v.z); o.w = f2bf(v.w);
    *(ushort4*)(dst + (size_t)(tk + r) * 512 + tn + c4) = o;
  }
}

// =====================================================================
// GEMM cores (proven).
// =====================================================================
__device__ __forceinline__ void gemm_core_b128(
    const __hip_bfloat16* __restrict__ A, const __hip_bfloat16* __restrict__ BT,
    __hip_bfloat16* As, __hip_bfloat16* Bs, int row0, int col0, f32x4 acc[4][4]) {
  const int tid = threadIdx.x;
  const int wv = tid >> 6, lane = tid & 63;
  const int g = lane >> 4, r16 = lane & 15;
  const int wm = wv >> 1, wn = wv & 1;
  const char* Ab = (const char*)A;
  const char* Bb = (const char*)BT;
  for (int k0 = 0; k0 < 512; k0 += 32) {
    {
      const int row = tid >> 2, off = (tid & 3) << 4;
      gload_lds16(Ab + (size_t)(row0 + row) * 1024 + k0 * 2 + off,
                  (char*)As + (wv << 10));
      const int i2 = tid + 256;
      const int row2 = i2 >> 2, off2 = (i2 & 3) << 4;
      gload_lds16(Ab + (size_t)(row0 + row2) * 1024 + k0 * 2 + off2,
                  (char*)As + 4096 + (wv << 10));
    }
    {
      const int row = tid >> 2, off = (tid & 3) << 4;
      gload_lds16(Bb + (size_t)(col0 + row) * 1024 + k0 * 2 + off,
                  (char*)Bs + (wv << 10));
      const int i2 = tid + 256;
      const int row2 = i2 >> 2, off2 = (i2 & 3) << 4;
      gload_lds16(Bb + (size_t)(col0 + row2) * 1024 + k0 * 2 + off2,
                  (char*)Bs + 4096 + (wv << 10));
    }
    __syncthreads();
    bf16x8 a[4], b[4];
#pragma unroll
    for (int m = 0; m < 4; ++m)
      a[m] = *(const bf16x8*)(As + (wm * 64 + m * 16 + r16) * 32 + g * 8);
#pragma unroll
    for (int n = 0; n < 4; ++n)
      b[n] = *(const bf16x8*)(Bs + (wn * 64 + n * 16 + r16) * 32 + g * 8);
#pragma unroll
    for (int m = 0; m < 4; ++m)
#pragma unroll
      for (int n = 0; n < 4; ++n)
        acc[m][n] = __builtin_amdgcn_mfma_f32_16x16x32_bf16(a[m], b[n], acc[m][n], 0, 0, 0);
    __syncthreads();
  }
}

__device__ __forceinline__ void gemm_core_b64(
    const __hip_bfloat16* __restrict__ A, const __hip_bfloat16* __restrict__ BT,
    __hip_bfloat16* As, __hip_bfloat16* Bs, int row0, int col0, f32x4 acc[2][4]) {
  const int tid = threadIdx.x;
  const int wv = tid >> 6, lane = tid & 63;
  const int g = lane >> 4, r16 = lane & 15;
  const int wm = wv >> 1, wn = wv & 1;
  const char* Ab = (const char*)A;
  const char* Bb = (const char*)BT;
  for (int k0 = 0; k0 < 512; k0 += 32) {
    {
      const int row = tid >> 2, off = (tid & 3) << 4;
      gload_lds16(Ab + (size_t)(row0 + row) * 1024 + k0 * 2 + off,
                  (char*)As + (wv << 10));
    }
    {
      const int row = tid >> 2, off = (tid & 3) << 4;
      gload_lds16(Bb + (size_t)(col0 + row) * 1024 + k0 * 2 + off,
                  (char*)Bs + (wv << 10));
      const int i2 = tid + 256;
      const int row2 = i2 >> 2, off2 = (i2 & 3) << 4;
      gload_lds16(Bb + (size_t)(col0 + row2) * 1024 + k0 * 2 + off2,
                  (char*)Bs + 4096 + (wv << 10));
    }
    __syncthreads();
    bf16x8 a[2], b[4];
#pragma unroll
    for (int m = 0; m < 2; ++m)
      a[m] = *(const bf16x8*)(As + (wm * 32 + m * 16 + r16) * 32 + g * 8);
#pragma unroll
    for (int n = 0; n < 4; ++n)
      b[n] = *(const bf16x8*)(Bs + (wn * 64 + n * 16 + r16) * 32 + g * 8);
#pragma unroll
    for (int m = 0; m < 2; ++m)
#pragma unroll
      for (int n = 0; n < 4; ++n)
        acc[m][n] = __builtin_amdgcn_mfma_f32_16x16x32_bf16(a[m], b[n], acc[m][n], 0, 0, 0);
    __syncthreads();
  }
}

// bf16 C = A@W^T + bias (one 128x128 tile)
__device__ __forceinline__ void gemm_bias_body(
    const __hip_bfloat16* __restrict__ A, const __hip_bfloat16* __restrict__ WT,
    const float* __restrict__ bias, __hip_bfloat16* __restrict__ C,
    int row0, int col0, __hip_bfloat16* As, __hip_bfloat16* Bs) {
  f32x4 acc[4][4];
#pragma unroll
  for (int m = 0; m < 4; ++m)
#pragma unroll
    for (int n = 0; n < 4; ++n) acc[m][n] = (f32x4)(0.0f);
  gemm_core_b128(A, WT, As, Bs, row0, col0, acc);
  const int lane = threadIdx.x & 63, wv = threadIdx.x >> 6;
  const int g = lane >> 4, r16 = lane & 15, wm = wv >> 1, wn = wv & 1;
#pragma unroll
  for (int n = 0; n < 4; ++n) {
    const int col = col0 + wn * 64 + n * 16 + r16;
    const float bn = bias ? bias[col] : 0.f;
#pragma unroll
    for (int m = 0; m < 4; ++m) {
      const int rowb = row0 + wm * 64 + m * 16 + g * 4;
#pragma unroll
      for (int r = 0; r < 4; ++r)
        C[(size_t)(rowb + r) * 512 + col] = __float2bfloat16(acc[m][n][r] + bn);
    }
  }
}

__device__ __forceinline__ void bias_fuse_body(
    const float* __restrict__ bo, const float* __restrict__ W,
    const float* __restrict__ add, float* __restrict__ bfz, int n) {
  float acc = add ? add[n] : 0.f;
  for (int m = 0; m < 512; ++m)
    acc = fmaf(bo[m], W[(size_t)m * 512 + n], acc);
  bfz[n] = acc;
}

// =====================================================================
// Mega Q/K/V + folded fusew/bias-fuse. EXTRAS FIRST (z == 0) so they
// launch in the first block generation and hide under the qkv work —
// appending them (old z==12) made them a quarter-machine tail.
// z = 1..12: the 12 projections (proven body), slot zz = z-1.
// =====================================================================
__global__ __launch_bounds__(256)
void gemm_qkv_all_kernel(const __hip_bfloat16* __restrict__ A,
                         const __hip_bfloat16* __restrict__ WT_base,
                         const float* __restrict__ loc_bq, const float* __restrict__ loc_bk,
                         const float* __restrict__ loc_bv, const float* __restrict__ g_bq,
                         const float* __restrict__ g_bk, const float* __restrict__ g_bv,
                         const float* __restrict__ loc_bo, const float* __restrict__ g_bo,
                         const float* __restrict__ out_w, const float* __restrict__ out_b,
                         __hip_bfloat16* __restrict__ proj_base,
                         float* __restrict__ bfused) {
  __shared__ __attribute__((aligned(16))) __hip_bfloat16 As[4096];
  __shared__ __attribute__((aligned(16))) __hip_bfloat16 Bs[4096];
  const size_t MS = (size_t)512 * 512;
  const int z = blockIdx.z;

  if (z == 0) {
    const int y = blockIdx.y;
    if ((y & 12) == 0) {
      // fusew: 64 blocks, WfT[wz] = (wo_wz @ outw_wz)^T
      const int wz = y >> 4, row = y & 3, col = blockIdx.x;
      f32x4 acc[4][4];
#pragma unroll
      for (int m = 0; m < 4; ++m)
#pragma unroll
        for (int n = 0; n < 4; ++n) acc[m][n] = (f32x4)(0.0f);
      gemm_core_b128(WT_base + (size_t)(12 + wz) * MS, WT_base + (size_t)(16 + wz) * MS,
                     As, Bs, row * 128, col * 128, acc);
      __hip_bfloat16* C = (__hip_bfloat16*)(WT_base + (size_t)(20 + wz) * MS);
      const int lane = threadIdx.x & 63, wv = threadIdx.x >> 6;
      const int g = lane >> 4, r16 = lane & 15, wm = wv >> 1, wn = wv & 1;
#pragma unroll
      for (int n = 0; n < 4; ++n) {
        const int cc = col * 128 + wn * 64 + n * 16 + r16;
#pragma unroll
        for (int m = 0; m < 4; ++m) {
          const int rowb = row * 128 + wm * 64 + m * 16 + g * 4;
#pragma unroll
          for (int r = 0; r < 4; ++r)
            C[(size_t)(rowb + r) * 512 + cc] = __float2bfloat16(acc[m][n][r]);
        }
      }
    } else if (((y & 15) == 4 || (y & 15) == 5) && blockIdx.x == 0) {
      // bias fuse: 8 blocks
      const int wz = y >> 4, half = y & 1;
      const int n = half * 256 + threadIdx.x;
      const float* bo = (wz < 3) ? loc_bo + wz * 512 : g_bo;
      bias_fuse_body(bo, out_w + (size_t)wz * MS, wz == 0 ? out_b : nullptr,
                     bfused + wz * 512, n);
    }
    return;
  }

  const int zz = z - 1;
  const float* bias;
  if (zz < 3)       bias = loc_bq + zz * 512;
  else if (zz < 6)  bias = loc_bk + (zz - 3) * 512;
  else if (zz < 9)  bias = loc_bv + (zz - 6) * 512;
  else              bias = (zz == 9) ? g_bq : (zz == 10) ? g_bk : g_bv;
  gemm_bias_body(A, WT_base + (size_t)zz * MS, bias,
                 proj_base + (size_t)zz * (size_t)(8192 * 512),
                 blockIdx.y * 128, blockIdx.x * 128, As, Bs);
}

// Fallback per-level Q/K/V projection.
__global__ __launch_bounds__(256)
void gemm_qkv_kernel(const __hip_bfloat16* __restrict__ A,
                     const __hip_bfloat16* __restrict__ WT_base, size_t wt_stride,
                     const float* __restrict__ b0, const float* __restrict__ b1,
                     const float* __restrict__ b2,
                     __hip_bfloat16* __restrict__ out_base) {
  __shared__ __attribute__((aligned(16))) __hip_bfloat16 As[4096];
  __shared__ __attribute__((aligned(16))) __hip_bfloat16 Bs[4096];
  const int z = blockIdx.z;
  const float* bias = (z == 0) ? b0 : (z == 1) ? b1 : b2;
  gemm_bias_body(A, WT_base + (size_t)z * wt_stride, bias,
                 out_base + (size_t)z * (size_t)(8192 * 512),
                 blockIdx.y * 128, blockIdx.x * 128, As, Bs);
}

// Fused-weight GEMM (fallback path).
__global__ __launch_bounds__(256)
void gemm_fusew_kernel(const __hip_bfloat16* __restrict__ A_base,
                       const __hip_bfloat16* __restrict__ BT_base,
                       __hip_bfloat16* __restrict__ C_base) {
  __shared__ __attribute__((aligned(16))) __hip_bfloat16 As[4096];
  __shared__ __attribute__((aligned(16))) __hip_bfloat16 Bs[4096];
  const size_t MS = (size_t)512 * 512;
  const int z = blockIdx.z;
  f32x4 acc[4][4];
#pragma unroll
  for (int m = 0; m < 4; ++m)
#pragma unroll
    for (int n = 0; n < 4; ++n) acc[m][n] = (f32x4)(0.0f);
  gemm_core_b128(A_base + z * MS, BT_base + z * MS, As, Bs,
                 blockIdx.y * 128, blockIdx.x * 128, acc);
  __hip_bfloat16* C = C_base + z * MS;
  const int lane = threadIdx.x & 63, wv = threadIdx.x >> 6;
  const int g = lane >> 4, r16 = lane & 15, wm = wv >> 1, wn = wv & 1;
#pragma unroll
  for (int n = 0; n < 4; ++n) {
    const int col = blockIdx.x * 128 + wn * 64 + n * 16 + r16;
#pragma unroll
    for (int m = 0; m < 4; ++m) {
      const int rowb = blockIdx.y * 128 + wm * 64 + m * 16 + g * 4;
#pragma unroll
      for (int r = 0; r < 4; ++r)
        C[(size_t)(rowb + r) * 512 + col] = __float2bfloat16(acc[m][n][r]);
    }
  }
}

__global__ __launch_bounds__(256)
void bias_fuse_kernel(const float* __restrict__ loc_bo, const float* __restrict__ g_bo,
                      const float* __restrict__ out_w, const float* __restrict__ out_b,
                      float* __restrict__ bfused) {
  const int z = blockIdx.y;
  const int n = blockIdx.x * 256 + threadIdx.x;
  const float* bo = (z < 3) ? loc_bo + z * 512 : g_bo;
  bias_fuse_body(bo, out_w + (size_t)z * 512 * 512, z == 0 ? out_b : nullptr,
                 bfused + z * 512, n);
}

// =====================================================================
// Local attention body (R9-proven, W now a runtime parameter — only
// masks / epilogue bounds depend on it, MFMA structure is W-invariant).
// =====================================================================
__device__ __forceinline__ const __hip_bfloat16* slot_row(
    int W, const __hip_bfloat16* __restrict__ X, const __hip_bfloat16* __restrict__ biasb,
    int b, int tloc, int pg, int sl, int* ch_out) {
  const int PAD = (W - 1) >> 1;
  const int hloc = sl >> 3, p = sl & 7;
  const int m = (pg * 4 + hloc) * W + p;
  const int j = m >> 3;
  *ch_out = m & 7;
  int sr = tloc + j - PAD;
  if (p < W) {
    if (sr >= 0 && sr < T_SEQ) return X + ((size_t)(b * T_SEQ + sr) << 9);
    return biasb;
  }
  sr = sr < 0 ? 0 : (sr > T_SEQ - 1 ? T_SEQ - 1 : sr);
  return X + ((size_t)(b * T_SEQ + sr) << 9);
}

__device__ __forceinline__ void local_attn_body(
    int W, int bx, const __hip_bfloat16* __restrict__ Xq,
    const __hip_bfloat16* __restrict__ Xk, const __hip_bfloat16* __restrict__ Xv,
    const __hip_bfloat16* __restrict__ bqb, const __hip_bfloat16* __restrict__ bkb,
    const __hip_bfloat16* __restrict__ bvb, __hip_bfloat16* __restrict__ abar,
    unsigned* pool) {
  const int tid = threadIdx.x;
  const int wv = tid >> 6, lane = tid & 63;
  const int bt = bx * 4 + wv;
  const int b = bt >> 10, tloc = bt & 1023;
  unsigned* L = pool + wv * 2048;
  const int dl = lane & 31, hi = lane >> 5;

  {
    const int k2 = dl, dhalf = hi;
    int ch0, ch1;
    const __hip_bfloat16* r0 =
        slot_row(W, Xv, bvb, b, tloc, (2 * k2) >> 5, (2 * k2) & 31, &ch0);
    const __hip_bfloat16* r1 =
        slot_row(W, Xv, bvb, b, tloc, (2 * k2 + 1) >> 5, (2 * k2 + 1) & 31, &ch1);
    u16x8 A0[4], A1[4];
#pragma unroll
    for (int q = 0; q < 4; ++q) {
      A0[q] = *(const u16x8*)(r0 + ch0 * 64 + dhalf * 32 + q * 8);
      A1[q] = *(const u16x8*)(r1 + ch1 * 64 + dhalf * 32 + q * 8);
    }
#pragma unroll
    for (int q = 0; q < 4; ++q)
#pragma unroll
      for (int e = 0; e < 8; ++e) {
        const int d_ = dhalf * 32 + q * 8 + e;
        const unsigned dw = (unsigned)A0[q][e] | ((unsigned)A1[q][e] << 16);
        const int byte = (d_ * 128 + k2 * 4) ^ ((d_ & 7) << 4);
        L[byte >> 2] = dw;
      }
  }

  f32x16 accP[2][2];
#pragma unroll
  for (int pg = 0; pg < 2; ++pg)
#pragma unroll
    for (int dh = 0; dh < 2; ++dh) accP[pg][dh] = (f32x16)(0.0f);

  const int myb = dl >> 3;

#pragma unroll
  for (int pg = 0; pg < 2; ++pg) {
    int chK, chQ;
    const __hip_bfloat16* rK = slot_row(W, Xk, bkb, b, tloc, pg, dl, &chK);
    const __hip_bfloat16* rQ = slot_row(W, Xq, bqb, b, tloc, pg, dl, &chQ);
    f32x16 sa = (f32x16)(0.0f);
#pragma unroll
    for (int i = 0; i < 4; ++i) {
      const bf16x8 kf = *(const bf16x8*)(rK + chK * 64 + i * 16 + hi * 8);
      const bf16x8 qf = *(const bf16x8*)(rQ + chQ * 64 + i * 16 + hi * 8);
      sa = __builtin_amdgcn_mfma_f32_32x32x16_bf16(kf, qf, sa, 0, 0, 0);
    }

    float sel[4];
#pragma unroll
    for (int r4 = 0; r4 < 4; ++r4)
      sel[r4] = (myb == 0) ? sa[r4]
              : (myb == 1) ? sa[4 + r4]
              : (myb == 2) ? sa[8 + r4] : sa[12 + r4];

    float mx = -3e38f;
#pragma unroll
    for (int r4 = 0; r4 < 4; ++r4)
      if (r4 + 4 * hi < W) mx = fmaxf(mx, sel[r4]);
    mx = fmaxf(mx, __shfl_xor(mx, 32));
    float e[4], ls = 0.f;
#pragma unroll
    for (int r4 = 0; r4 < 4; ++r4) {
      e[r4] = (r4 + 4 * hi < W) ? __expf(0.125f * (sel[r4] - mx)) : 0.f;
      ls += e[r4];
    }
    ls += __shfl_xor(ls, 32);
    const float inv = 1.f / ls;

    unsigned dw0, dw1;
    CVTPK(dw0, e[0] * inv, e[1] * inv);
    CVTPK(dw1, e[2] * inv, e[3] * inv);
    const unsigned q0 = __shfl_xor(dw0, 32);
    const unsigned q1 = __shfl_xor(dw1, 32);

#pragma unroll
    for (int kh = 0; kh < 2; ++kh) {
      const bool on = (2 * kh + hi) == myb;
      u32x4 bw;
      if (hi == 0) { bw[0] = dw0; bw[1] = dw1; bw[2] = q0; bw[3] = q1; }
      else         { bw[0] = q0;  bw[1] = q1;  bw[2] = dw0; bw[3] = dw1; }
      if (!on) { bw[0] = 0u; bw[1] = 0u; bw[2] = 0u; bw[3] = 0u; }
      const bf16x8 pf = __builtin_bit_cast(bf16x8, bw);
#pragma unroll
      for (int dh = 0; dh < 2; ++dh) {
        const int d_ = dh * 32 + dl;
        const int off = (d_ * 128 + pg * 64 + kh * 32 + hi * 16) ^ ((d_ & 7) << 4);
        const bf16x8 va =
            __builtin_bit_cast(bf16x8, *(const u32x4*)((const char*)L + off));
        accP[pg][dh] = __builtin_amdgcn_mfma_f32_32x32x16_bf16(va, pf, accP[pg][dh], 0, 0, 0);
      }
    }
  }

#pragma unroll
  for (int pg = 0; pg < 2; ++pg) {
    if ((dl & 7) < W) {
      const int m_o = (pg * 4 + (dl >> 3)) * W + (dl & 7);
#pragma unroll
      for (int dh = 0; dh < 2; ++dh) {
#pragma unroll
        for (int rq = 0; rq < 4; ++rq) {
          unsigned wa, wb;
          CVTPK(wa, accP[pg][dh][4 * rq + 0], accP[pg][dh][4 * rq + 1]);
          CVTPK(wb, accP[pg][dh][4 * rq + 2], accP[pg][dh][4 * rq + 3]);
          const int dwi = m_o * 34 + dh * 16 + rq * 4 + hi * 2;
          uint2 w; w.x = wa; w.y = wb;
          *(uint2*)(L + dwi) = w;
        }
      }
    }
  }
  asm volatile("s_waitcnt lgkmcnt(0)" ::: "memory");

  const int cho = lane >> 3, fb = lane & 7;
  float o[8] = {0.f, 0.f, 0.f, 0.f, 0.f, 0.f, 0.f, 0.f};
  for (int jj = 0; jj < W; ++jj) {
    const int mo = 8 * jj + cho;
    const uint2 w0 = *(const uint2*)(L + mo * 34 + fb * 4);
    const uint2 w1 = *(const uint2*)(L + mo * 34 + fb * 4 + 2);
    o[0] += bf2f((unsigned short)(w0.x & 0xffff));
    o[1] += bf2f((unsigned short)(w0.x >> 16));
    o[2] += bf2f((unsigned short)(w0.y & 0xffff));
    o[3] += bf2f((unsigned short)(w0.y >> 16));
    o[4] += bf2f((unsigned short)(w1.x & 0xffff));
    o[5] += bf2f((unsigned short)(w1.x >> 16));
    o[6] += bf2f((unsigned short)(w1.y & 0xffff));
    o[7] += bf2f((unsigned short)(w1.y >> 16));
  }
  const float invw = 1.f / (float)W;
  u16x8 ov;
#pragma unroll
  for (int e2 = 0; e2 < 8; ++e2) ov[e2] = f2bf(o[e2] * invw);
  *(u16x8*)(abar + ((size_t)bt << 9) + cho * 64 + fb * 8) = ov;
}

// All 3 local levels in ONE dispatch (6144 blocks, runtime W — same
// body/LDS/registers, single I$ copy; merges 3 dispatch tails).
__global__ __launch_bounds__(256, 4)
void local_attn_all_kernel(const __hip_bfloat16* __restrict__ proj,
                           const __hip_bfloat16* __restrict__ bqkvb,
                           __hip_bfloat16* __restrict__ abar0,
                           __hip_bfloat16* __restrict__ abar1,
                           __hip_bfloat16* __restrict__ abar2) {
  __shared__ __attribute__((aligned(16))) unsigned pool[8192];
  const size_t SZ = (size_t)8192 * 512;
  const int bid = blockIdx.x;
  const int lv = bid >> 11;
  const int bxr = bid & 2047;
  const int bx = (bxr & 7) * 256 + (bxr >> 3);   // XCD-chunked swizzle
  const int W = (lv == 0) ? 3 : (lv == 1) ? 5 : 7;
  __hip_bfloat16* abar = (lv == 0) ? abar0 : (lv == 1) ? abar1 : abar2;
  local_attn_body(W, bx, proj + (size_t)lv * SZ, proj + (size_t)(3 + lv) * SZ,
                  proj + (size_t)(6 + lv) * SZ,
                  bqkvb + (lv * 3 + 0) * 512, bqkvb + (lv * 3 + 1) * 512,
                  bqkvb + (lv * 3 + 2) * 512, abar, pool);
}

// Fallback single-level wrappers (template W constant-folds into body).
template <int W>
__global__ __launch_bounds__(256, 4)
void local_attn_mfma_kernel(const __hip_bfloat16* __restrict__ Xq,
                            const __hip_bfloat16* __restrict__ Xk,
                            const __hip_bfloat16* __restrict__ Xv,
                            const __hip_bfloat16* __restrict__ bqb,
                            const __hip_bfloat16* __restrict__ bkb,
                            const __hip_bfloat16* __restrict__ bvb,
                            __hip_bfloat16* __restrict__ abar) {
  __shared__ __attribute__((aligned(16))) unsigned pool[8192];
  const int bx = (blockIdx.x & 7) * 256 + (blockIdx.x >> 3);
  local_attn_body(W, bx, Xq, Xk, Xv, bqb, bkb, bvb, abar, pool);
}

// =====================================================================
// Global attention body (R9-proven, 54us).
// =====================================================================
#define REDIST(pb, kb_)                                                  \
    {                                                                    \
      unsigned t0_, t1_, t2_, t3_, t4_, t5_, t6_, t7_;                   \
      CVTPK(t0_, pb[0], pb[1]);   CVTPK(t1_, pb[2], pb[3]);              \
      CVTPK(t2_, pb[4], pb[5]);   CVTPK(t3_, pb[6], pb[7]);              \
      CVTPK(t4_, pb[8], pb[9]);   CVTPK(t5_, pb[10], pb[11]);            \
      CVTPK(t6_, pb[12], pb[13]); CVTPK(t7_, pb[14], pb[15]);            \
      swap32(t0_, t2_, lane); swap32(t1_, t3_, lane);                    \
      swap32(t4_, t6_, lane); swap32(t5_, t7_, lane);                    \
      bw[kb_][0][0] = t0_; bw[kb_][0][1] = t1_; bw[kb_][0][2] = t2_;     \
      bw[kb_][0][3] = t3_;                                               \
      bw[kb_][1][0] = t4_; bw[kb_][1][1] = t5_; bw[kb_][1][2] = t6_;     \
      bw[kb_][1][3] = t7_;                                               \
    }

__device__ __forceinline__ void global_attn_body(
    int qblk, int bh, const __hip_bfloat16* __restrict__ Xq,
    const __hip_bfloat16* __restrict__ Xk, const __hip_bfloat16* __restrict__ Xv,
    __hip_bfloat16* __restrict__ att, unsigned* pool) {
  const int tid = threadIdx.x;
  const int lane = tid & 63;
  const int wv = tid >> 6;
  const size_t base = (size_t)bh << 16;
  const int c = lane & 31;
  const int g = lane >> 5;
  const int q0 = qblk * 128 + wv * 32;

  const __hip_bfloat16* Qp = Xq + base;
  const __hip_bfloat16* Kp = Xk + base;
  const __hip_bfloat16* Vp = Xv + base;

  bf16x8 qf[4];
#pragma unroll
  for (int s = 0; s < 4; ++s)
    qf[s] = *(const bf16x8*)(Qp + (size_t)(q0 + c) * 64 + s * 16 + g * 8);

  const int k2 = tid & 31, dblk = tid >> 5;

  bf16x8 kf[2][4];
  u16x8 v0, v1, v0n, v1n;

  v0 = *(const u16x8*)(Vp + (size_t)(2 * k2) * 64 + dblk * 8);
  v1 = *(const u16x8*)(Vp + (size_t)(2 * k2 + 1) * 64 + dblk * 8);
#pragma unroll
  for (int kb = 0; kb < 2; ++kb)
#pragma unroll
    for (int s = 0; s < 4; ++s)
      kf[kb][s] = *(const bf16x8*)(Kp + (size_t)(kb * 32 + c) * 64 + s * 16 + g * 8);

  f32x16 Oa = (f32x16)(0.0f), Ob = (f32x16)(0.0f);
  float m_run = -3e38f, l_run = 0.f;

  for (int kt = 0; kt < 16; ++kt) {
    unsigned* vb = pool + (kt & 1) * 2048;
#pragma unroll
    for (int jj = 0; jj < 8; ++jj) {
      const int d = dblk * 8 + jj;
      const unsigned dw = (unsigned)v0[jj] | ((unsigned)v1[jj] << 16);
      const int byte = (d * 128 + k2 * 4) ^ ((d & 7) << 4);
      vb[byte >> 2] = dw;
    }
    if (kt < 15) {
      const __hip_bfloat16* vsrc = Vp + (size_t)((kt + 1) * 64 + 2 * k2) * 64 + dblk * 8;
      v0n = *(const u16x8*)vsrc;
      v1n = *(const u16x8*)(vsrc + 64);
    }
    __syncthreads();

    f32x16 sa = (f32x16)(0.0f), sb = (f32x16)(0.0f);
#pragma unroll
    for (int s = 0; s < 4; ++s)
      sa = __builtin_amdgcn_mfma_f32_32x32x16_bf16(kf[0][s], qf[s], sa, 0, 0, 0);
#pragma unroll
    for (int s = 0; s < 4; ++s)
      sb = __builtin_amdgcn_mfma_f32_32x32x16_bf16(kf[1][s], qf[s], sb, 0, 0, 0);

    if (kt < 15) {
#pragma unroll
      for (int kb = 0; kb < 2; ++kb)
#pragma unroll
        for (int s = 0; s < 4; ++s)
          kf[kb][s] = *(const bf16x8*)(Kp + (size_t)((kt + 1) * 64 + kb * 32 + c) * 64 +
                                       s * 16 + g * 8);
    }

    float mx = sa[0];
#pragma unroll
    for (int r = 1; r < 16; ++r) mx = fmaxf(mx, sa[r]);
#pragma unroll
    for (int r = 0; r < 16; ++r) mx = fmaxf(mx, sb[r]);
    mx = fmaxf(mx, __shfl_xor(mx, 32));
    const float m_new = fmaxf(m_run, mx * 0.125f);
    const float alpha = __expf(m_run - m_new);

    float p0[16], p1[16];
    float lsum = 0.f;
#pragma unroll
    for (int r = 0; r < 16; ++r) { p0[r] = __expf(fmaf(sa[r], 0.125f, -m_new)); lsum += p0[r]; }
#pragma unroll
    for (int r = 0; r < 16; ++r) { p1[r] = __expf(fmaf(sb[r], 0.125f, -m_new)); lsum += p1[r]; }
    lsum += __shfl_xor(lsum, 32);
    l_run = fmaf(l_run, alpha, lsum);
    m_run = m_new;
#pragma unroll
    for (int r = 0; r < 16; ++r) { Oa[r] *= alpha; Ob[r] *= alpha; }

    unsigned bw[2][2][4];
    REDIST(p0, 0)
    REDIST(p1, 1)

    const unsigned* vbr = pool + (kt & 1) * 2048;
#pragma unroll
    for (int kb = 0; kb < 2; ++kb)
#pragma unroll
      for (int st = 0; st < 2; ++st) {
        const u32x4 pw = { bw[kb][st][0], bw[kb][st][1], bw[kb][st][2], bw[kb][st][3] };
        const bf16x8 pf = __builtin_bit_cast(bf16x8, pw);
        {
          const int row = c;
          const int off = (row * 128 + (kb * 64 + st * 32 + g * 16)) ^ ((row & 7) << 4);
          const bf16x8 va = __builtin_bit_cast(bf16x8, *(const u32x4*)((const char*)vbr + off));
          Oa = __builtin_amdgcn_mfma_f32_32x32x16_bf16(va, pf, Oa, 0, 0, 0);
        }
        {
          const int row = 32 + c;
          const int off = (row * 128 + (kb * 64 + st * 32 + g * 16)) ^ ((row & 7) << 4);
          const bf16x8 va = __builtin_bit_cast(bf16x8, *(const u32x4*)((const char*)vbr + off));
          Ob = __builtin_amdgcn_mfma_f32_32x32x16_bf16(va, pf, Ob, 0, 0, 0);
        }
      }

    v0 = v0n; v1 = v1n;
  }

  const float inv = 1.f / l_run;
  __hip_bfloat16* drow = att + base + (size_t)(q0 + c) * 64;
#pragma unroll
  for (int qd = 0; qd < 4; ++qd) {
    unsigned lo, hi2;
    {
      const float a0 = Oa[4 * qd + 0] * inv, a1 = Oa[4 * qd + 1] * inv;
      const float a2 = Oa[4 * qd + 2] * inv, a3 = Oa[4 * qd + 3] * inv;
      CVTPK(lo, a0, a1); CVTPK(hi2, a2, a3);
      uint2 w; w.x = lo; w.y = hi2;
      *(uint2*)(drow + 8 * qd + 4 * g) = w;
    }
    {
      const float a0 = Ob[4 * qd + 0] * inv, a1 = Ob[4 * qd + 1] * inv;
      const float a2 = Ob[4 * qd + 2] * inv, a3 = Ob[4 * qd + 3] * inv;
      CVTPK(lo, a0, a1); CVTPK(hi2, a2, a3);
      uint2 w; w.x = lo; w.y = hi2;
      *(uint2*)(drow + 32 + 8 * qd + 4 * g) = w;
    }
  }
}

// Grid (64,8): XCD = bh & 7 -> all q-blocks of one head on one XCD.
__global__ __launch_bounds__(256)
void global_attn_mfma_kernel(const __hip_bfloat16* __restrict__ Xq,
                             const __hip_bfloat16* __restrict__ Xk,
                             const __hip_bfloat16* __restrict__ Xv,
                             __hip_bfloat16* __restrict__ att) {
  __shared__ __attribute__((aligned(16))) unsigned pool[4096];
  global_attn_body(blockIdx.y, blockIdx.x, Xq, Xk, Xv, att, pool);
}

// =====================================================================
// Final fused output GEMM (BM=64, grid (4,128)) — proven.
// =====================================================================
__global__ __launch_bounds__(256)
void gemm_out_fused_kernel(const __hip_bfloat16* __restrict__ A0,
                           const __hip_bfloat16* __restrict__ A1,
                           const __hip_bfloat16* __restrict__ A2,
                           const __hip_bfloat16* __restrict__ A3,
                           const __hip_bfloat16* __restrict__ WT_base,
                           const float* __restrict__ bfused,
                           float* __restrict__ out) {
  __shared__ __attribute__((aligned(16))) __hip_bfloat16 As[2048];
  __shared__ __attribute__((aligned(16))) __hip_bfloat16 Bs[4096];
  const size_t MS = (size_t)512 * 512;
  const int row0 = blockIdx.y * 64, col0 = blockIdx.x * 128;
  f32x4 acc[2][4];
#pragma unroll
  for (int m = 0; m < 2; ++m)
#pragma unroll
    for (int n = 0; n < 4; ++n) acc[m][n] = (f32x4)(0.0f);
  const __hip_bfloat16* Az[4] = {A0, A1, A2, A3};
  for (int z = 0; z < 4; ++z)
    gemm_core_b64(Az[z], WT_base + (size_t)z * MS, As, Bs, row0, col0, acc);
  const int lane = threadIdx.x & 63, wv = threadIdx.x >> 6;
  const int g = lane >> 4, r16 = lane & 15, wm = wv >> 1, wn = wv & 1;
#pragma unroll
  for (int n = 0; n < 4; ++n) {
    const int col = col0 + wn * 64 + n * 16 + r16;
    const float bn = bfused[col] + bfused[512 + col] + bfused[1024 + col] +
                     bfused[1536 + col];
#pragma unroll
    for (int m = 0; m < 2; ++m) {
      const int rowb = row0 + wm * 32 + m * 16 + g * 4;
#pragma unroll
      for (int r = 0; r < 4; ++r)
        out[(size_t)(rowb + r) * 512 + col] = acc[m][n][r] + bn;
    }
  }
}

// =====================================================================
// Launch
// =====================================================================
extern "C" void kernel_launch(void* const* d_in, const int* in_sizes, int n_in,
                              void* d_out, int out_size, void* d_ws, size_t ws_size,
                              hipStream_t stream) {
  const float* x      = (const float*)d_in[0];
  const float* loc_wq = (const float*)d_in[1];
  const float* loc_bq = (const float*)d_in[2];
  const float* loc_wk = (const float*)d_in[3];
  const float* loc_bk = (const float*)d_in[4];
  const float* loc_wv = (const float*)d_in[5];
  const float* loc_bv = (const float*)d_in[6];
  const float* loc_wo = (const float*)d_in[7];
  const float* loc_bo = (const float*)d_in[8];
  const float* g_wq  = (const float*)d_in[9];
  const float* g_bq  = (const float*)d_in[10];
  const float* g_wk  = (const float*)d_in[11];
  const float* g_bk  = (const float*)d_in[12];
  const float* g_wv  = (const float*)d_in[13];
  const float* g_bv  = (const float*)d_in[14];
  const float* g_wo  = (const float*)d_in[15];
  const float* g_bo  = (const float*)d_in[16];
  const float* out_w = (const float*)d_in[17];
  const float* out_b = (const float*)d_in[18];
  float* out = (float*)d_out;

  __hip_bfloat16* wsb = (__hip_bfloat16*)d_ws;
  const size_t SZ = (size_t)8192 * 512;
  const size_t MS = (size_t)512 * 512;

  __hip_bfloat16* xb    = wsb;
  __hip_bfloat16* WT    = wsb + SZ;
  float* bfused = (float*)(wsb + SZ + 24 * MS);
  __hip_bfloat16* bqkvb = wsb + SZ + 24 * MS + 4096;
  __hip_bfloat16* proj  = wsb + SZ + 24 * MS + 16384;

  const size_t need_big = 2 * (17 * SZ + 24 * MS + 16384);
  const bool big = ws_size >= need_big;

  const dim3 thr(256);

  prep_weights_kernel<<<dim3(256, 22), thr, 0, stream>>>(
      loc_wq, loc_wk, loc_wv, g_wq, g_wk, g_wv, out_w, loc_wo, g_wo,
      x, loc_bq, loc_bk, loc_bv, WT, xb, bqkvb);

  __hip_bfloat16 *abar0, *abar1, *abar2, *abar3;

  if (big) {
    abar0 = proj + 12 * SZ;
    abar1 = proj + 13 * SZ;
    abar2 = proj + 14 * SZ;
    abar3 = proj + 15 * SZ;
    // extras (z=0, launch first) + qkv x12 in one dispatch
    gemm_qkv_all_kernel<<<dim3(4, 64, 13), thr, 0, stream>>>(
        xb, WT, loc_bq, loc_bk, loc_bv, g_bq, g_bk, g_bv,
        loc_bo, g_bo, out_w, out_b, proj, bfused);
    // all 3 local levels in one dispatch
    local_attn_all_kernel<<<6144, thr, 0, stream>>>(proj, bqkvb, abar0, abar1, abar2);
    global_attn_mfma_kernel<<<dim3(64, 8), thr, 0, stream>>>(
        proj + 9 * SZ, proj + 10 * SZ, proj + 11 * SZ, abar3);
  } else {
    gemm_fusew_kernel<<<dim3(4, 4, 4), thr, 0, stream>>>(WT + 12 * MS, WT + 16 * MS,
                                                         WT + 20 * MS);
    bias_fuse_kernel<<<dim3(2, 4), thr, 0, stream>>>(loc_bo, g_bo, out_w, out_b, bfused);
    __hip_bfloat16* Xq = proj;
    __hip_bfloat16* Xk = proj + SZ;
    __hip_bfloat16* Xv = proj + 2 * SZ;
    abar0 = proj + 3 * SZ;
    abar1 = proj + 4 * SZ;
    abar2 = proj + 5 * SZ;
    abar3 = proj + 6 * SZ;
    __hip_bfloat16* abars[3] = {abar0, abar1, abar2};
    const dim3 gqkv(4, 64, 3);
    for (int lv = 0; lv < 3; ++lv) {
      gemm_qkv_kernel<<<gqkv, thr, 0, stream>>>(
          xb, WT + lv * MS, 3 * MS,
          loc_bq + lv * 512, loc_bk + lv * 512, loc_bv + lv * 512, Xq);
      const __hip_bfloat16* bqb = bqkvb + (lv * 3 + 0) * 512;
      const __hip_bfloat16* bkb = bqkvb + (lv * 3 + 1) * 512;
      const __hip_bfloat16* bvb = bqkvb + (lv * 3 + 2) * 512;
      if (lv == 0)
        local_attn_mfma_kernel<3><<<2048, thr, 0, stream>>>(Xq, Xk, Xv, bqb, bkb, bvb, abars[lv]);
      else if (lv == 1)
        local_attn_mfma_kernel<5><<<2048, thr, 0, stream>>>(Xq, Xk, Xv, bqb, bkb, bvb, abars[lv]);
      else
        local_attn_mfma_kernel<7><<<2048, thr, 0, stream>>>(Xq, Xk, Xv, bqb, bkb, bvb, abars[lv]);
    }
    gemm_qkv_kernel<<<gqkv, thr, 0, stream>>>(xb, WT + 9 * MS, MS, g_bq, g_bk, g_bv, Xq);
    global_attn_mfma_kernel<<<dim3(64, 8), thr, 0, stream>>>(Xq, Xk, Xv, abar3);
  }

  gemm_out_fused_kernel<<<dim3(4, 128), thr, 0, stream>>>(abar0, abar1, abar2, abar3,
                                                          WT + 20 * MS, bfused, out);
}

// Round 16
// 237.702 us; speedup vs baseline: 1.2926x; 1.0235x over previous
//
#include <hip/hip_runtime.h>
#include <hip/hip_bf16.h>
#include <cstddef>

#define T_SEQ 1024
#define D_MODEL 512

typedef __attribute__((ext_vector_type(8))) __bf16 bf16x8;
typedef __attribute__((ext_vector_type(4))) float f32x4;
typedef __attribute__((ext_vector_type(16))) float f32x16;
typedef __attribute__((ext_vector_type(8))) unsigned short u16x8;
typedef __attribute__((ext_vector_type(4))) unsigned int u32x4;

typedef const unsigned int __attribute__((address_space(1)))* gas1_t;
typedef unsigned int __attribute__((address_space(3)))* las3_t;

__device__ __forceinline__ void gload_lds16(const void* g, void* l) {
  __builtin_amdgcn_global_load_lds((gas1_t)g, (las3_t)l, 16, 0, 0);
}

__device__ __forceinline__ float bf2f(unsigned short u) {
  return __uint_as_float(((unsigned)u) << 16);
}
__device__ __forceinline__ unsigned short f2bf(float f) {
  __hip_bfloat16 h = __float2bfloat16(f);
  return *(unsigned short*)&h;
}

#define CVTPK(dst, a, b) \
  asm("v_cvt_pk_bf16_f32 %0, %1, %2" : "=v"(dst) : "v"(a), "v"(b))

__device__ __forceinline__ void swap32(unsigned& a, unsigned& b, int lane) {
  const unsigned ax = __shfl_xor(a, 32);
  const unsigned bx = __shfl_xor(b, 32);
  const bool lo = lane < 32;
  const unsigned na = lo ? a : bx;
  const unsigned nb = lo ? ax : b;
  a = na; b = nb;
}

// =====================================================================
// Prep (proven): 22 z-slices of weight transpose/cast + x cast + bias.
// =====================================================================
__global__ __launch_bounds__(256)
void prep_weights_kernel(const float* __restrict__ loc_wq, const float* __restrict__ loc_wk,
                         const float* __restrict__ loc_wv, const float* __restrict__ g_wq,
                         const float* __restrict__ g_wk, const float* __restrict__ g_wv,
                         const float* __restrict__ out_w, const float* __restrict__ loc_wo,
                         const float* __restrict__ g_wo, const float* __restrict__ x,
                         const float* __restrict__ loc_bq, const float* __restrict__ loc_bk,
                         const float* __restrict__ loc_bv,
                         __hip_bfloat16* __restrict__ WT, __hip_bfloat16* __restrict__ xb,
                         __hip_bfloat16* __restrict__ bqkvb) {
  __shared__ float tile[32][33];
  const size_t MS = (size_t)512 * 512;
  const int z = blockIdx.y;
  const int t = threadIdx.x;

  if (z == 20) {
    const int base = blockIdx.x * 16384 + t * 8;
#pragma unroll
    for (int it = 0; it < 8; ++it) {
      const int i = base + it * 2048;
      const float4 a = *(const float4*)(x + i);
      const float4 b = *(const float4*)(x + i + 4);
      u16x8 o;
      o[0] = f2bf(a.x); o[1] = f2bf(a.y); o[2] = f2bf(a.z); o[3] = f2bf(a.w);
      o[4] = f2bf(b.x); o[5] = f2bf(b.y); o[6] = f2bf(b.z); o[7] = f2bf(b.w);
      *(u16x8*)(xb + i) = o;
    }
    return;
  }
  if (z == 21) {
    const int i = blockIdx.x * 256 + t;
    if (blockIdx.x < 18) {
      const int which = i >> 9, lv = which / 3, role = which % 3, e = i & 511;
      const float* src = role == 0 ? loc_bq : role == 1 ? loc_bk : loc_bv;
      bqkvb[i] = __float2bfloat16(src[lv * 512 + e]);
    }
    return;
  }

  const float* src;
  bool tr = true;
  if (z < 3)       src = loc_wq + (size_t)z * MS;
  else if (z < 6)  src = loc_wk + (size_t)(z - 3) * MS;
  else if (z < 9)  src = loc_wv + (size_t)(z - 6) * MS;
  else if (z == 9)  src = g_wq;
  else if (z == 10) src = g_wk;
  else if (z == 11) src = g_wv;
  else if (z < 16) src = out_w + (size_t)(z - 12) * MS;
  else if (z < 19) { src = loc_wo + (size_t)(z - 16) * MS; tr = false; }
  else             { src = g_wo; tr = false; }
  __hip_bfloat16* dst = WT + (size_t)z * MS;

  const int tk = (blockIdx.x & 15) * 32;
  const int tn = (blockIdx.x >> 4) * 32;
  const int r = t >> 3, c4 = (t & 7) * 4;
  const float4 v = *(const float4*)(src + (size_t)(tk + r) * 512 + tn + c4);
  if (tr) {
    tile[r][c4 + 0] = v.x; tile[r][c4 + 1] = v.y;
    tile[r][c4 + 2] = v.z; tile[r][c4 + 3] = v.w;
    __syncthreads();
    ushort4 o;
    o.x = f2bf(tile[c4 + 0][r]); o.y = f2bf(tile[c4 + 1][r]);
    o.z = f2bf(tile[c4 + 2][r]); o.w = f2bf(tile[c4 + 3][r]);
    *(ushort4*)(dst + (size_t)(tn + r) * 512 + tk + c4) = o;
  } else {
    ushort4 o;
    o.x = f2bf(v.x); o.y = f2bf(v.y); o.z = f2bf(v.z); o.w = f2bf(v.w);
    *(ushort4*)(dst + (size_t)(tk + r) * 512 + tn + c4) = o;
  }
}

// =====================================================================
// GEMM cores (proven).
// =====================================================================
__device__ __forceinline__ void gemm_core_b128(
    const __hip_bfloat16* __restrict__ A, const __hip_bfloat16* __restrict__ BT,
    __hip_bfloat16* As, __hip_bfloat16* Bs, int row0, int col0, f32x4 acc[4][4]) {
  const int tid = threadIdx.x;
  const int wv = tid >> 6, lane = tid & 63;
  const int g = lane >> 4, r16 = lane & 15;
  const int wm = wv >> 1, wn = wv & 1;
  const char* Ab = (const char*)A;
  const char* Bb = (const char*)BT;
  for (int k0 = 0; k0 < 512; k0 += 32) {
    {
      const int row = tid >> 2, off = (tid & 3) << 4;
      gload_lds16(Ab + (size_t)(row0 + row) * 1024 + k0 * 2 + off,
                  (char*)As + (wv << 10));
      const int i2 = tid + 256;
      const int row2 = i2 >> 2, off2 = (i2 & 3) << 4;
      gload_lds16(Ab + (size_t)(row0 + row2) * 1024 + k0 * 2 + off2,
                  (char*)As + 4096 + (wv << 10));
    }
    {
      const int row = tid >> 2, off = (tid & 3) << 4;
      gload_lds16(Bb + (size_t)(col0 + row) * 1024 + k0 * 2 + off,
                  (char*)Bs + (wv << 10));
      const int i2 = tid + 256;
      const int row2 = i2 >> 2, off2 = (i2 & 3) << 4;
      gload_lds16(Bb + (size_t)(col0 + row2) * 1024 + k0 * 2 + off2,
                  (char*)Bs + 4096 + (wv << 10));
    }
    __syncthreads();
    bf16x8 a[4], b[4];
#pragma unroll
    for (int m = 0; m < 4; ++m)
      a[m] = *(const bf16x8*)(As + (wm * 64 + m * 16 + r16) * 32 + g * 8);
#pragma unroll
    for (int n = 0; n < 4; ++n)
      b[n] = *(const bf16x8*)(Bs + (wn * 64 + n * 16 + r16) * 32 + g * 8);
#pragma unroll
    for (int m = 0; m < 4; ++m)
#pragma unroll
      for (int n = 0; n < 4; ++n)
        acc[m][n] = __builtin_amdgcn_mfma_f32_16x16x32_bf16(a[m], b[n], acc[m][n], 0, 0, 0);
    __syncthreads();
  }
}

__device__ __forceinline__ void gemm_core_b64(
    const __hip_bfloat16* __restrict__ A, const __hip_bfloat16* __restrict__ BT,
    __hip_bfloat16* As, __hip_bfloat16* Bs, int row0, int col0, f32x4 acc[2][4]) {
  const int tid = threadIdx.x;
  const int wv = tid >> 6, lane = tid & 63;
  const int g = lane >> 4, r16 = lane & 15;
  const int wm = wv >> 1, wn = wv & 1;
  const char* Ab = (const char*)A;
  const char* Bb = (const char*)BT;
  for (int k0 = 0; k0 < 512; k0 += 32) {
    {
      const int row = tid >> 2, off = (tid & 3) << 4;
      gload_lds16(Ab + (size_t)(row0 + row) * 1024 + k0 * 2 + off,
                  (char*)As + (wv << 10));
    }
    {
      const int row = tid >> 2, off = (tid & 3) << 4;
      gload_lds16(Bb + (size_t)(col0 + row) * 1024 + k0 * 2 + off,
                  (char*)Bs + (wv << 10));
      const int i2 = tid + 256;
      const int row2 = i2 >> 2, off2 = (i2 & 3) << 4;
      gload_lds16(Bb + (size_t)(col0 + row2) * 1024 + k0 * 2 + off2,
                  (char*)Bs + 4096 + (wv << 10));
    }
    __syncthreads();
    bf16x8 a[2], b[4];
#pragma unroll
    for (int m = 0; m < 2; ++m)
      a[m] = *(const bf16x8*)(As + (wm * 32 + m * 16 + r16) * 32 + g * 8);
#pragma unroll
    for (int n = 0; n < 4; ++n)
      b[n] = *(const bf16x8*)(Bs + (wn * 64 + n * 16 + r16) * 32 + g * 8);
#pragma unroll
    for (int m = 0; m < 2; ++m)
#pragma unroll
      for (int n = 0; n < 4; ++n)
        acc[m][n] = __builtin_amdgcn_mfma_f32_16x16x32_bf16(a[m], b[n], acc[m][n], 0, 0, 0);
    __syncthreads();
  }
}

// bf16 C = A@W^T + bias (one 128x128 tile)
__device__ __forceinline__ void gemm_bias_body(
    const __hip_bfloat16* __restrict__ A, const __hip_bfloat16* __restrict__ WT,
    const float* __restrict__ bias, __hip_bfloat16* __restrict__ C,
    int row0, int col0, __hip_bfloat16* As, __hip_bfloat16* Bs) {
  f32x4 acc[4][4];
#pragma unroll
  for (int m = 0; m < 4; ++m)
#pragma unroll
    for (int n = 0; n < 4; ++n) acc[m][n] = (f32x4)(0.0f);
  gemm_core_b128(A, WT, As, Bs, row0, col0, acc);
  const int lane = threadIdx.x & 63, wv = threadIdx.x >> 6;
  const int g = lane >> 4, r16 = lane & 15, wm = wv >> 1, wn = wv & 1;
#pragma unroll
  for (int n = 0; n < 4; ++n) {
    const int col = col0 + wn * 64 + n * 16 + r16;
    const float bn = bias ? bias[col] : 0.f;
#pragma unroll
    for (int m = 0; m < 4; ++m) {
      const int rowb = row0 + wm * 64 + m * 16 + g * 4;
#pragma unroll
      for (int r = 0; r < 4; ++r)
        C[(size_t)(rowb + r) * 512 + col] = __float2bfloat16(acc[m][n][r] + bn);
    }
  }
}

__device__ __forceinline__ void bias_fuse_body(
    const float* __restrict__ bo, const float* __restrict__ W,
    const float* __restrict__ add, float* __restrict__ bfz, int n) {
  float acc = add ? add[n] : 0.f;
  for (int m = 0; m < 512; ++m)
    acc = fmaf(bo[m], W[(size_t)m * 512 + n], acc);
  bfz[n] = acc;
}

// =====================================================================
// Mega Q/K/V (1-D grid, 3144 blocks), XCD-y-chunked for L2 reuse:
//  bid 0..71:   extras (64 fusew + 8 bias-fuse) — launch first, ride free.
//  bid 72..3143: i = bid-72; xcd = i&7 owns y-panels [8*xcd, 8*xcd+8);
//    within XCD order (z, y, x): the XCD's 1MB A-chunk stays L2-resident
//    across all 12 weight sweeps (FETCH was 12 full re-reads of xb).
// =====================================================================
__global__ __launch_bounds__(256)
void gemm_qkv_all_kernel(const __hip_bfloat16* __restrict__ A,
                         const __hip_bfloat16* __restrict__ WT_base,
                         const float* __restrict__ loc_bq, const float* __restrict__ loc_bk,
                         const float* __restrict__ loc_bv, const float* __restrict__ g_bq,
                         const float* __restrict__ g_bk, const float* __restrict__ g_bv,
                         const float* __restrict__ loc_bo, const float* __restrict__ g_bo,
                         const float* __restrict__ out_w, const float* __restrict__ out_b,
                         __hip_bfloat16* __restrict__ proj_base,
                         float* __restrict__ bfused) {
  __shared__ __attribute__((aligned(16))) __hip_bfloat16 As[4096];
  __shared__ __attribute__((aligned(16))) __hip_bfloat16 Bs[4096];
  const size_t MS = (size_t)512 * 512;
  const int bid = blockIdx.x;

  if (bid < 72) {
    if (bid < 64) {
      // fusew: WfT[wz] = (wo_wz @ outw_wz)^T
      const int wz = bid >> 4, row = (bid >> 2) & 3, col = bid & 3;
      f32x4 acc[4][4];
#pragma unroll
      for (int m = 0; m < 4; ++m)
#pragma unroll
        for (int n = 0; n < 4; ++n) acc[m][n] = (f32x4)(0.0f);
      gemm_core_b128(WT_base + (size_t)(12 + wz) * MS, WT_base + (size_t)(16 + wz) * MS,
                     As, Bs, row * 128, col * 128, acc);
      __hip_bfloat16* C = (__hip_bfloat16*)(WT_base + (size_t)(20 + wz) * MS);
      const int lane = threadIdx.x & 63, wv = threadIdx.x >> 6;
      const int g = lane >> 4, r16 = lane & 15, wm = wv >> 1, wn = wv & 1;
#pragma unroll
      for (int n = 0; n < 4; ++n) {
        const int cc = col * 128 + wn * 64 + n * 16 + r16;
#pragma unroll
        for (int m = 0; m < 4; ++m) {
          const int rowb = row * 128 + wm * 64 + m * 16 + g * 4;
#pragma unroll
          for (int r = 0; r < 4; ++r)
            C[(size_t)(rowb + r) * 512 + cc] = __float2bfloat16(acc[m][n][r]);
        }
      }
    } else {
      // bias fuse: 8 blocks
      const int i = bid - 64;
      const int wz = i >> 1, half = i & 1;
      const int n = half * 256 + threadIdx.x;
      const float* bo = (wz < 3) ? loc_bo + wz * 512 : g_bo;
      bias_fuse_body(bo, out_w + (size_t)wz * MS, wz == 0 ? out_b : nullptr,
                     bfused + wz * 512, n);
    }
    return;
  }

  const int i = bid - 72;         // 0..3071 ; XCD phase preserved (72%8==0)
  const int xcd = i & 7;
  const int j = i >> 3;           // 0..383
  const int z = j >> 5;           // 0..11 (weight sweep, outermost in-XCD)
  const int yl = (j >> 2) & 7;
  const int xcol = j & 3;
  const int y = xcd * 8 + yl;

  const float* bias;
  if (z < 3)       bias = loc_bq + z * 512;
  else if (z < 6)  bias = loc_bk + (z - 3) * 512;
  else if (z < 9)  bias = loc_bv + (z - 6) * 512;
  else             bias = (z == 9) ? g_bq : (z == 10) ? g_bk : g_bv;
  gemm_bias_body(A, WT_base + (size_t)z * MS, bias,
                 proj_base + (size_t)z * (size_t)(8192 * 512),
                 y * 128, xcol * 128, As, Bs);
}

// Fallback per-level Q/K/V projection.
__global__ __launch_bounds__(256)
void gemm_qkv_kernel(const __hip_bfloat16* __restrict__ A,
                     const __hip_bfloat16* __restrict__ WT_base, size_t wt_stride,
                     const float* __restrict__ b0, const float* __restrict__ b1,
                     const float* __restrict__ b2,
                     __hip_bfloat16* __restrict__ out_base) {
  __shared__ __attribute__((aligned(16))) __hip_bfloat16 As[4096];
  __shared__ __attribute__((aligned(16))) __hip_bfloat16 Bs[4096];
  const int z = blockIdx.z;
  const float* bias = (z == 0) ? b0 : (z == 1) ? b1 : b2;
  gemm_bias_body(A, WT_base + (size_t)z * wt_stride, bias,
                 out_base + (size_t)z * (size_t)(8192 * 512),
                 blockIdx.y * 128, blockIdx.x * 128, As, Bs);
}

// Fused-weight GEMM (fallback path).
__global__ __launch_bounds__(256)
void gemm_fusew_kernel(const __hip_bfloat16* __restrict__ A_base,
                       const __hip_bfloat16* __restrict__ BT_base,
                       __hip_bfloat16* __restrict__ C_base) {
  __shared__ __attribute__((aligned(16))) __hip_bfloat16 As[4096];
  __shared__ __attribute__((aligned(16))) __hip_bfloat16 Bs[4096];
  const size_t MS = (size_t)512 * 512;
  const int z = blockIdx.z;
  f32x4 acc[4][4];
#pragma unroll
  for (int m = 0; m < 4; ++m)
#pragma unroll
    for (int n = 0; n < 4; ++n) acc[m][n] = (f32x4)(0.0f);
  gemm_core_b128(A_base + z * MS, BT_base + z * MS, As, Bs,
                 blockIdx.y * 128, blockIdx.x * 128, acc);
  __hip_bfloat16* C = C_base + z * MS;
  const int lane = threadIdx.x & 63, wv = threadIdx.x >> 6;
  const int g = lane >> 4, r16 = lane & 15, wm = wv >> 1, wn = wv & 1;
#pragma unroll
  for (int n = 0; n < 4; ++n) {
    const int col = blockIdx.x * 128 + wn * 64 + n * 16 + r16;
#pragma unroll
    for (int m = 0; m < 4; ++m) {
      const int rowb = blockIdx.y * 128 + wm * 64 + m * 16 + g * 4;
#pragma unroll
      for (int r = 0; r < 4; ++r)
        C[(size_t)(rowb + r) * 512 + col] = __float2bfloat16(acc[m][n][r]);
    }
  }
}

__global__ __launch_bounds__(256)
void bias_fuse_kernel(const float* __restrict__ loc_bo, const float* __restrict__ g_bo,
                      const float* __restrict__ out_w, const float* __restrict__ out_b,
                      float* __restrict__ bfused) {
  const int z = blockIdx.y;
  const int n = blockIdx.x * 256 + threadIdx.x;
  const float* bo = (z < 3) ? loc_bo + z * 512 : g_bo;
  bias_fuse_body(bo, out_w + (size_t)z * 512 * 512, z == 0 ? out_b : nullptr,
                 bfused + z * 512, n);
}

// =====================================================================
// Local attention body (R9-proven, runtime W).
// =====================================================================
__device__ __forceinline__ const __hip_bfloat16* slot_row(
    int W, const __hip_bfloat16* __restrict__ X, const __hip_bfloat16* __restrict__ biasb,
    int b, int tloc, int pg, int sl, int* ch_out) {
  const int PAD = (W - 1) >> 1;
  const int hloc = sl >> 3, p = sl & 7;
  const int m = (pg * 4 + hloc) * W + p;
  const int j = m >> 3;
  *ch_out = m & 7;
  int sr = tloc + j - PAD;
  if (p < W) {
    if (sr >= 0 && sr < T_SEQ) return X + ((size_t)(b * T_SEQ + sr) << 9);
    return biasb;
  }
  sr = sr < 0 ? 0 : (sr > T_SEQ - 1 ? T_SEQ - 1 : sr);
  return X + ((size_t)(b * T_SEQ + sr) << 9);
}

__device__ __forceinline__ void local_attn_body(
    int W, int bx, const __hip_bfloat16* __restrict__ Xq,
    const __hip_bfloat16* __restrict__ Xk, const __hip_bfloat16* __restrict__ Xv,
    const __hip_bfloat16* __restrict__ bqb, const __hip_bfloat16* __restrict__ bkb,
    const __hip_bfloat16* __restrict__ bvb, __hip_bfloat16* __restrict__ abar,
    unsigned* pool) {
  const int tid = threadIdx.x;
  const int wv = tid >> 6, lane = tid & 63;
  const int bt = bx * 4 + wv;
  const int b = bt >> 10, tloc = bt & 1023;
  unsigned* L = pool + wv * 2048;
  const int dl = lane & 31, hi = lane >> 5;

  {
    const int k2 = dl, dhalf = hi;
    int ch0, ch1;
    const __hip_bfloat16* r0 =
        slot_row(W, Xv, bvb, b, tloc, (2 * k2) >> 5, (2 * k2) & 31, &ch0);
    const __hip_bfloat16* r1 =
        slot_row(W, Xv, bvb, b, tloc, (2 * k2 + 1) >> 5, (2 * k2 + 1) & 31, &ch1);
    u16x8 A0[4], A1[4];
#pragma unroll
    for (int q = 0; q < 4; ++q) {
      A0[q] = *(const u16x8*)(r0 + ch0 * 64 + dhalf * 32 + q * 8);
      A1[q] = *(const u16x8*)(r1 + ch1 * 64 + dhalf * 32 + q * 8);
    }
#pragma unroll
    for (int q = 0; q < 4; ++q)
#pragma unroll
      for (int e = 0; e < 8; ++e) {
        const int d_ = dhalf * 32 + q * 8 + e;
        const unsigned dw = (unsigned)A0[q][e] | ((unsigned)A1[q][e] << 16);
        const int byte = (d_ * 128 + k2 * 4) ^ ((d_ & 7) << 4);
        L[byte >> 2] = dw;
      }
  }

  f32x16 accP[2][2];
#pragma unroll
  for (int pg = 0; pg < 2; ++pg)
#pragma unroll
    for (int dh = 0; dh < 2; ++dh) accP[pg][dh] = (f32x16)(0.0f);

  const int myb = dl >> 3;

#pragma unroll
  for (int pg = 0; pg < 2; ++pg) {
    int chK, chQ;
    const __hip_bfloat16* rK = slot_row(W, Xk, bkb, b, tloc, pg, dl, &chK);
    const __hip_bfloat16* rQ = slot_row(W, Xq, bqb, b, tloc, pg, dl, &chQ);
    f32x16 sa = (f32x16)(0.0f);
#pragma unroll
    for (int i = 0; i < 4; ++i) {
      const bf16x8 kf = *(const bf16x8*)(rK + chK * 64 + i * 16 + hi * 8);
      const bf16x8 qf = *(const bf16x8*)(rQ + chQ * 64 + i * 16 + hi * 8);
      sa = __builtin_amdgcn_mfma_f32_32x32x16_bf16(kf, qf, sa, 0, 0, 0);
    }

    float sel[4];
#pragma unroll
    for (int r4 = 0; r4 < 4; ++r4)
      sel[r4] = (myb == 0) ? sa[r4]
              : (myb == 1) ? sa[4 + r4]
              : (myb == 2) ? sa[8 + r4] : sa[12 + r4];

    float mx = -3e38f;
#pragma unroll
    for (int r4 = 0; r4 < 4; ++r4)
      if (r4 + 4 * hi < W) mx = fmaxf(mx, sel[r4]);
    mx = fmaxf(mx, __shfl_xor(mx, 32));
    float e[4], ls = 0.f;
#pragma unroll
    for (int r4 = 0; r4 < 4; ++r4) {
      e[r4] = (r4 + 4 * hi < W) ? __expf(0.125f * (sel[r4] - mx)) : 0.f;
      ls += e[r4];
    }
    ls += __shfl_xor(ls, 32);
    const float inv = 1.f / ls;

    unsigned dw0, dw1;
    CVTPK(dw0, e[0] * inv, e[1] * inv);
    CVTPK(dw1, e[2] * inv, e[3] * inv);
    const unsigned q0 = __shfl_xor(dw0, 32);
    const unsigned q1 = __shfl_xor(dw1, 32);

#pragma unroll
    for (int kh = 0; kh < 2; ++kh) {
      const bool on = (2 * kh + hi) == myb;
      u32x4 bw;
      if (hi == 0) { bw[0] = dw0; bw[1] = dw1; bw[2] = q0; bw[3] = q1; }
      else         { bw[0] = q0;  bw[1] = q1;  bw[2] = dw0; bw[3] = dw1; }
      if (!on) { bw[0] = 0u; bw[1] = 0u; bw[2] = 0u; bw[3] = 0u; }
      const bf16x8 pf = __builtin_bit_cast(bf16x8, bw);
#pragma unroll
      for (int dh = 0; dh < 2; ++dh) {
        const int d_ = dh * 32 + dl;
        const int off = (d_ * 128 + pg * 64 + kh * 32 + hi * 16) ^ ((d_ & 7) << 4);
        const bf16x8 va =
            __builtin_bit_cast(bf16x8, *(const u32x4*)((const char*)L + off));
        accP[pg][dh] = __builtin_amdgcn_mfma_f32_32x32x16_bf16(va, pf, accP[pg][dh], 0, 0, 0);
      }
    }
  }

#pragma unroll
  for (int pg = 0; pg < 2; ++pg) {
    if ((dl & 7) < W) {
      const int m_o = (pg * 4 + (dl >> 3)) * W + (dl & 7);
#pragma unroll
      for (int dh = 0; dh < 2; ++dh) {
#pragma unroll
        for (int rq = 0; rq < 4; ++rq) {
          unsigned wa, wb;
          CVTPK(wa, accP[pg][dh][4 * rq + 0], accP[pg][dh][4 * rq + 1]);
          CVTPK(wb, accP[pg][dh][4 * rq + 2], accP[pg][dh][4 * rq + 3]);
          const int dwi = m_o * 34 + dh * 16 + rq * 4 + hi * 2;
          uint2 w; w.x = wa; w.y = wb;
          *(uint2*)(L + dwi) = w;
        }
      }
    }
  }
  asm volatile("s_waitcnt lgkmcnt(0)" ::: "memory");

  const int cho = lane >> 3, fb = lane & 7;
  float o[8] = {0.f, 0.f, 0.f, 0.f, 0.f, 0.f, 0.f, 0.f};
  for (int jj = 0; jj < W; ++jj) {
    const int mo = 8 * jj + cho;
    const uint2 w0 = *(const uint2*)(L + mo * 34 + fb * 4);
    const uint2 w1 = *(const uint2*)(L + mo * 34 + fb * 4 + 2);
    o[0] += bf2f((unsigned short)(w0.x & 0xffff));
    o[1] += bf2f((unsigned short)(w0.x >> 16));
    o[2] += bf2f((unsigned short)(w0.y & 0xffff));
    o[3] += bf2f((unsigned short)(w0.y >> 16));
    o[4] += bf2f((unsigned short)(w1.x & 0xffff));
    o[5] += bf2f((unsigned short)(w1.x >> 16));
    o[6] += bf2f((unsigned short)(w1.y & 0xffff));
    o[7] += bf2f((unsigned short)(w1.y >> 16));
  }
  const float invw = 1.f / (float)W;
  u16x8 ov;
#pragma unroll
  for (int e2 = 0; e2 < 8; ++e2) ov[e2] = f2bf(o[e2] * invw);
  *(u16x8*)(abar + ((size_t)bt << 9) + cho * 64 + fb * 8) = ov;
}

// All 3 local levels in ONE dispatch (6144 blocks, runtime W).
__global__ __launch_bounds__(256, 4)
void local_attn_all_kernel(const __hip_bfloat16* __restrict__ proj,
                           const __hip_bfloat16* __restrict__ bqkvb,
                           __hip_bfloat16* __restrict__ abar0,
                           __hip_bfloat16* __restrict__ abar1,
                           __hip_bfloat16* __restrict__ abar2) {
  __shared__ __attribute__((aligned(16))) unsigned pool[8192];
  const size_t SZ = (size_t)8192 * 512;
  const int bid = blockIdx.x;
  const int lv = bid >> 11;
  const int bxr = bid & 2047;
  const int bx = (bxr & 7) * 256 + (bxr >> 3);   // XCD-chunked swizzle
  const int W = (lv == 0) ? 3 : (lv == 1) ? 5 : 7;
  __hip_bfloat16* abar = (lv == 0) ? abar0 : (lv == 1) ? abar1 : abar2;
  local_attn_body(W, bx, proj + (size_t)lv * SZ, proj + (size_t)(3 + lv) * SZ,
                  proj + (size_t)(6 + lv) * SZ,
                  bqkvb + (lv * 3 + 0) * 512, bqkvb + (lv * 3 + 1) * 512,
                  bqkvb + (lv * 3 + 2) * 512, abar, pool);
}

// Fallback single-level wrappers.
template <int W>
__global__ __launch_bounds__(256, 4)
void local_attn_mfma_kernel(const __hip_bfloat16* __restrict__ Xq,
                            const __hip_bfloat16* __restrict__ Xk,
                            const __hip_bfloat16* __restrict__ Xv,
                            const __hip_bfloat16* __restrict__ bqb,
                            const __hip_bfloat16* __restrict__ bkb,
                            const __hip_bfloat16* __restrict__ bvb,
                            __hip_bfloat16* __restrict__ abar) {
  __shared__ __attribute__((aligned(16))) unsigned pool[8192];
  const int bx = (blockIdx.x & 7) * 256 + (blockIdx.x >> 3);
  local_attn_body(W, bx, Xq, Xk, Xv, bqb, bkb, bvb, abar, pool);
}

// =====================================================================
// Global attention body (R9-proven, 54us).
// =====================================================================
#define REDIST(pb, kb_)                                                  \
    {                                                                    \
      unsigned t0_, t1_, t2_, t3_, t4_, t5_, t6_, t7_;                   \
      CVTPK(t0_, pb[0], pb[1]);   CVTPK(t1_, pb[2], pb[3]);              \
      CVTPK(t2_, pb[4], pb[5]);   CVTPK(t3_, pb[6], pb[7]);              \
      CVTPK(t4_, pb[8], pb[9]);   CVTPK(t5_, pb[10], pb[11]);            \
      CVTPK(t6_, pb[12], pb[13]); CVTPK(t7_, pb[14], pb[15]);            \
      swap32(t0_, t2_, lane); swap32(t1_, t3_, lane);                    \
      swap32(t4_, t6_, lane); swap32(t5_, t7_, lane);                    \
      bw[kb_][0][0] = t0_; bw[kb_][0][1] = t1_; bw[kb_][0][2] = t2_;     \
      bw[kb_][0][3] = t3_;                                               \
      bw[kb_][1][0] = t4_; bw[kb_][1][1] = t5_; bw[kb_][1][2] = t6_;     \
      bw[kb_][1][3] = t7_;                                               \
    }

__device__ __forceinline__ void global_attn_body(
    int qblk, int bh, const __hip_bfloat16* __restrict__ Xq,
    const __hip_bfloat16* __restrict__ Xk, const __hip_bfloat16* __restrict__ Xv,
    __hip_bfloat16* __restrict__ att, unsigned* pool) {
  const int tid = threadIdx.x;
  const int lane = tid & 63;
  const int wv = tid >> 6;
  const size_t base = (size_t)bh << 16;
  const int c = lane & 31;
  const int g = lane >> 5;
  const int q0 = qblk * 128 + wv * 32;

  const __hip_bfloat16* Qp = Xq + base;
  const __hip_bfloat16* Kp = Xk + base;
  const __hip_bfloat16* Vp = Xv + base;

  bf16x8 qf[4];
#pragma unroll
  for (int s = 0; s < 4; ++s)
    qf[s] = *(const bf16x8*)(Qp + (size_t)(q0 + c) * 64 + s * 16 + g * 8);

  const int k2 = tid & 31, dblk = tid >> 5;

  bf16x8 kf[2][4];
  u16x8 v0, v1, v0n, v1n;

  v0 = *(const u16x8*)(Vp + (size_t)(2 * k2) * 64 + dblk * 8);
  v1 = *(const u16x8*)(Vp + (size_t)(2 * k2 + 1) * 64 + dblk * 8);
#pragma unroll
  for (int kb = 0; kb < 2; ++kb)
#pragma unroll
    for (int s = 0; s < 4; ++s)
      kf[kb][s] = *(const bf16x8*)(Kp + (size_t)(kb * 32 + c) * 64 + s * 16 + g * 8);

  f32x16 Oa = (f32x16)(0.0f), Ob = (f32x16)(0.0f);
  float m_run = -3e38f, l_run = 0.f;

  for (int kt = 0; kt < 16; ++kt) {
    unsigned* vb = pool + (kt & 1) * 2048;
#pragma unroll
    for (int jj = 0; jj < 8; ++jj) {
      const int d = dblk * 8 + jj;
      const unsigned dw = (unsigned)v0[jj] | ((unsigned)v1[jj] << 16);
      const int byte = (d * 128 + k2 * 4) ^ ((d & 7) << 4);
      vb[byte >> 2] = dw;
    }
    if (kt < 15) {
      const __hip_bfloat16* vsrc = Vp + (size_t)((kt + 1) * 64 + 2 * k2) * 64 + dblk * 8;
      v0n = *(const u16x8*)vsrc;
      v1n = *(const u16x8*)(vsrc + 64);
    }
    __syncthreads();

    f32x16 sa = (f32x16)(0.0f), sb = (f32x16)(0.0f);
#pragma unroll
    for (int s = 0; s < 4; ++s)
      sa = __builtin_amdgcn_mfma_f32_32x32x16_bf16(kf[0][s], qf[s], sa, 0, 0, 0);
#pragma unroll
    for (int s = 0; s < 4; ++s)
      sb = __builtin_amdgcn_mfma_f32_32x32x16_bf16(kf[1][s], qf[s], sb, 0, 0, 0);

    if (kt < 15) {
#pragma unroll
      for (int kb = 0; kb < 2; ++kb)
#pragma unroll
        for (int s = 0; s < 4; ++s)
          kf[kb][s] = *(const bf16x8*)(Kp + (size_t)((kt + 1) * 64 + kb * 32 + c) * 64 +
                                       s * 16 + g * 8);
    }

    float mx = sa[0];
#pragma unroll
    for (int r = 1; r < 16; ++r) mx = fmaxf(mx, sa[r]);
#pragma unroll
    for (int r = 0; r < 16; ++r) mx = fmaxf(mx, sb[r]);
    mx = fmaxf(mx, __shfl_xor(mx, 32));
    const float m_new = fmaxf(m_run, mx * 0.125f);
    const float alpha = __expf(m_run - m_new);

    float p0[16], p1[16];
    float lsum = 0.f;
#pragma unroll
    for (int r = 0; r < 16; ++r) { p0[r] = __expf(fmaf(sa[r], 0.125f, -m_new)); lsum += p0[r]; }
#pragma unroll
    for (int r = 0; r < 16; ++r) { p1[r] = __expf(fmaf(sb[r], 0.125f, -m_new)); lsum += p1[r]; }
    lsum += __shfl_xor(lsum, 32);
    l_run = fmaf(l_run, alpha, lsum);
    m_run = m_new;
#pragma unroll
    for (int r = 0; r < 16; ++r) { Oa[r] *= alpha; Ob[r] *= alpha; }

    unsigned bw[2][2][4];
    REDIST(p0, 0)
    REDIST(p1, 1)

    const unsigned* vbr = pool + (kt & 1) * 2048;
#pragma unroll
    for (int kb = 0; kb < 2; ++kb)
#pragma unroll
      for (int st = 0; st < 2; ++st) {
        const u32x4 pw = { bw[kb][st][0], bw[kb][st][1], bw[kb][st][2], bw[kb][st][3] };
        const bf16x8 pf = __builtin_bit_cast(bf16x8, pw);
        {
          const int row = c;
          const int off = (row * 128 + (kb * 64 + st * 32 + g * 16)) ^ ((row & 7) << 4);
          const bf16x8 va = __builtin_bit_cast(bf16x8, *(const u32x4*)((const char*)vbr + off));
          Oa = __builtin_amdgcn_mfma_f32_32x32x16_bf16(va, pf, Oa, 0, 0, 0);
        }
        {
          const int row = 32 + c;
          const int off = (row * 128 + (kb * 64 + st * 32 + g * 16)) ^ ((row & 7) << 4);
          const bf16x8 va = __builtin_bit_cast(bf16x8, *(const u32x4*)((const char*)vbr + off));
          Ob = __builtin_amdgcn_mfma_f32_32x32x16_bf16(va, pf, Ob, 0, 0, 0);
        }
      }

    v0 = v0n; v1 = v1n;
  }

  const float inv = 1.f / l_run;
  __hip_bfloat16* drow = att + base + (size_t)(q0 + c) * 64;
#pragma unroll
  for (int qd = 0; qd < 4; ++qd) {
    unsigned lo, hi2;
    {
      const float a0 = Oa[4 * qd + 0] * inv, a1 = Oa[4 * qd + 1] * inv;
      const float a2 = Oa[4 * qd + 2] * inv, a3 = Oa[4 * qd + 3] * inv;
      CVTPK(lo, a0, a1); CVTPK(hi2, a2, a3);
      uint2 w; w.x = lo; w.y = hi2;
      *(uint2*)(drow + 8 * qd + 4 * g) = w;
    }
    {
      const float a0 = Ob[4 * qd + 0] * inv, a1 = Ob[4 * qd + 1] * inv;
      const float a2 = Ob[4 * qd + 2] * inv, a3 = Ob[4 * qd + 3] * inv;
      CVTPK(lo, a0, a1); CVTPK(hi2, a2, a3);
      uint2 w; w.x = lo; w.y = hi2;
      *(uint2*)(drow + 32 + 8 * qd + 4 * g) = w;
    }
  }
}

// Grid (64,8): XCD = bh & 7 -> all q-blocks of one head on one XCD.
__global__ __launch_bounds__(256)
void global_attn_mfma_kernel(const __hip_bfloat16* __restrict__ Xq,
                             const __hip_bfloat16* __restrict__ Xk,
                             const __hip_bfloat16* __restrict__ Xv,
                             __hip_bfloat16* __restrict__ att) {
  __shared__ __attribute__((aligned(16))) unsigned pool[4096];
  global_attn_body(blockIdx.y, blockIdx.x, Xq, Xk, Xv, att, pool);
}

// =====================================================================
// Final fused output GEMM (BM=64): 1-D 512 blocks, XCD-y-chunked —
// each XCD owns 16 y-panels; per-panel x-sweep keeps the 256KB A-panel
// in its L2 (was: 4 x-blocks of a panel scattered across 4 XCDs).
// =====================================================================
__global__ __launch_bounds__(256)
void gemm_out_fused_kernel(const __hip_bfloat16* __restrict__ A0,
                           const __hip_bfloat16* __restrict__ A1,
                           const __hip_bfloat16* __restrict__ A2,
                           const __hip_bfloat16* __restrict__ A3,
                           const __hip_bfloat16* __restrict__ WT_base,
                           const float* __restrict__ bfused,
                           float* __restrict__ out) {
  __shared__ __attribute__((aligned(16))) __hip_bfloat16 As[2048];
  __shared__ __attribute__((aligned(16))) __hip_bfloat16 Bs[4096];
  const size_t MS = (size_t)512 * 512;
  const int bid = blockIdx.x;
  const int xcd = bid & 7;
  const int j = bid >> 3;               // 0..63
  const int y = xcd * 16 + (j >> 2);    // 0..127
  const int xcol = j & 3;
  const int row0 = y * 64, col0 = xcol * 128;
  f32x4 acc[2][4];
#pragma unroll
  for (int m = 0; m < 2; ++m)
#pragma unroll
    for (int n = 0; n < 4; ++n) acc[m][n] = (f32x4)(0.0f);
  const __hip_bfloat16* Az[4] = {A0, A1, A2, A3};
  for (int z = 0; z < 4; ++z)
    gemm_core_b64(Az[z], WT_base + (size_t)z * MS, As, Bs, row0, col0, acc);
  const int lane = threadIdx.x & 63, wv = threadIdx.x >> 6;
  const int g = lane >> 4, r16 = lane & 15, wm = wv >> 1, wn = wv & 1;
#pragma unroll
  for (int n = 0; n < 4; ++n) {
    const int col = col0 + wn * 64 + n * 16 + r16;
    const float bn = bfused[col] + bfused[512 + col] + bfused[1024 + col] +
                     bfused[1536 + col];
#pragma unroll
    for (int m = 0; m < 2; ++m) {
      const int rowb = row0 + wm * 32 + m * 16 + g * 4;
#pragma unroll
      for (int r = 0; r < 4; ++r)
        out[(size_t)(rowb + r) * 512 + col] = acc[m][n][r] + bn;
    }
  }
}

// =====================================================================
// Launch
// =====================================================================
extern "C" void kernel_launch(void* const* d_in, const int* in_sizes, int n_in,
                              void* d_out, int out_size, void* d_ws, size_t ws_size,
                              hipStream_t stream) {
  const float* x      = (const float*)d_in[0];
  const float* loc_wq = (const float*)d_in[1];
  const float* loc_bq = (const float*)d_in[2];
  const float* loc_wk = (const float*)d_in[3];
  const float* loc_bk = (const float*)d_in[4];
  const float* loc_wv = (const float*)d_in[5];
  const float* loc_bv = (const float*)d_in[6];
  const float* loc_wo = (const float*)d_in[7];
  const float* loc_bo = (const float*)d_in[8];
  const float* g_wq  = (const float*)d_in[9];
  const float* g_bq  = (const float*)d_in[10];
  const float* g_wk  = (const float*)d_in[11];
  const float* g_bk  = (const float*)d_in[12];
  const float* g_wv  = (const float*)d_in[13];
  const float* g_bv  = (const float*)d_in[14];
  const float* g_wo  = (const float*)d_in[15];
  const float* g_bo  = (const float*)d_in[16];
  const float* out_w = (const float*)d_in[17];
  const float* out_b = (const float*)d_in[18];
  float* out = (float*)d_out;

  __hip_bfloat16* wsb = (__hip_bfloat16*)d_ws;
  const size_t SZ = (size_t)8192 * 512;
  const size_t MS = (size_t)512 * 512;

  __hip_bfloat16* xb    = wsb;
  __hip_bfloat16* WT    = wsb + SZ;
  float* bfused = (float*)(wsb + SZ + 24 * MS);
  __hip_bfloat16* bqkvb = wsb + SZ + 24 * MS + 4096;
  __hip_bfloat16* proj  = wsb + SZ + 24 * MS + 16384;

  const size_t need_big = 2 * (17 * SZ + 24 * MS + 16384);
  const bool big = ws_size >= need_big;

  const dim3 thr(256);

  prep_weights_kernel<<<dim3(256, 22), thr, 0, stream>>>(
      loc_wq, loc_wk, loc_wv, g_wq, g_wk, g_wv, out_w, loc_wo, g_wo,
      x, loc_bq, loc_bk, loc_bv, WT, xb, bqkvb);

  __hip_bfloat16 *abar0, *abar1, *abar2, *abar3;

  if (big) {
    abar0 = proj + 12 * SZ;
    abar1 = proj + 13 * SZ;
    abar2 = proj + 14 * SZ;
    abar3 = proj + 15 * SZ;
    // extras (first 72 blocks) + qkv x12, XCD-y-chunked 1-D mapping
    gemm_qkv_all_kernel<<<3144, thr, 0, stream>>>(
        xb, WT, loc_bq, loc_bk, loc_bv, g_bq, g_bk, g_bv,
        loc_bo, g_bo, out_w, out_b, proj, bfused);
    // all 3 local levels in one dispatch
    local_attn_all_kernel<<<6144, thr, 0, stream>>>(proj, bqkvb, abar0, abar1, abar2);
    global_attn_mfma_kernel<<<dim3(64, 8), thr, 0, stream>>>(
        proj + 9 * SZ, proj + 10 * SZ, proj + 11 * SZ, abar3);
  } else {
    gemm_fusew_kernel<<<dim3(4, 4, 4), thr, 0, stream>>>(WT + 12 * MS, WT + 16 * MS,
                                                         WT + 20 * MS);
    bias_fuse_kernel<<<dim3(2, 4), thr, 0, stream>>>(loc_bo, g_bo, out_w, out_b, bfused);
    __hip_bfloat16* Xq = proj;
    __hip_bfloat16* Xk = proj + SZ;
    __hip_bfloat16* Xv = proj + 2 * SZ;
    abar0 = proj + 3 * SZ;
    abar1 = proj + 4 * SZ;
    abar2 = proj + 5 * SZ;
    abar3 = proj + 6 * SZ;
    __hip_bfloat16* abars[3] = {abar0, abar1, abar2};
    const dim3 gqkv(4, 64, 3);
    for (int lv = 0; lv < 3; ++lv) {
      gemm_qkv_kernel<<<gqkv, thr, 0, stream>>>(
          xb, WT + lv * MS, 3 * MS,
          loc_bq + lv * 512, loc_bk + lv * 512, loc_bv + lv * 512, Xq);
      const __hip_bfloat16* bqb = bqkvb + (lv * 3 + 0) * 512;
      const __hip_bfloat16* bkb = bqkvb + (lv * 3 + 1) * 512;
      const __hip_bfloat16* bvb = bqkvb + (lv * 3 + 2) * 512;
      if (lv == 0)
        local_attn_mfma_kernel<3><<<2048, thr, 0, stream>>>(Xq, Xk, Xv, bqb, bkb, bvb, abars[lv]);
      else if (lv == 1)
        local_attn_mfma_kernel<5><<<2048, thr, 0, stream>>>(Xq, Xk, Xv, bqb, bkb, bvb, abars[lv]);
      else
        local_attn_mfma_kernel<7><<<2048, thr, 0, stream>>>(Xq, Xk, Xv, bqb, bkb, bvb, abars[lv]);
    }
    gemm_qkv_kernel<<<gqkv, thr, 0, stream>>>(xb, WT + 9 * MS, MS, g_bq, g_bk, g_bv, Xq);
    global_attn_mfma_kernel<<<dim3(64, 8), thr, 0, stream>>>(Xq, Xk, Xv, abar3);
  }

  gemm_out_fused_kernel<<<512, thr, 0, stream>>>(abar0, abar1, abar2, abar3,
                                                 WT + 20 * MS, bfused, out);
}